// Round 1
// baseline (853.606 us; speedup 1.0000x reference)
//
#include <hip/hip_runtime.h>
#include <math.h>

// Sizes
// B=8, L=1024, D=512, N=64, NC=4, HIDDEN=1024 (act width), up rows=2048, R=64

__device__ __forceinline__ float sigmoidf_(float x) { return 1.0f / (1.0f + expf(-x)); }
__device__ __forceinline__ float geluf_(float x) { return 0.5f * x * (1.0f + erff(x * 0.70710678118654752f)); }

// ---------------------------------------------------------------------------
// P1: per-component A_bar (forward-substitution, lhs is lower-triangular) and
// A32 = A_bar^32 via 5 squarings. Stores A_bar TRANSPOSED for conflict-free
// matvec reads later. 4 blocks x 256 threads.
// ---------------------------------------------------------------------------
__global__ __launch_bounds__(256) void prep_comp(const float* __restrict__ log_dt,
                                                 float* __restrict__ AbarT,
                                                 float* __restrict__ A32,
                                                 float* __restrict__ dtbuf) {
    int comp = blockIdx.x, tid = threadIdx.x;
    __shared__ float sq[64];
    __shared__ float M1[4096];
    __shared__ float M2[4096];
    float ldt = log_dt[comp];
    float dt = log1pf(expf(ldt)) + 1e-6f;  // softplus + 1e-6 (ldt ~ -2.3..-1.1, safe)
    if (tid < 64) sq[tid] = sqrtf(2.0f * tid + 1.0f);
    __syncthreads();
    if (tid < 64) {
        int j = tid;
        float hdt = 0.5f * dt;
        for (int i = 0; i < j; ++i) M1[i * 64 + j] = 0.0f;
        for (int i = j; i < 64; ++i) {
            float r = (i == j) ? (1.0f - hdt * (float)(j + 1)) : (-hdt * sq[i] * sq[j]);
            for (int k = j; k < i; ++k) r -= hdt * sq[i] * sq[k] * M1[k * 64 + j];
            M1[i * 64 + j] = r / (1.0f + hdt * (float)(i + 1));
        }
    }
    __syncthreads();
    // AbarT[comp][k][i] = Abar[i][k]
    for (int idx = tid; idx < 4096; idx += 256) {
        int k = idx >> 6, i = idx & 63;
        AbarT[comp * 4096 + idx] = M1[i * 64 + k];
    }
    float* cur = M1;
    float* nxt = M2;
    for (int s = 0; s < 5; ++s) {
        __syncthreads();
        for (int idx = tid; idx < 4096; idx += 256) {
            int i = idx >> 6, j = idx & 63;
            float acc = 0.0f;
            for (int k = j; k <= i; ++k) acc += cur[i * 64 + k] * cur[k * 64 + j];
            nxt[idx] = acc;  // upper (j>i) -> empty loop -> 0
        }
        float* t = cur; cur = nxt; nxt = t;
    }
    __syncthreads();
    for (int idx = tid; idx < 4096; idx += 256) A32[comp * 4096 + idx] = cur[idx];
    if (tid == 0) dtbuf[comp] = dt;
}

// ---------------------------------------------------------------------------
// P2: B_bar rows via forward substitution, one thread per (comp, d).
// 8 blocks x 256 threads = 2048 solves of size 64.
// ---------------------------------------------------------------------------
__global__ __launch_bounds__(256) void compute_bbar(const float* __restrict__ Bp,
                                                    const float* __restrict__ dtbuf,
                                                    float* __restrict__ Bbar) {
    int gid = blockIdx.x * 256 + threadIdx.x;  // comp*512 + d
    int comp = gid >> 9;
    __shared__ float sq[64];
    if (threadIdx.x < 64) sq[threadIdx.x] = sqrtf(2.0f * threadIdx.x + 1.0f);
    __syncthreads();
    float dt = dtbuf[comp];
    float hdt = 0.5f * dt;
    const float* bp = Bp + (size_t)gid * 64;
    float y[64];
#pragma unroll
    for (int i = 0; i < 64; ++i) {
        float s = dt * bp[i];
        float fi = hdt * sq[i];
#pragma unroll
        for (int k = 0; k < i; ++k) s -= fi * sq[k] * y[k];
        y[i] = s / (1.0f + hdt * (float)(i + 1));
    }
    float* out = Bbar + (size_t)gid * 64;
#pragma unroll
    for (int i = 0; i < 64; ++i) out[i] = y[i];
}

// ---------------------------------------------------------------------------
// P3: per-(d, comp) block: v_r = Abar^r b_d (r<32), u_q = C_d Abar^(32q) (q<32)
// via 31 fused matvec phases; then Kpart[comp][d][l=32q+r] = u_q . v_r (+D at l=0).
// Grid (512, 4) x 256 threads. LDS ~50 KB.
// ---------------------------------------------------------------------------
__global__ __launch_bounds__(256) void compute_K(const float* __restrict__ Cp,
                                                 const float* __restrict__ Bbar,
                                                 const float* __restrict__ AbarT,
                                                 const float* __restrict__ A32,
                                                 const float* __restrict__ Dp,
                                                 float* __restrict__ Kpart) {
    int d = blockIdx.x, comp = blockIdx.y, tid = threadIdx.x;
    __shared__ float Ms1[64 * 65];  // Ms1[k*65+i] = Abar[i][k]
    __shared__ float Ms2[64 * 65];  // Ms2[m*65+n] = A32[m][n]
    __shared__ float uvv[32 * 65];  // v_r
    __shared__ float uvu[32 * 65];  // u_q
    for (int idx = tid; idx < 4096; idx += 256) {
        int k = idx >> 6, i = idx & 63;
        Ms1[k * 65 + i] = AbarT[comp * 4096 + idx];
        Ms2[k * 65 + i] = A32[comp * 4096 + idx];
    }
    if (tid < 64) {
        uvv[tid] = Bbar[((size_t)comp * 512 + d) * 64 + tid];
        uvu[tid] = Cp[((size_t)comp * 512 + d) * 64 + tid];
    }
    __syncthreads();
    int half = tid >> 7, hh = tid & 1, idx = (tid >> 1) & 63;
    for (int r = 1; r < 32; ++r) {
        float s = 0.0f;
        if (half == 0) {  // v_r[i] = sum_{k<=i} Abar[i][k] v_{r-1}[k]
            int i = idx;
            int k0 = hh * 32, k1 = min(k0 + 32, i + 1);
            for (int k = k0; k < k1; ++k) s += Ms1[k * 65 + i] * uvv[(r - 1) * 65 + k];
        } else {  // u_q[n] = sum_{m>=n} u_{q-1}[m] A32[m][n]
            int n = idx;
            int m0 = max(hh * 32, n), m1 = hh * 32 + 32;
            for (int m = m0; m < m1; ++m) s += Ms2[m * 65 + n] * uvu[(r - 1) * 65 + m];
        }
        s += __shfl_xor(s, 1, 64);
        if (hh == 0) {
            if (half == 0) uvv[r * 65 + idx] = s;
            else uvu[r * 65 + idx] = s;
        }
        __syncthreads();
    }
    float dval = Dp[comp * 512 + d];
    int l0 = tid * 4;
    float ov[4];
#pragma unroll
    for (int j = 0; j < 4; ++j) {
        int l = l0 + j, q = l >> 5, rr = l & 31;
        float s = 0.0f;
#pragma unroll 8
        for (int n = 0; n < 64; ++n) s += uvu[q * 65 + n] * uvv[rr * 65 + n];
        if (l == 0) s += dval;
        ov[j] = s;
    }
    float4 o; o.x = ov[0]; o.y = ov[1]; o.z = ov[2]; o.w = ov[3];
    *(float4*)&Kpart[((size_t)comp * 512 + d) * 1024 + l0] = o;
}

// Sum over components, REVERSE time index (XLA conv = correlation; with left-pad
// L-1 the causal tap for lag tau is K[:, 1023-tau]).
__global__ __launch_bounds__(256) void reduce_K(const float* __restrict__ Kpart,
                                                float* __restrict__ Kr) {
    int idx = blockIdx.x * 256 + threadIdx.x;  // 0..524287
    int d = idx >> 10, l = idx & 1023;
    float s = Kpart[idx] + Kpart[524288 + idx] + Kpart[2 * 524288 + idx] + Kpart[3 * 524288 + idx];
    Kr[(size_t)d * 1024 + (1023 - l)] = s;
}

// ---------------------------------------------------------------------------
// Transpose x (B,T,C) -> xT (B,C,T) for coalesced conv loads.
// ---------------------------------------------------------------------------
__global__ __launch_bounds__(256) void transpose_x(const float* __restrict__ x,
                                                   float* __restrict__ xT) {
    __shared__ float tile[32][33];
    int t0 = blockIdx.x * 32, c0 = blockIdx.y * 32, b = blockIdx.z;
    int tx = threadIdx.x & 31, ty = threadIdx.x >> 5;
#pragma unroll
    for (int m = 0; m < 4; ++m)
        tile[ty + 8 * m][tx] = x[((size_t)b * 1024 + t0 + ty + 8 * m) * 512 + c0 + tx];
    __syncthreads();
#pragma unroll
    for (int m = 0; m < 4; ++m)
        xT[((size_t)b * 512 + c0 + ty + 8 * m) * 1024 + t0 + tx] = tile[tx][ty + 8 * m];
}

// ---------------------------------------------------------------------------
// Causal full-length depthwise conv, one (b,c) per block (64 threads).
// Each thread: two octets of 8 consecutive t (o=tid and o=127-tid for balance),
// s-tiles of 8 with a 16-float register window (2 LDS b128 per 64 FMA).
// Also produces per-(b,c) time-sum for SE.
// ---------------------------------------------------------------------------
__global__ __launch_bounds__(64) void conv_kernel(const float* __restrict__ xT,
                                                  const float* __restrict__ Kr,
                                                  float* __restrict__ y,
                                                  float* __restrict__ ssum) {
    int bc = blockIdx.x, b = bc >> 9, c = bc & 511, tid = threadIdx.x;
    __shared__ __align__(16) float xss[1032];
    __shared__ __align__(16) float ks[1024];
    float* xs = xss + 8;
    for (int j = tid * 4; j < 1024; j += 256) {
        *(float4*)&xs[j] = *(const float4*)&xT[(size_t)bc * 1024 + j];
        *(float4*)&ks[j] = *(const float4*)&Kr[(size_t)c * 1024 + j];
    }
    if (tid < 8) xss[tid] = 0.0f;
    __syncthreads();
    float total = 0.0f;
    for (int oc = 0; oc < 2; ++oc) {
        int o = (oc == 0) ? tid : (127 - tid);
        int base = o * 8;
        float4 b0 = *(const float4*)&xs[base];
        float4 b1 = *(const float4*)&xs[base + 4];
        float h[8] = {b0.x, b0.y, b0.z, b0.w, b1.x, b1.y, b1.z, b1.w};
        float acc[8] = {0, 0, 0, 0, 0, 0, 0, 0};
        for (int s0 = 0; s0 <= base; s0 += 8) {
            float4 a0 = *(const float4*)&xs[base - s0 - 8];  // hits xss[0..7]=0 on last tile
            float4 a1 = *(const float4*)&xs[base - s0 - 4];
            float4 k0 = *(const float4*)&ks[s0];
            float4 k1 = *(const float4*)&ks[s0 + 4];
            float xw[16] = {a0.x, a0.y, a0.z, a0.w, a1.x, a1.y, a1.z, a1.w,
                            h[0], h[1], h[2], h[3], h[4], h[5], h[6], h[7]};
            float kk[8] = {k0.x, k0.y, k0.z, k0.w, k1.x, k1.y, k1.z, k1.w};
#pragma unroll
            for (int ss = 0; ss < 8; ++ss)
#pragma unroll
                for (int j = 0; j < 8; ++j)
                    acc[j] += kk[ss] * xw[8 + j - ss];
#pragma unroll
            for (int p = 0; p < 8; ++p) h[p] = xw[p];
        }
#pragma unroll
        for (int j = 0; j < 8; ++j) {
            y[((size_t)b * 1024 + base + j) * 512 + c] = acc[j];
            total += acc[j];
        }
    }
#pragma unroll
    for (int off = 32; off > 0; off >>= 1) total += __shfl_down(total, off, 64);
    if (tid == 0) ssum[bc] = total;
}

// ---------------------------------------------------------------------------
// SE gate: g[b,c] = sigmoid(relu(mean_t(y) @ w1^T + b1) @ w2^T + b2). 8 blocks.
// ---------------------------------------------------------------------------
__global__ __launch_bounds__(256) void se_kernel(const float* __restrict__ ssum,
                                                 const float* __restrict__ w1,
                                                 const float* __restrict__ b1,
                                                 const float* __restrict__ w2,
                                                 const float* __restrict__ b2,
                                                 float* __restrict__ g) {
    int b = blockIdx.x, tid = threadIdx.x;
    __shared__ float s_sh[512];
    __shared__ float part[256];
    __shared__ float h_sh[64];
    for (int c = tid; c < 512; c += 256) s_sh[c] = ssum[b * 512 + c] * (1.0f / 1024.0f);
    __syncthreads();
    int r = tid & 63, seg = tid >> 6;
    float p = 0.0f;
    for (int c = seg * 128; c < seg * 128 + 128; ++c) p += s_sh[c] * w1[r * 512 + c];
    part[tid] = p;
    __syncthreads();
    if (tid < 64) {
        float h = part[tid] + part[tid + 64] + part[tid + 128] + part[tid + 192] + b1[tid];
        h_sh[tid] = fmaxf(h, 0.0f);
    }
    __syncthreads();
    for (int c = tid; c < 512; c += 256) {
        float acc = b2[c];
#pragma unroll 8
        for (int rr = 0; rr < 64; ++rr) acc += h_sh[rr] * w2[c * 64 + rr];
        g[b * 512 + c] = 1.0f / (1.0f + expf(-acc));
    }
}

// ---------------------------------------------------------------------------
// fuse1: y1 = LN(x + y*g, n1). One row (b,t) per block, 128 threads x float4.
// ---------------------------------------------------------------------------
__global__ __launch_bounds__(128) void fuse1_kernel(const float* __restrict__ x,
                                                    const float* __restrict__ y,
                                                    const float* __restrict__ g,
                                                    const float* __restrict__ n1g,
                                                    const float* __restrict__ n1b,
                                                    float* __restrict__ y1) {
    int row = blockIdx.x, b = row >> 10, tid = threadIdx.x, c = tid * 4;
    __shared__ float r1[2], r2[2];
    float4 xv = *(const float4*)&x[(size_t)row * 512 + c];
    float4 yv = *(const float4*)&y[(size_t)row * 512 + c];
    float4 gv = *(const float4*)&g[b * 512 + c];
    float4 v;
    v.x = xv.x + yv.x * gv.x; v.y = xv.y + yv.y * gv.y;
    v.z = xv.z + yv.z * gv.z; v.w = xv.w + yv.w * gv.w;
    float s1 = v.x + v.y + v.z + v.w;
    float s2 = v.x * v.x + v.y * v.y + v.z * v.z + v.w * v.w;
#pragma unroll
    for (int off = 32; off > 0; off >>= 1) {
        s1 += __shfl_down(s1, off, 64);
        s2 += __shfl_down(s2, off, 64);
    }
    if ((tid & 63) == 0) { r1[tid >> 6] = s1; r2[tid >> 6] = s2; }
    __syncthreads();
    float mean = (r1[0] + r1[1]) * (1.0f / 512.0f);
    float var = (r2[0] + r2[1]) * (1.0f / 512.0f) - mean * mean;
    float rstd = rsqrtf(var + 1e-5f);
    float4 g4 = *(const float4*)&n1g[c];
    float4 b4 = *(const float4*)&n1b[c];
    float4 o;
    o.x = (v.x - mean) * rstd * g4.x + b4.x; o.y = (v.y - mean) * rstd * g4.y + b4.y;
    o.z = (v.z - mean) * rstd * g4.z + b4.z; o.w = (v.w - mean) * rstd * g4.w + b4.w;
    *(float4*)&y1[(size_t)row * 512 + c] = o;
}

// ---------------------------------------------------------------------------
// Tiled f32 GEMM: C = A @ W^T (+bias), W row-major [N][K]. BM=128 BN=64 BK=16,
// 256 threads, 8x4 microtile. GLU=true computes both halves (W rows n and
// Nout+n) and writes gelu(a)*sigmoid(g) directly (u never materialized).
// ---------------------------------------------------------------------------
template <bool GLU>
__global__ __launch_bounds__(256) void gemm_bt(const float* __restrict__ A,
                                               const float* __restrict__ W,
                                               const float* __restrict__ bias,
                                               float* __restrict__ Cout,
                                               int K, int Nout) {
    int m0 = blockIdx.x * 128, n0 = blockIdx.y * 64;
    int tid = threadIdx.x, tx = tid & 15, ty = tid >> 4;
    __shared__ __align__(16) float As[16][132];
    __shared__ __align__(16) float Ws0[16][68];
    __shared__ __align__(16) float Ws1[16][68];
    float acc_a[8][4] = {{0}};
    float acc_g[8][4] = {{0}};
    int lrow = tid >> 2, lcol = (tid & 3) * 4;
    const float* Ap = A + (size_t)(m0 + lrow) * K + lcol;
    const float* Ap2 = Ap + (size_t)64 * K;
    const float* Wp0 = W + (size_t)(n0 + lrow) * K + lcol;
    const float* Wp1 = GLU ? (W + (size_t)(Nout + n0 + lrow) * K + lcol) : W;
    for (int kt = 0; kt < K; kt += 16) {
        float4 av0 = *(const float4*)(Ap + kt);
        float4 av1 = *(const float4*)(Ap2 + kt);
        float4 wv0 = *(const float4*)(Wp0 + kt);
        float4 wv1 = make_float4(0, 0, 0, 0);
        if (GLU) wv1 = *(const float4*)(Wp1 + kt);
        __syncthreads();
        As[lcol + 0][lrow] = av0.x; As[lcol + 1][lrow] = av0.y;
        As[lcol + 2][lrow] = av0.z; As[lcol + 3][lrow] = av0.w;
        As[lcol + 0][lrow + 64] = av1.x; As[lcol + 1][lrow + 64] = av1.y;
        As[lcol + 2][lrow + 64] = av1.z; As[lcol + 3][lrow + 64] = av1.w;
        Ws0[lcol + 0][lrow] = wv0.x; Ws0[lcol + 1][lrow] = wv0.y;
        Ws0[lcol + 2][lrow] = wv0.z; Ws0[lcol + 3][lrow] = wv0.w;
        if (GLU) {
            Ws1[lcol + 0][lrow] = wv1.x; Ws1[lcol + 1][lrow] = wv1.y;
            Ws1[lcol + 2][lrow] = wv1.z; Ws1[lcol + 3][lrow] = wv1.w;
        }
        __syncthreads();
#pragma unroll
        for (int k = 0; k < 16; ++k) {
            float4 a0 = *(const float4*)&As[k][ty * 8];
            float4 a1 = *(const float4*)&As[k][ty * 8 + 4];
            float4 w0 = *(const float4*)&Ws0[k][tx * 4];
            float am[8] = {a0.x, a0.y, a0.z, a0.w, a1.x, a1.y, a1.z, a1.w};
            float wn[4] = {w0.x, w0.y, w0.z, w0.w};
#pragma unroll
            for (int mi = 0; mi < 8; ++mi)
#pragma unroll
                for (int ni = 0; ni < 4; ++ni)
                    acc_a[mi][ni] += am[mi] * wn[ni];
            if (GLU) {
                float4 w1v = *(const float4*)&Ws1[k][tx * 4];
                float wg[4] = {w1v.x, w1v.y, w1v.z, w1v.w};
#pragma unroll
                for (int mi = 0; mi < 8; ++mi)
#pragma unroll
                    for (int ni = 0; ni < 4; ++ni)
                        acc_g[mi][ni] += am[mi] * wg[ni];
            }
        }
    }
    int col = n0 + tx * 4;
    if (GLU) {
        float4 ba = *(const float4*)&bias[col];
        float4 bg = *(const float4*)&bias[Nout + col];
#pragma unroll
        for (int mi = 0; mi < 8; ++mi) {
            int row = m0 + ty * 8 + mi;
            float4 o;
            o.x = geluf_(acc_a[mi][0] + ba.x) * sigmoidf_(acc_g[mi][0] + bg.x);
            o.y = geluf_(acc_a[mi][1] + ba.y) * sigmoidf_(acc_g[mi][1] + bg.y);
            o.z = geluf_(acc_a[mi][2] + ba.z) * sigmoidf_(acc_g[mi][2] + bg.z);
            o.w = geluf_(acc_a[mi][3] + ba.w) * sigmoidf_(acc_g[mi][3] + bg.w);
            *(float4*)&Cout[(size_t)row * Nout + col] = o;
        }
    } else {
        float4 ba = *(const float4*)&bias[col];
#pragma unroll
        for (int mi = 0; mi < 8; ++mi) {
            int row = m0 + ty * 8 + mi;
            float4 o;
            o.x = acc_a[mi][0] + ba.x; o.y = acc_a[mi][1] + ba.y;
            o.z = acc_a[mi][2] + ba.z; o.w = acc_a[mi][3] + ba.w;
            *(float4*)&Cout[(size_t)row * Nout + col] = o;
        }
    }
}

// ---------------------------------------------------------------------------
// fuse2: z2 = LN(y1+z, mixn); out = LN(y1+z2, n2). One row per block.
// ---------------------------------------------------------------------------
__global__ __launch_bounds__(128) void fuse2_kernel(const float* __restrict__ y1,
                                                    const float* __restrict__ z,
                                                    const float* __restrict__ mg,
                                                    const float* __restrict__ mb,
                                                    const float* __restrict__ g2,
                                                    const float* __restrict__ b2v,
                                                    float* __restrict__ out) {
    int row = blockIdx.x, tid = threadIdx.x, c = tid * 4;
    __shared__ float r1[2], r2[2];
    float4 a = *(const float4*)&y1[(size_t)row * 512 + c];
    float4 zv = *(const float4*)&z[(size_t)row * 512 + c];
    float4 t1;
    t1.x = a.x + zv.x; t1.y = a.y + zv.y; t1.z = a.z + zv.z; t1.w = a.w + zv.w;
    float s1 = t1.x + t1.y + t1.z + t1.w;
    float s2 = t1.x * t1.x + t1.y * t1.y + t1.z * t1.z + t1.w * t1.w;
#pragma unroll
    for (int off = 32; off > 0; off >>= 1) {
        s1 += __shfl_down(s1, off, 64);
        s2 += __shfl_down(s2, off, 64);
    }
    if ((tid & 63) == 0) { r1[tid >> 6] = s1; r2[tid >> 6] = s2; }
    __syncthreads();
    float mean = (r1[0] + r1[1]) * (1.0f / 512.0f);
    float var = (r2[0] + r2[1]) * (1.0f / 512.0f) - mean * mean;
    float rstd = rsqrtf(var + 1e-5f);
    float4 mg4 = *(const float4*)&mg[c];
    float4 mb4 = *(const float4*)&mb[c];
    float4 t2;
    t2.x = a.x + ((t1.x - mean) * rstd * mg4.x + mb4.x);
    t2.y = a.y + ((t1.y - mean) * rstd * mg4.y + mb4.y);
    t2.z = a.z + ((t1.z - mean) * rstd * mg4.z + mb4.z);
    t2.w = a.w + ((t1.w - mean) * rstd * mg4.w + mb4.w);
    __syncthreads();  // protect r1/r2 reuse
    s1 = t2.x + t2.y + t2.z + t2.w;
    s2 = t2.x * t2.x + t2.y * t2.y + t2.z * t2.z + t2.w * t2.w;
#pragma unroll
    for (int off = 32; off > 0; off >>= 1) {
        s1 += __shfl_down(s1, off, 64);
        s2 += __shfl_down(s2, off, 64);
    }
    if ((tid & 63) == 0) { r1[tid >> 6] = s1; r2[tid >> 6] = s2; }
    __syncthreads();
    float mean2 = (r1[0] + r1[1]) * (1.0f / 512.0f);
    float var2 = (r2[0] + r2[1]) * (1.0f / 512.0f) - mean2 * mean2;
    float rstd2 = rsqrtf(var2 + 1e-5f);
    float4 gg = *(const float4*)&g2[c];
    float4 bb = *(const float4*)&b2v[c];
    float4 o;
    o.x = (t2.x - mean2) * rstd2 * gg.x + bb.x;
    o.y = (t2.y - mean2) * rstd2 * gg.y + bb.y;
    o.z = (t2.z - mean2) * rstd2 * gg.z + bb.z;
    o.w = (t2.w - mean2) * rstd2 * gg.w + bb.w;
    *(float4*)&out[(size_t)row * 512 + c] = o;
}

// ---------------------------------------------------------------------------
// Workspace layout (floats). Total 19,570,752 floats = ~78.3 MB.
// act (8.4M) aliases xT+y, both dead by the time GEMM1 runs.
// ---------------------------------------------------------------------------
extern "C" void kernel_launch(void* const* d_in, const int* in_sizes, int n_in,
                              void* d_out, int out_size, void* d_ws, size_t ws_size,
                              hipStream_t stream) {
    (void)in_sizes; (void)n_in; (void)out_size; (void)ws_size;
    const float* x      = (const float*)d_in[0];
    const float* Bp     = (const float*)d_in[1];
    const float* Cp     = (const float*)d_in[2];
    const float* Dp     = (const float*)d_in[3];
    const float* log_dt = (const float*)d_in[4];
    const float* se_w1  = (const float*)d_in[5];
    const float* se_b1  = (const float*)d_in[6];
    const float* se_w2  = (const float*)d_in[7];
    const float* se_b2  = (const float*)d_in[8];
    const float* n1g    = (const float*)d_in[9];
    const float* n1b    = (const float*)d_in[10];
    const float* up_w   = (const float*)d_in[11];
    const float* up_b   = (const float*)d_in[12];
    const float* dn_w   = (const float*)d_in[13];
    const float* dn_b   = (const float*)d_in[14];
    const float* mxg    = (const float*)d_in[15];
    const float* mxb    = (const float*)d_in[16];
    const float* n2g    = (const float*)d_in[17];
    const float* n2b    = (const float*)d_in[18];

    float* ws    = (float*)d_ws;
    float* Kr    = ws + 0;         //   524288
    float* AbarT = ws + 524288;    //    16384
    float* A32   = ws + 540672;    //    16384
    float* Bbar  = ws + 557056;    //   131072
    float* dtb   = ws + 688128;    //       64
    float* Kpart = ws + 688192;    //  2097152
    float* xT    = ws + 2785344;   //  4194304
    float* yb    = ws + 6979648;   //  4194304
    float* ssum  = ws + 11173952;  //     4096
    float* gbuf  = ws + 11178048;  //     4096
    float* y1    = ws + 11182144;  //  4194304
    float* zb    = ws + 15376448;  //  4194304
    float* act   = ws + 2785344;   //  8388608 (alias over xT + y)
    float* outp  = (float*)d_out;

    hipLaunchKernelGGL(prep_comp, dim3(4), dim3(256), 0, stream, log_dt, AbarT, A32, dtb);
    hipLaunchKernelGGL(compute_bbar, dim3(8), dim3(256), 0, stream, Bp, dtb, Bbar);
    hipLaunchKernelGGL(compute_K, dim3(512, 4), dim3(256), 0, stream, Cp, Bbar, AbarT, A32, Dp, Kpart);
    hipLaunchKernelGGL(reduce_K, dim3(2048), dim3(256), 0, stream, Kpart, Kr);
    hipLaunchKernelGGL(transpose_x, dim3(32, 16, 8), dim3(256), 0, stream, x, xT);
    hipLaunchKernelGGL(conv_kernel, dim3(4096), dim3(64), 0, stream, xT, Kr, yb, ssum);
    hipLaunchKernelGGL(se_kernel, dim3(8), dim3(256), 0, stream, ssum, se_w1, se_b1, se_w2, se_b2, gbuf);
    hipLaunchKernelGGL(fuse1_kernel, dim3(8192), dim3(128), 0, stream, x, yb, gbuf, n1g, n1b, y1);
    hipLaunchKernelGGL((gemm_bt<true>), dim3(64, 16), dim3(256), 0, stream, y1, up_w, up_b, act, 512, 1024);
    hipLaunchKernelGGL((gemm_bt<false>), dim3(64, 8), dim3(256), 0, stream, act, dn_w, dn_b, zb, 1024, 512);
    hipLaunchKernelGGL(fuse2_kernel, dim3(8192), dim3(128), 0, stream, y1, zb, mxg, mxb, n2g, n2b, outp);
}

// Round 2
// 595.847 us; speedup vs baseline: 1.4326x; 1.4326x over previous
//
#include <hip/hip_runtime.h>
#include <math.h>

// Sizes: B=8, L=1024, D=512, N=64, NC=4, HIDDEN=1024, up rows=2048, R=64

typedef short bf16x8 __attribute__((ext_vector_type(8)));
typedef float f32x4 __attribute__((ext_vector_type(4)));

__device__ __forceinline__ float sigmoidf_(float x) { return 1.0f / (1.0f + expf(-x)); }
__device__ __forceinline__ float geluf_(float x) { return 0.5f * x * (1.0f + erff(x * 0.70710678118654752f)); }
__device__ __forceinline__ unsigned short f2bf(float f) {
    unsigned u = __float_as_uint(f);
    unsigned r = (u + 0x7FFFu + ((u >> 16) & 1u)) >> 16;
    return (unsigned short)r;
}

// ---------------------------------------------------------------------------
// P1: per-component A_bar (forward-substitution; lhs lower-triangular) and
// A32 = A_bar^32 via 5 squarings. AbarT stored transposed.
// ---------------------------------------------------------------------------
__global__ __launch_bounds__(256) void prep_comp(const float* __restrict__ log_dt,
                                                 float* __restrict__ AbarT,
                                                 float* __restrict__ A32,
                                                 float* __restrict__ dtbuf) {
    int comp = blockIdx.x, tid = threadIdx.x;
    __shared__ float sq[64];
    __shared__ float M1[4096];
    __shared__ float M2[4096];
    float ldt = log_dt[comp];
    float dt = log1pf(expf(ldt)) + 1e-6f;
    if (tid < 64) sq[tid] = sqrtf(2.0f * tid + 1.0f);
    __syncthreads();
    if (tid < 64) {
        int j = tid;
        float hdt = 0.5f * dt;
        for (int i = 0; i < j; ++i) M1[i * 64 + j] = 0.0f;
        for (int i = j; i < 64; ++i) {
            float r = (i == j) ? (1.0f - hdt * (float)(j + 1)) : (-hdt * sq[i] * sq[j]);
            for (int k = j; k < i; ++k) r -= hdt * sq[i] * sq[k] * M1[k * 64 + j];
            M1[i * 64 + j] = r / (1.0f + hdt * (float)(i + 1));
        }
    }
    __syncthreads();
    for (int idx = tid; idx < 4096; idx += 256) {
        int k = idx >> 6, i = idx & 63;
        AbarT[comp * 4096 + idx] = M1[i * 64 + k];
    }
    float* cur = M1;
    float* nxt = M2;
    for (int s = 0; s < 5; ++s) {
        __syncthreads();
        for (int idx = tid; idx < 4096; idx += 256) {
            int i = idx >> 6, j = idx & 63;
            float acc = 0.0f;
            for (int k = j; k <= i; ++k) acc += cur[i * 64 + k] * cur[k * 64 + j];
            nxt[idx] = acc;
        }
        float* t = cur; cur = nxt; nxt = t;
    }
    __syncthreads();
    for (int idx = tid; idx < 4096; idx += 256) A32[comp * 4096 + idx] = cur[idx];
    if (tid == 0) dtbuf[comp] = dt;
}

__global__ __launch_bounds__(256) void compute_bbar(const float* __restrict__ Bp,
                                                    const float* __restrict__ dtbuf,
                                                    float* __restrict__ Bbar) {
    int gid = blockIdx.x * 256 + threadIdx.x;
    int comp = gid >> 9;
    __shared__ float sq[64];
    if (threadIdx.x < 64) sq[threadIdx.x] = sqrtf(2.0f * threadIdx.x + 1.0f);
    __syncthreads();
    float dt = dtbuf[comp];
    float hdt = 0.5f * dt;
    const float* bp = Bp + (size_t)gid * 64;
    float y[64];
#pragma unroll
    for (int i = 0; i < 64; ++i) {
        float s = dt * bp[i];
        float fi = hdt * sq[i];
#pragma unroll
        for (int k = 0; k < i; ++k) s -= fi * sq[k] * y[k];
        y[i] = s / (1.0f + hdt * (float)(i + 1));
    }
    float* out = Bbar + (size_t)gid * 64;
#pragma unroll
    for (int i = 0; i < 64; ++i) out[i] = y[i];
}

__global__ __launch_bounds__(256) void compute_K(const float* __restrict__ Cp,
                                                 const float* __restrict__ Bbar,
                                                 const float* __restrict__ AbarT,
                                                 const float* __restrict__ A32,
                                                 const float* __restrict__ Dp,
                                                 float* __restrict__ Kpart) {
    int d = blockIdx.x, comp = blockIdx.y, tid = threadIdx.x;
    __shared__ float Ms1[64 * 65];
    __shared__ float Ms2[64 * 65];
    __shared__ float uvv[32 * 65];
    __shared__ float uvu[32 * 65];
    for (int idx = tid; idx < 4096; idx += 256) {
        int k = idx >> 6, i = idx & 63;
        Ms1[k * 65 + i] = AbarT[comp * 4096 + idx];
        Ms2[k * 65 + i] = A32[comp * 4096 + idx];
    }
    if (tid < 64) {
        uvv[tid] = Bbar[((size_t)comp * 512 + d) * 64 + tid];
        uvu[tid] = Cp[((size_t)comp * 512 + d) * 64 + tid];
    }
    __syncthreads();
    int half = tid >> 7, hh = tid & 1, idx = (tid >> 1) & 63;
    for (int r = 1; r < 32; ++r) {
        float s = 0.0f;
        if (half == 0) {
            int i = idx;
            int k0 = hh * 32, k1 = min(k0 + 32, i + 1);
            for (int k = k0; k < k1; ++k) s += Ms1[k * 65 + i] * uvv[(r - 1) * 65 + k];
        } else {
            int n = idx;
            int m0 = max(hh * 32, n), m1 = hh * 32 + 32;
            for (int m = m0; m < m1; ++m) s += Ms2[m * 65 + n] * uvu[(r - 1) * 65 + m];
        }
        s += __shfl_xor(s, 1, 64);
        if (hh == 0) {
            if (half == 0) uvv[r * 65 + idx] = s;
            else uvu[r * 65 + idx] = s;
        }
        __syncthreads();
    }
    float dval = Dp[comp * 512 + d];
    int l0 = tid * 4;
    float ov[4];
#pragma unroll
    for (int j = 0; j < 4; ++j) {
        int l = l0 + j, q = l >> 5, rr = l & 31;
        float s = 0.0f;
#pragma unroll 8
        for (int n = 0; n < 64; ++n) s += uvu[q * 65 + n] * uvv[rr * 65 + n];
        if (l == 0) s += dval;
        ov[j] = s;
    }
    float4 o; o.x = ov[0]; o.y = ov[1]; o.z = ov[2]; o.w = ov[3];
    *(float4*)&Kpart[((size_t)comp * 512 + d) * 1024 + l0] = o;
}

__global__ __launch_bounds__(256) void reduce_K(const float* __restrict__ Kpart,
                                                float* __restrict__ Kr) {
    int idx = blockIdx.x * 256 + threadIdx.x;
    int d = idx >> 10, l = idx & 1023;
    float s = Kpart[idx] + Kpart[524288 + idx] + Kpart[2 * 524288 + idx] + Kpart[3 * 524288 + idx];
    Kr[(size_t)d * 1024 + (1023 - l)] = s;
}

__global__ __launch_bounds__(256) void transpose_x(const float* __restrict__ x,
                                                   float* __restrict__ xT) {
    __shared__ float tile[32][33];
    int t0 = blockIdx.x * 32, c0 = blockIdx.y * 32, b = blockIdx.z;
    int tx = threadIdx.x & 31, ty = threadIdx.x >> 5;
#pragma unroll
    for (int m = 0; m < 4; ++m)
        tile[ty + 8 * m][tx] = x[((size_t)b * 1024 + t0 + ty + 8 * m) * 512 + c0 + tx];
    __syncthreads();
#pragma unroll
    for (int m = 0; m < 4; ++m)
        xT[((size_t)b * 512 + c0 + ty + 8 * m) * 1024 + t0 + tx] = tile[tx][ty + 8 * m];
}

__global__ __launch_bounds__(64) void conv_kernel(const float* __restrict__ xT,
                                                  const float* __restrict__ Kr,
                                                  float* __restrict__ y,
                                                  float* __restrict__ ssum) {
    int bc = blockIdx.x, b = bc >> 9, c = bc & 511, tid = threadIdx.x;
    __shared__ __align__(16) float xss[1032];
    __shared__ __align__(16) float ks[1024];
    float* xs = xss + 8;
    for (int j = tid * 4; j < 1024; j += 256) {
        *(float4*)&xs[j] = *(const float4*)&xT[(size_t)bc * 1024 + j];
        *(float4*)&ks[j] = *(const float4*)&Kr[(size_t)c * 1024 + j];
    }
    if (tid < 8) xss[tid] = 0.0f;
    __syncthreads();
    float total = 0.0f;
    for (int oc = 0; oc < 2; ++oc) {
        int o = (oc == 0) ? tid : (127 - tid);
        int base = o * 8;
        float4 b0 = *(const float4*)&xs[base];
        float4 b1 = *(const float4*)&xs[base + 4];
        float h[8] = {b0.x, b0.y, b0.z, b0.w, b1.x, b1.y, b1.z, b1.w};
        float acc[8] = {0, 0, 0, 0, 0, 0, 0, 0};
        for (int s0 = 0; s0 <= base; s0 += 8) {
            float4 a0 = *(const float4*)&xs[base - s0 - 8];
            float4 a1 = *(const float4*)&xs[base - s0 - 4];
            float4 k0 = *(const float4*)&ks[s0];
            float4 k1 = *(const float4*)&ks[s0 + 4];
            float xw[16] = {a0.x, a0.y, a0.z, a0.w, a1.x, a1.y, a1.z, a1.w,
                            h[0], h[1], h[2], h[3], h[4], h[5], h[6], h[7]};
            float kk[8] = {k0.x, k0.y, k0.z, k0.w, k1.x, k1.y, k1.z, k1.w};
#pragma unroll
            for (int ss = 0; ss < 8; ++ss)
#pragma unroll
                for (int j = 0; j < 8; ++j)
                    acc[j] += kk[ss] * xw[8 + j - ss];
#pragma unroll
            for (int p = 0; p < 8; ++p) h[p] = xw[p];
        }
#pragma unroll
        for (int j = 0; j < 8; ++j) {
            y[((size_t)b * 1024 + base + j) * 512 + c] = acc[j];
            total += acc[j];
        }
    }
#pragma unroll
    for (int off = 32; off > 0; off >>= 1) total += __shfl_down(total, off, 64);
    if (tid == 0) ssum[bc] = total;
}

__global__ __launch_bounds__(256) void se_kernel(const float* __restrict__ ssum,
                                                 const float* __restrict__ w1,
                                                 const float* __restrict__ b1,
                                                 const float* __restrict__ w2,
                                                 const float* __restrict__ b2,
                                                 float* __restrict__ g) {
    int b = blockIdx.x, tid = threadIdx.x;
    __shared__ float s_sh[512];
    __shared__ float part[256];
    __shared__ float h_sh[64];
    for (int c = tid; c < 512; c += 256) s_sh[c] = ssum[b * 512 + c] * (1.0f / 1024.0f);
    __syncthreads();
    int r = tid & 63, seg = tid >> 6;
    float p = 0.0f;
    for (int c = seg * 128; c < seg * 128 + 128; ++c) p += s_sh[c] * w1[r * 512 + c];
    part[tid] = p;
    __syncthreads();
    if (tid < 64) {
        float h = part[tid] + part[tid + 64] + part[tid + 128] + part[tid + 192] + b1[tid];
        h_sh[tid] = fmaxf(h, 0.0f);
    }
    __syncthreads();
    for (int c = tid; c < 512; c += 256) {
        float acc = b2[c];
#pragma unroll 8
        for (int rr = 0; rr < 64; ++rr) acc += h_sh[rr] * w2[c * 64 + rr];
        g[b * 512 + c] = 1.0f / (1.0f + expf(-acc));
    }
}

// fuse1: y1 = LN(x + y*g); writes f32 y1 AND bf16 y1b (GEMM1 input).
__global__ __launch_bounds__(128) void fuse1_kernel(const float* __restrict__ x,
                                                    const float* __restrict__ y,
                                                    const float* __restrict__ g,
                                                    const float* __restrict__ n1g,
                                                    const float* __restrict__ n1b,
                                                    float* __restrict__ y1,
                                                    unsigned short* __restrict__ y1b) {
    int row = blockIdx.x, b = row >> 10, tid = threadIdx.x, c = tid * 4;
    __shared__ float r1[2], r2[2];
    float4 xv = *(const float4*)&x[(size_t)row * 512 + c];
    float4 yv = *(const float4*)&y[(size_t)row * 512 + c];
    float4 gv = *(const float4*)&g[b * 512 + c];
    float4 v;
    v.x = xv.x + yv.x * gv.x; v.y = xv.y + yv.y * gv.y;
    v.z = xv.z + yv.z * gv.z; v.w = xv.w + yv.w * gv.w;
    float s1 = v.x + v.y + v.z + v.w;
    float s2 = v.x * v.x + v.y * v.y + v.z * v.z + v.w * v.w;
#pragma unroll
    for (int off = 32; off > 0; off >>= 1) {
        s1 += __shfl_down(s1, off, 64);
        s2 += __shfl_down(s2, off, 64);
    }
    if ((tid & 63) == 0) { r1[tid >> 6] = s1; r2[tid >> 6] = s2; }
    __syncthreads();
    float mean = (r1[0] + r1[1]) * (1.0f / 512.0f);
    float var = (r2[0] + r2[1]) * (1.0f / 512.0f) - mean * mean;
    float rstd = rsqrtf(var + 1e-5f);
    float4 g4 = *(const float4*)&n1g[c];
    float4 b4 = *(const float4*)&n1b[c];
    float4 o;
    o.x = (v.x - mean) * rstd * g4.x + b4.x; o.y = (v.y - mean) * rstd * g4.y + b4.y;
    o.z = (v.z - mean) * rstd * g4.z + b4.z; o.w = (v.w - mean) * rstd * g4.w + b4.w;
    *(float4*)&y1[(size_t)row * 512 + c] = o;
    uint2 pk;
    pk.x = (unsigned)f2bf(o.x) | ((unsigned)f2bf(o.y) << 16);
    pk.y = (unsigned)f2bf(o.z) | ((unsigned)f2bf(o.w) << 16);
    *(uint2*)&y1b[(size_t)row * 512 + c] = pk;
}

// f32 -> bf16 (RNE), 8 elems/thread.
__global__ __launch_bounds__(256) void f32_to_bf16(const float* __restrict__ in,
                                                   unsigned short* __restrict__ out,
                                                   int n8) {
    int i = blockIdx.x * 256 + threadIdx.x;
    if (i >= n8) return;
    float4 a = ((const float4*)in)[2 * i];
    float4 b = ((const float4*)in)[2 * i + 1];
    uint4 o;
    o.x = (unsigned)f2bf(a.x) | ((unsigned)f2bf(a.y) << 16);
    o.y = (unsigned)f2bf(a.z) | ((unsigned)f2bf(a.w) << 16);
    o.z = (unsigned)f2bf(b.x) | ((unsigned)f2bf(b.y) << 16);
    o.w = (unsigned)f2bf(b.z) | ((unsigned)f2bf(b.w) << 16);
    *(uint4*)&out[(size_t)i * 8] = o;
}

__device__ __forceinline__ int swz_slot(int slot, int row) {
    return slot ^ (row & 3) ^ ((row >> 2) & 3);
}

// ---------------------------------------------------------------------------
// GEMM1 + GLU (bf16 MFMA). BM=128, out cols 64/block; B-tile holds the 64 'a'
// rows and 64 'g' rows of up_w so GLU combines in-register.
// acc: 2 row-frags x 4 col-frags x {a,g}. 16 MFMA + 10 ds_read_b128 per K-step.
// ---------------------------------------------------------------------------
__global__ __launch_bounds__(256) void gemm_glu(const unsigned short* __restrict__ A,
                                                const unsigned short* __restrict__ W,
                                                const float* __restrict__ bias,
                                                unsigned short* __restrict__ act) {
    const int K = 512;
    int m0 = blockIdx.x * 128, n0 = blockIdx.y * 64;
    int tid = threadIdx.x, w = tid >> 6, l = tid & 63;
    __shared__ short As[4096];
    __shared__ short Bs[4096];
    // staging: chunk ids tid, tid+256 for each of A,B
    int idA0 = tid, idA1 = tid + 256;
    int rA0 = idA0 >> 2, sA0 = idA0 & 3, rA1 = idA1 >> 2, sA1 = idA1 & 3;
    int ldsA0 = rA0 * 32 + swz_slot(sA0, rA0) * 8;
    int ldsA1 = rA1 * 32 + swz_slot(sA1, rA1) * 8;
    const unsigned short* pA0 = A + (size_t)(m0 + rA0) * K + sA0 * 8;
    const unsigned short* pA1 = A + (size_t)(m0 + rA1) * K + sA1 * 8;
    int gB0 = (rA0 < 64) ? (n0 + rA0) : (1024 + n0 + rA0 - 64);
    int gB1 = (rA1 < 64) ? (n0 + rA1) : (1024 + n0 + rA1 - 64);
    const unsigned short* pB0 = W + (size_t)gB0 * K + sA0 * 8;
    const unsigned short* pB1 = W + (size_t)gB1 * K + sA1 * 8;
    // fragment LDS offsets (short units), fixed across K
    int p = l >> 4, lr = l & 15;
    int aoff[2], bAoff[4], bGoff[4];
#pragma unroll
    for (int rt = 0; rt < 2; ++rt) {
        int r = w * 32 + rt * 16 + lr;
        aoff[rt] = r * 32 + swz_slot(p, r) * 8;
    }
#pragma unroll
    for (int ct = 0; ct < 4; ++ct) {
        int ca = ct * 16 + lr, cg = 64 + ct * 16 + lr;
        bAoff[ct] = ca * 32 + swz_slot(p, ca) * 8;
        bGoff[ct] = cg * 32 + swz_slot(p, cg) * 8;
    }
    f32x4 accA[2][4], accG[2][4];
#pragma unroll
    for (int rt = 0; rt < 2; ++rt)
#pragma unroll
        for (int ct = 0; ct < 4; ++ct) {
            accA[rt][ct] = (f32x4)0.0f;
            accG[rt][ct] = (f32x4)0.0f;
        }
    for (int kt = 0; kt < K; kt += 32) {
        uint4 va0 = *(const uint4*)pA0;
        uint4 va1 = *(const uint4*)pA1;
        uint4 vb0 = *(const uint4*)pB0;
        uint4 vb1 = *(const uint4*)pB1;
        __syncthreads();
        *(uint4*)&As[ldsA0] = va0;
        *(uint4*)&As[ldsA1] = va1;
        *(uint4*)&Bs[ldsA0] = vb0;
        *(uint4*)&Bs[ldsA1] = vb1;
        __syncthreads();
        bf16x8 af[2], bA[4], bG[4];
#pragma unroll
        for (int rt = 0; rt < 2; ++rt) af[rt] = *(bf16x8*)&As[aoff[rt]];
#pragma unroll
        for (int ct = 0; ct < 4; ++ct) {
            bA[ct] = *(bf16x8*)&Bs[bAoff[ct]];
            bG[ct] = *(bf16x8*)&Bs[bGoff[ct]];
        }
#pragma unroll
        for (int rt = 0; rt < 2; ++rt)
#pragma unroll
            for (int ct = 0; ct < 4; ++ct) {
                accA[rt][ct] = __builtin_amdgcn_mfma_f32_16x16x32_bf16(af[rt], bA[ct], accA[rt][ct], 0, 0, 0);
                accG[rt][ct] = __builtin_amdgcn_mfma_f32_16x16x32_bf16(af[rt], bG[ct], accG[rt][ct], 0, 0, 0);
            }
        pA0 += 32; pA1 += 32; pB0 += 32; pB1 += 32;
    }
#pragma unroll
    for (int rt = 0; rt < 2; ++rt)
#pragma unroll
        for (int ct = 0; ct < 4; ++ct) {
            int col = n0 + ct * 16 + lr;
            float ba = bias[col], bg = bias[1024 + col];
#pragma unroll
            for (int reg = 0; reg < 4; ++reg) {
                int row = m0 + w * 32 + rt * 16 + p * 4 + reg;
                float a = accA[rt][ct][reg] + ba;
                float g = accG[rt][ct][reg] + bg;
                act[(size_t)row * 1024 + col] = f2bf(geluf_(a) * sigmoidf_(g));
            }
        }
}

// ---------------------------------------------------------------------------
// GEMM2 (bf16 MFMA, m97-style): BM=128, BN=128, 2x2 waves, 4x4 frags.
// C = A @ W^T + bias, f32 out.
// ---------------------------------------------------------------------------
__global__ __launch_bounds__(256) void gemm_plain(const unsigned short* __restrict__ A,
                                                  const unsigned short* __restrict__ W,
                                                  const float* __restrict__ bias,
                                                  float* __restrict__ Cout) {
    const int K = 1024, N = 512;
    int m0 = blockIdx.x * 128, n0 = blockIdx.y * 128;
    int tid = threadIdx.x, w = tid >> 6, l = tid & 63;
    int wr = w >> 1, wc = w & 1;
    __shared__ short As[4096];
    __shared__ short Bs[4096];
    int idA0 = tid, idA1 = tid + 256;
    int rA0 = idA0 >> 2, sA0 = idA0 & 3, rA1 = idA1 >> 2, sA1 = idA1 & 3;
    int ldsA0 = rA0 * 32 + swz_slot(sA0, rA0) * 8;
    int ldsA1 = rA1 * 32 + swz_slot(sA1, rA1) * 8;
    const unsigned short* pA0 = A + (size_t)(m0 + rA0) * K + sA0 * 8;
    const unsigned short* pA1 = A + (size_t)(m0 + rA1) * K + sA1 * 8;
    const unsigned short* pB0 = W + (size_t)(n0 + rA0) * K + sA0 * 8;
    const unsigned short* pB1 = W + (size_t)(n0 + rA1) * K + sA1 * 8;
    int p = l >> 4, lr = l & 15;
    int aoff[4], boff[4];
#pragma unroll
    for (int t = 0; t < 4; ++t) {
        int r = wr * 64 + t * 16 + lr;
        aoff[t] = r * 32 + swz_slot(p, r) * 8;
        int c = wc * 64 + t * 16 + lr;
        boff[t] = c * 32 + swz_slot(p, c) * 8;
    }
    f32x4 acc[4][4];
#pragma unroll
    for (int i = 0; i < 4; ++i)
#pragma unroll
        for (int j = 0; j < 4; ++j) acc[i][j] = (f32x4)0.0f;
    for (int kt = 0; kt < K; kt += 32) {
        uint4 va0 = *(const uint4*)pA0;
        uint4 va1 = *(const uint4*)pA1;
        uint4 vb0 = *(const uint4*)pB0;
        uint4 vb1 = *(const uint4*)pB1;
        __syncthreads();
        *(uint4*)&As[ldsA0] = va0;
        *(uint4*)&As[ldsA1] = va1;
        *(uint4*)&Bs[ldsA0] = vb0;
        *(uint4*)&Bs[ldsA1] = vb1;
        __syncthreads();
        bf16x8 af[4], bf[4];
#pragma unroll
        for (int t = 0; t < 4; ++t) {
            af[t] = *(bf16x8*)&As[aoff[t]];
            bf[t] = *(bf16x8*)&Bs[boff[t]];
        }
#pragma unroll
        for (int i = 0; i < 4; ++i)
#pragma unroll
            for (int j = 0; j < 4; ++j)
                acc[i][j] = __builtin_amdgcn_mfma_f32_16x16x32_bf16(af[i], bf[j], acc[i][j], 0, 0, 0);
        pA0 += 32; pA1 += 32; pB0 += 32; pB1 += 32;
    }
#pragma unroll
    for (int i = 0; i < 4; ++i)
#pragma unroll
        for (int j = 0; j < 4; ++j) {
            int col = n0 + wc * 64 + j * 16 + lr;
            float bb = bias[col];
#pragma unroll
            for (int reg = 0; reg < 4; ++reg) {
                int row = m0 + wr * 64 + i * 16 + p * 4 + reg;
                Cout[(size_t)row * N + col] = acc[i][j][reg] + bb;
            }
        }
}

__global__ __launch_bounds__(128) void fuse2_kernel(const float* __restrict__ y1,
                                                    const float* __restrict__ z,
                                                    const float* __restrict__ mg,
                                                    const float* __restrict__ mb,
                                                    const float* __restrict__ g2,
                                                    const float* __restrict__ b2v,
                                                    float* __restrict__ out) {
    int row = blockIdx.x, tid = threadIdx.x, c = tid * 4;
    __shared__ float r1[2], r2[2];
    float4 a = *(const float4*)&y1[(size_t)row * 512 + c];
    float4 zv = *(const float4*)&z[(size_t)row * 512 + c];
    float4 t1;
    t1.x = a.x + zv.x; t1.y = a.y + zv.y; t1.z = a.z + zv.z; t1.w = a.w + zv.w;
    float s1 = t1.x + t1.y + t1.z + t1.w;
    float s2 = t1.x * t1.x + t1.y * t1.y + t1.z * t1.z + t1.w * t1.w;
#pragma unroll
    for (int off = 32; off > 0; off >>= 1) {
        s1 += __shfl_down(s1, off, 64);
        s2 += __shfl_down(s2, off, 64);
    }
    if ((tid & 63) == 0) { r1[tid >> 6] = s1; r2[tid >> 6] = s2; }
    __syncthreads();
    float mean = (r1[0] + r1[1]) * (1.0f / 512.0f);
    float var = (r2[0] + r2[1]) * (1.0f / 512.0f) - mean * mean;
    float rstd = rsqrtf(var + 1e-5f);
    float4 mg4 = *(const float4*)&mg[c];
    float4 mb4 = *(const float4*)&mb[c];
    float4 t2;
    t2.x = a.x + ((t1.x - mean) * rstd * mg4.x + mb4.x);
    t2.y = a.y + ((t1.y - mean) * rstd * mg4.y + mb4.y);
    t2.z = a.z + ((t1.z - mean) * rstd * mg4.z + mb4.z);
    t2.w = a.w + ((t1.w - mean) * rstd * mg4.w + mb4.w);
    __syncthreads();
    s1 = t2.x + t2.y + t2.z + t2.w;
    s2 = t2.x * t2.x + t2.y * t2.y + t2.z * t2.z + t2.w * t2.w;
#pragma unroll
    for (int off = 32; off > 0; off >>= 1) {
        s1 += __shfl_down(s1, off, 64);
        s2 += __shfl_down(s2, off, 64);
    }
    if ((tid & 63) == 0) { r1[tid >> 6] = s1; r2[tid >> 6] = s2; }
    __syncthreads();
    float mean2 = (r1[0] + r1[1]) * (1.0f / 512.0f);
    float var2 = (r2[0] + r2[1]) * (1.0f / 512.0f) - mean2 * mean2;
    float rstd2 = rsqrtf(var2 + 1e-5f);
    float4 gg = *(const float4*)&g2[c];
    float4 bb = *(const float4*)&b2v[c];
    float4 o;
    o.x = (t2.x - mean2) * rstd2 * gg.x + bb.x;
    o.y = (t2.y - mean2) * rstd2 * gg.y + bb.y;
    o.z = (t2.z - mean2) * rstd2 * gg.z + bb.z;
    o.w = (t2.w - mean2) * rstd2 * gg.w + bb.w;
    *(float4*)&out[(size_t)row * 512 + c] = o;
}

// ---------------------------------------------------------------------------
// Workspace (floats), total 19,570,752 = ~78.3 MB.
//   act(bf16, 8.4M shorts) aliases xT; y1b(bf16) aliases zb's head (zb written
//   after y1b's last read); up_wb/dn_wb alias Kpart (dead after reduce_K).
// ---------------------------------------------------------------------------
extern "C" void kernel_launch(void* const* d_in, const int* in_sizes, int n_in,
                              void* d_out, int out_size, void* d_ws, size_t ws_size,
                              hipStream_t stream) {
    (void)in_sizes; (void)n_in; (void)out_size; (void)ws_size;
    const float* x      = (const float*)d_in[0];
    const float* Bp     = (const float*)d_in[1];
    const float* Cp     = (const float*)d_in[2];
    const float* Dp     = (const float*)d_in[3];
    const float* log_dt = (const float*)d_in[4];
    const float* se_w1  = (const float*)d_in[5];
    const float* se_b1  = (const float*)d_in[6];
    const float* se_w2  = (const float*)d_in[7];
    const float* se_b2  = (const float*)d_in[8];
    const float* n1g    = (const float*)d_in[9];
    const float* n1b    = (const float*)d_in[10];
    const float* up_w   = (const float*)d_in[11];
    const float* up_b   = (const float*)d_in[12];
    const float* dn_w   = (const float*)d_in[13];
    const float* dn_b   = (const float*)d_in[14];
    const float* mxg    = (const float*)d_in[15];
    const float* mxb    = (const float*)d_in[16];
    const float* n2g    = (const float*)d_in[17];
    const float* n2b    = (const float*)d_in[18];

    float* ws    = (float*)d_ws;
    float* Kr    = ws + 0;         //   524288
    float* AbarT = ws + 524288;    //    16384
    float* A32   = ws + 540672;    //    16384
    float* Bbar  = ws + 557056;    //   131072
    float* dtb   = ws + 688128;    //       64
    float* Kpart = ws + 688192;    //  2097152
    float* xT    = ws + 2785344;   //  4194304
    float* yb    = ws + 6979648;   //  4194304
    float* ssum  = ws + 11173952;  //     4096
    float* gbuf  = ws + 11178048;  //     4096
    float* y1    = ws + 11182144;  //  4194304
    float* zb    = ws + 15376448;  //  4194304
    unsigned short* up_wb = (unsigned short*)(ws + 688192);   // aliases Kpart
    unsigned short* dn_wb = (unsigned short*)(ws + 1212480);  // aliases Kpart
    unsigned short* act   = (unsigned short*)(ws + 2785344);  // aliases xT
    unsigned short* y1b   = (unsigned short*)(ws + 15376448); // aliases zb head
    float* outp  = (float*)d_out;

    hipLaunchKernelGGL(prep_comp, dim3(4), dim3(256), 0, stream, log_dt, AbarT, A32, dtb);
    hipLaunchKernelGGL(compute_bbar, dim3(8), dim3(256), 0, stream, Bp, dtb, Bbar);
    hipLaunchKernelGGL(compute_K, dim3(512, 4), dim3(256), 0, stream, Cp, Bbar, AbarT, A32, Dp, Kpart);
    hipLaunchKernelGGL(reduce_K, dim3(2048), dim3(256), 0, stream, Kpart, Kr);
    hipLaunchKernelGGL(f32_to_bf16, dim3(512), dim3(256), 0, stream, up_w, up_wb, 131072);
    hipLaunchKernelGGL(f32_to_bf16, dim3(256), dim3(256), 0, stream, dn_w, dn_wb, 65536);
    hipLaunchKernelGGL(transpose_x, dim3(32, 16, 8), dim3(256), 0, stream, x, xT);
    hipLaunchKernelGGL(conv_kernel, dim3(4096), dim3(64), 0, stream, xT, Kr, yb, ssum);
    hipLaunchKernelGGL(se_kernel, dim3(8), dim3(256), 0, stream, ssum, se_w1, se_b1, se_w2, se_b2, gbuf);
    hipLaunchKernelGGL(fuse1_kernel, dim3(8192), dim3(128), 0, stream, x, yb, gbuf, n1g, n1b, y1, y1b);
    hipLaunchKernelGGL(gemm_glu, dim3(64, 16), dim3(256), 0, stream, y1b, up_wb, up_b, act);
    hipLaunchKernelGGL(gemm_plain, dim3(64, 4), dim3(256), 0, stream, act, dn_wb, dn_b, zb);
    hipLaunchKernelGGL(fuse2_kernel, dim3(8192), dim3(128), 0, stream, y1, zb, mxg, mxb, n2g, n2b, outp);
}

// Round 3
// 470.486 us; speedup vs baseline: 1.8143x; 1.2664x over previous
//
#include <hip/hip_runtime.h>
#include <math.h>

// Sizes: B=8, L=1024, D=512, N=64, NC=4, HIDDEN=1024, up rows=2048, R=64

typedef short bf16x8 __attribute__((ext_vector_type(8)));
typedef float f32x4 __attribute__((ext_vector_type(4)));

__device__ __forceinline__ float sigmoidf_(float x) { return 1.0f / (1.0f + expf(-x)); }
__device__ __forceinline__ float geluf_(float x) { return 0.5f * x * (1.0f + erff(x * 0.70710678118654752f)); }
__device__ __forceinline__ unsigned short f2bf(float f) {
    unsigned u = __float_as_uint(f);
    unsigned r = (u + 0x7FFFu + ((u >> 16) & 1u)) >> 16;
    return (unsigned short)r;
}
__device__ __forceinline__ unsigned pk2(unsigned short a, unsigned short b) {
    return (unsigned)a | ((unsigned)b << 16);
}

// ---------------------------------------------------------------------------
// P1: per-component A_bar (forward-substitution; lhs lower-triangular) and
// A32 = A_bar^32 via 5 squarings. AbarT stored transposed.
// ---------------------------------------------------------------------------
__global__ __launch_bounds__(256) void prep_comp(const float* __restrict__ log_dt,
                                                 float* __restrict__ AbarT,
                                                 float* __restrict__ A32,
                                                 float* __restrict__ dtbuf) {
    int comp = blockIdx.x, tid = threadIdx.x;
    __shared__ float sq[64];
    __shared__ float M1[4096];
    __shared__ float M2[4096];
    float ldt = log_dt[comp];
    float dt = log1pf(expf(ldt)) + 1e-6f;
    if (tid < 64) sq[tid] = sqrtf(2.0f * tid + 1.0f);
    __syncthreads();
    if (tid < 64) {
        int j = tid;
        float hdt = 0.5f * dt;
        for (int i = 0; i < j; ++i) M1[i * 64 + j] = 0.0f;
        for (int i = j; i < 64; ++i) {
            float r = (i == j) ? (1.0f - hdt * (float)(j + 1)) : (-hdt * sq[i] * sq[j]);
            for (int k = j; k < i; ++k) r -= hdt * sq[i] * sq[k] * M1[k * 64 + j];
            M1[i * 64 + j] = r / (1.0f + hdt * (float)(i + 1));
        }
    }
    __syncthreads();
    for (int idx = tid; idx < 4096; idx += 256) {
        int k = idx >> 6, i = idx & 63;
        AbarT[comp * 4096 + idx] = M1[i * 64 + k];
    }
    float* cur = M1;
    float* nxt = M2;
    for (int s = 0; s < 5; ++s) {
        __syncthreads();
        for (int idx = tid; idx < 4096; idx += 256) {
            int i = idx >> 6, j = idx & 63;
            float acc = 0.0f;
            for (int k = j; k <= i; ++k) acc += cur[i * 64 + k] * cur[k * 64 + j];
            nxt[idx] = acc;
        }
        float* t = cur; cur = nxt; nxt = t;
    }
    __syncthreads();
    for (int idx = tid; idx < 4096; idx += 256) A32[comp * 4096 + idx] = cur[idx];
    if (tid == 0) dtbuf[comp] = dt;
}

__global__ __launch_bounds__(256) void compute_bbar(const float* __restrict__ Bp,
                                                    const float* __restrict__ dtbuf,
                                                    float* __restrict__ Bbar) {
    int gid = blockIdx.x * 256 + threadIdx.x;
    int comp = gid >> 9;
    __shared__ float sq[64];
    if (threadIdx.x < 64) sq[threadIdx.x] = sqrtf(2.0f * threadIdx.x + 1.0f);
    __syncthreads();
    float dt = dtbuf[comp];
    float hdt = 0.5f * dt;
    const float* bp = Bp + (size_t)gid * 64;
    float y[64];
#pragma unroll
    for (int i = 0; i < 64; ++i) {
        float s = dt * bp[i];
        float fi = hdt * sq[i];
#pragma unroll
        for (int k = 0; k < i; ++k) s -= fi * sq[k] * y[k];
        y[i] = s / (1.0f + hdt * (float)(i + 1));
    }
    float* out = Bbar + (size_t)gid * 64;
#pragma unroll
    for (int i = 0; i < 64; ++i) out[i] = y[i];
}

__global__ __launch_bounds__(256) void compute_K(const float* __restrict__ Cp,
                                                 const float* __restrict__ Bbar,
                                                 const float* __restrict__ AbarT,
                                                 const float* __restrict__ A32,
                                                 const float* __restrict__ Dp,
                                                 float* __restrict__ Kpart) {
    int d = blockIdx.x, comp = blockIdx.y, tid = threadIdx.x;
    __shared__ float Ms1[64 * 65];
    __shared__ float Ms2[64 * 65];
    __shared__ float uvv[32 * 65];
    __shared__ float uvu[32 * 65];
    for (int idx = tid; idx < 4096; idx += 256) {
        int k = idx >> 6, i = idx & 63;
        Ms1[k * 65 + i] = AbarT[comp * 4096 + idx];
        Ms2[k * 65 + i] = A32[comp * 4096 + idx];
    }
    if (tid < 64) {
        uvv[tid] = Bbar[((size_t)comp * 512 + d) * 64 + tid];
        uvu[tid] = Cp[((size_t)comp * 512 + d) * 64 + tid];
    }
    __syncthreads();
    int half = tid >> 7, hh = tid & 1, idx = (tid >> 1) & 63;
    for (int r = 1; r < 32; ++r) {
        float s = 0.0f;
        if (half == 0) {
            int i = idx;
            int k0 = hh * 32, k1 = min(k0 + 32, i + 1);
            for (int k = k0; k < k1; ++k) s += Ms1[k * 65 + i] * uvv[(r - 1) * 65 + k];
        } else {
            int n = idx;
            int m0 = max(hh * 32, n), m1 = hh * 32 + 32;
            for (int m = m0; m < m1; ++m) s += Ms2[m * 65 + n] * uvu[(r - 1) * 65 + m];
        }
        s += __shfl_xor(s, 1, 64);
        if (hh == 0) {
            if (half == 0) uvv[r * 65 + idx] = s;
            else uvu[r * 65 + idx] = s;
        }
        __syncthreads();
    }
    float dval = Dp[comp * 512 + d];
    int l0 = tid * 4;
    float ov[4];
#pragma unroll
    for (int j = 0; j < 4; ++j) {
        int l = l0 + j, q = l >> 5, rr = l & 31;
        float s = 0.0f;
#pragma unroll 8
        for (int n = 0; n < 64; ++n) s += uvu[q * 65 + n] * uvv[rr * 65 + n];
        if (l == 0) s += dval;
        ov[j] = s;
    }
    float4 o; o.x = ov[0]; o.y = ov[1]; o.z = ov[2]; o.w = ov[3];
    *(float4*)&Kpart[((size_t)comp * 512 + d) * 1024 + l0] = o;
}

__global__ __launch_bounds__(256) void reduce_K(const float* __restrict__ Kpart,
                                                float* __restrict__ Kr) {
    int idx = blockIdx.x * 256 + threadIdx.x;
    int d = idx >> 10, l = idx & 1023;
    float s = Kpart[idx] + Kpart[524288 + idx] + Kpart[2 * 524288 + idx] + Kpart[3 * 524288 + idx];
    Kr[(size_t)d * 1024 + (1023 - l)] = s;
}

// Generic batched transpose: in [B][R][C] -> out [B][C][R]
__global__ __launch_bounds__(256) void transpose_bmat(const float* __restrict__ in,
                                                      float* __restrict__ out,
                                                      int R, int C) {
    __shared__ float tile[32][33];
    int r0 = blockIdx.x * 32, c0 = blockIdx.y * 32, b = blockIdx.z;
    int tx = threadIdx.x & 31, ty = threadIdx.x >> 5;
#pragma unroll
    for (int m = 0; m < 4; ++m)
        tile[ty + 8 * m][tx] = in[((size_t)b * R + r0 + ty + 8 * m) * C + c0 + tx];
    __syncthreads();
#pragma unroll
    for (int m = 0; m < 4; ++m)
        out[((size_t)b * C + c0 + ty + 8 * m) * R + r0 + tx] = tile[tx][ty + 8 * m];
}

// ---------------------------------------------------------------------------
// MFMA depthwise conv. Block = channel c. y[b,32q+r] = sum_dq sum_r'
// x[b,32(q-dq)+r'] * Kr[c][32dq + r - r'].  M=256 (m=q*8+b), N=32, K=32xdq.
// Toeplitz G built in LDS per 8-dq chunk from the Kr row; X and G as hi/lo
// bf16 (3-product MFMA ~ f32 accuracy). Writes yT[b][c][t] + ssum[b][c].
// ---------------------------------------------------------------------------
__global__ __launch_bounds__(256) void conv_mfma(const float* __restrict__ xT,
                                                 const float* __restrict__ Kr,
                                                 float* __restrict__ yT,
                                                 float* __restrict__ ssum) {
    int c = blockIdx.x, tid = threadIdx.x;
    int w = tid >> 6, l = tid & 63;
    __shared__ __align__(16) float krp[1088];          // Kr padded: krp[32+i]=Kr[i]
    __shared__ __align__(16) short xh[8512], xl[8512]; // 8 rows x 133 granules x 8
    __shared__ __align__(16) short gh[10240], gl[10240]; // 8dq x 32n x 5 gran x 8
    __shared__ float ssh[64];

    // Kr -> krp (1024 = 256*4), zero pads
    {
        float4 kv = *(const float4*)&Kr[(size_t)c * 1024 + tid * 4];
        *(float4*)&krp[32 + tid * 4] = kv;
        if (tid < 8) *(float4*)&krp[tid * 4] = make_float4(0, 0, 0, 0);
        else if (tid < 16) *(float4*)&krp[1056 + (tid - 8) * 4] = make_float4(0, 0, 0, 0);
    }
    // zero the t in [-32,0) granules
    if (tid < 32) {
        int b = tid >> 2, g = tid & 3;
        uint4 z = {0, 0, 0, 0};
        *(uint4*)&xh[(b * 133 + g) * 8] = z;
    } else if (tid < 64) {
        int t2 = tid - 32; int b = t2 >> 2, g = t2 & 3;
        uint4 z = {0, 0, 0, 0};
        *(uint4*)&xl[(b * 133 + g) * 8] = z;
    }
    // stage X hi/lo: 1024 data granules
#pragma unroll
    for (int i = 0; i < 4; ++i) {
        int gid = tid + 256 * i;
        int b = gid >> 7, gt = gid & 127;
        const float* src = &xT[((size_t)(b * 512 + c)) * 1024 + gt * 8];
        float4 v0 = *(const float4*)src;
        float4 v1 = *(const float4*)(src + 4);
        float vv[8] = {v0.x, v0.y, v0.z, v0.w, v1.x, v1.y, v1.z, v1.w};
        unsigned short hsv[8], lsv[8];
#pragma unroll
        for (int j2 = 0; j2 < 8; ++j2) {
            unsigned short h = f2bf(vv[j2]);
            hsv[j2] = h;
            lsv[j2] = f2bf(vv[j2] - __uint_as_float((unsigned)h << 16));
        }
        uint4 hh, ll;
        hh.x = pk2(hsv[0], hsv[1]); hh.y = pk2(hsv[2], hsv[3]);
        hh.z = pk2(hsv[4], hsv[5]); hh.w = pk2(hsv[6], hsv[7]);
        ll.x = pk2(lsv[0], lsv[1]); ll.y = pk2(lsv[2], lsv[3]);
        ll.z = pk2(lsv[4], lsv[5]); ll.w = pk2(lsv[6], lsv[7]);
        int off = (b * 133 + 4 + gt) * 8;
        *(uint4*)&xh[off] = hh;
        *(uint4*)&xl[off] = ll;
    }
    __syncthreads();

    f32x4 acc[4][2];
#pragma unroll
    for (int i = 0; i < 4; ++i) { acc[i][0] = (f32x4)0.0f; acc[i][1] = (f32x4)0.0f; }

    int lr = l & 15, kg4 = l >> 4;
    for (int ch = 0; ch < 4; ++ch) {
        int dq0 = ch * 8;
        // --- build G chunk in LDS ---
        {
            int dqloc = tid >> 5, n = tid & 31, dq = dq0 + dqloc;
            int s0 = 32 * dq + n + 1;  // krp index of ascending window start
            int a0 = s0 & ~3, sh = s0 & 3;
            float ff[36];
#pragma unroll
            for (int i = 0; i < 9; ++i) *(float4*)&ff[i * 4] = *(const float4*)&krp[a0 + i * 4];
            unsigned short hsv[32], lsv[32];
#pragma unroll
            for (int k = 0; k < 32; ++k) {
                int j2 = 31 - k;
                float v = (sh == 0) ? ff[j2] : (sh == 1) ? ff[j2 + 1] : (sh == 2) ? ff[j2 + 2] : ff[j2 + 3];
                unsigned short h = f2bf(v);
                hsv[k] = h;
                lsv[k] = f2bf(v - __uint_as_float((unsigned)h << 16));
            }
            int gbase = (dqloc * 32 + n) * 5 * 8;
#pragma unroll
            for (int kg = 0; kg < 4; ++kg) {
                uint4 hh, ll;
                hh.x = pk2(hsv[8 * kg + 0], hsv[8 * kg + 1]);
                hh.y = pk2(hsv[8 * kg + 2], hsv[8 * kg + 3]);
                hh.z = pk2(hsv[8 * kg + 4], hsv[8 * kg + 5]);
                hh.w = pk2(hsv[8 * kg + 6], hsv[8 * kg + 7]);
                ll.x = pk2(lsv[8 * kg + 0], lsv[8 * kg + 1]);
                ll.y = pk2(lsv[8 * kg + 2], lsv[8 * kg + 3]);
                ll.z = pk2(lsv[8 * kg + 4], lsv[8 * kg + 5]);
                ll.w = pk2(lsv[8 * kg + 6], lsv[8 * kg + 7]);
                *(uint4*)&gh[gbase + kg * 8] = hh;
                *(uint4*)&gl[gbase + kg * 8] = ll;
            }
        }
        __syncthreads();
        // --- MFMA over this chunk ---
        for (int dqloc = 0; dqloc < 8; ++dqloc) {
            int dq = dq0 + dqloc;
            bf16x8 bh[2], bl[2];
#pragma unroll
            for (int nf = 0; nf < 2; ++nf) {
                int go = ((dqloc * 32 + nf * 16 + lr) * 5 + kg4) * 8;
                bh[nf] = *(bf16x8*)&gh[go];
                bl[nf] = *(bf16x8*)&gl[go];
            }
#pragma unroll
            for (int ffi = 0; ffi < 4; ++ffi) {
                int F = w + 4 * ffi;
                if (2 * F + 1 < dq) continue;  // all rows zero-contribution
                int b = lr & 7, qoff = lr >> 3;
                int q = 2 * F + qoff;
                int j = 4 * (q - dq) + kg4 + 4;
                int xo = (b * 133 + j) * 8;
                bf16x8 ah = *(bf16x8*)&xh[xo];
                bf16x8 al = *(bf16x8*)&xl[xo];
#pragma unroll
                for (int nf = 0; nf < 2; ++nf) {
                    acc[ffi][nf] = __builtin_amdgcn_mfma_f32_16x16x32_bf16(ah, bh[nf], acc[ffi][nf], 0, 0, 0);
                    acc[ffi][nf] = __builtin_amdgcn_mfma_f32_16x16x32_bf16(al, bh[nf], acc[ffi][nf], 0, 0, 0);
                    acc[ffi][nf] = __builtin_amdgcn_mfma_f32_16x16x32_bf16(ah, bl[nf], acc[ffi][nf], 0, 0, 0);
                }
            }
        }
        __syncthreads();
    }

    // epilogue: write yT[b][c][t], accumulate ssum
    float bsum[4] = {0, 0, 0, 0};
#pragma unroll
    for (int ffi = 0; ffi < 4; ++ffi) {
        int F = w + 4 * ffi;
#pragma unroll
        for (int nf = 0; nf < 2; ++nf) {
#pragma unroll
            for (int reg = 0; reg < 4; ++reg) {
                int mloc = 4 * kg4 + reg;
                int b = mloc & 7;
                int q = 2 * F + (mloc >> 3);
                int t = 32 * q + nf * 16 + lr;
                yT[((size_t)(b * 512 + c)) * 1024 + t] = acc[ffi][nf][reg];
                bsum[reg] += acc[ffi][nf][reg];
            }
        }
    }
#pragma unroll
    for (int off = 1; off < 16; off <<= 1) {
#pragma unroll
        for (int reg = 0; reg < 4; ++reg) bsum[reg] += __shfl_xor(bsum[reg], off, 64);
    }
    if (lr == 0) {
#pragma unroll
        for (int reg = 0; reg < 4; ++reg) ssh[w * 16 + kg4 * 4 + reg] = bsum[reg];
    }
    __syncthreads();
    if (tid < 8) {
        float tot = 0.0f;
        for (int w2 = 0; w2 < 4; ++w2) tot += ssh[w2 * 16 + tid] + ssh[w2 * 16 + 8 + tid];
        ssum[tid * 512 + c] = tot;
    }
}

__global__ __launch_bounds__(256) void se_kernel(const float* __restrict__ ssum,
                                                 const float* __restrict__ w1,
                                                 const float* __restrict__ b1,
                                                 const float* __restrict__ w2,
                                                 const float* __restrict__ b2,
                                                 float* __restrict__ g) {
    int b = blockIdx.x, tid = threadIdx.x;
    __shared__ float s_sh[512];
    __shared__ float part[256];
    __shared__ float h_sh[64];
    for (int c = tid; c < 512; c += 256) s_sh[c] = ssum[b * 512 + c] * (1.0f / 1024.0f);
    __syncthreads();
    int r = tid & 63, seg = tid >> 6;
    float p = 0.0f;
    for (int c = seg * 128; c < seg * 128 + 128; ++c) p += s_sh[c] * w1[r * 512 + c];
    part[tid] = p;
    __syncthreads();
    if (tid < 64) {
        float h = part[tid] + part[tid + 64] + part[tid + 128] + part[tid + 192] + b1[tid];
        h_sh[tid] = fmaxf(h, 0.0f);
    }
    __syncthreads();
    for (int c = tid; c < 512; c += 256) {
        float acc = b2[c];
#pragma unroll 8
        for (int rr = 0; rr < 64; ++rr) acc += h_sh[rr] * w2[c * 64 + rr];
        g[b * 512 + c] = 1.0f / (1.0f + expf(-acc));
    }
}

// fuse1: y1b = bf16(LN(x + y*g, n1))
__global__ __launch_bounds__(128) void fuse1_kernel(const float* __restrict__ x,
                                                    const float* __restrict__ y,
                                                    const float* __restrict__ g,
                                                    const float* __restrict__ n1g,
                                                    const float* __restrict__ n1b,
                                                    unsigned short* __restrict__ y1b) {
    int row = blockIdx.x, b = row >> 10, tid = threadIdx.x, c = tid * 4;
    __shared__ float r1[2], r2[2];
    float4 xv = *(const float4*)&x[(size_t)row * 512 + c];
    float4 yv = *(const float4*)&y[(size_t)row * 512 + c];
    float4 gv = *(const float4*)&g[b * 512 + c];
    float4 v;
    v.x = xv.x + yv.x * gv.x; v.y = xv.y + yv.y * gv.y;
    v.z = xv.z + yv.z * gv.z; v.w = xv.w + yv.w * gv.w;
    float s1 = v.x + v.y + v.z + v.w;
    float s2 = v.x * v.x + v.y * v.y + v.z * v.z + v.w * v.w;
#pragma unroll
    for (int off = 32; off > 0; off >>= 1) {
        s1 += __shfl_down(s1, off, 64);
        s2 += __shfl_down(s2, off, 64);
    }
    if ((tid & 63) == 0) { r1[tid >> 6] = s1; r2[tid >> 6] = s2; }
    __syncthreads();
    float mean = (r1[0] + r1[1]) * (1.0f / 512.0f);
    float var = (r2[0] + r2[1]) * (1.0f / 512.0f) - mean * mean;
    float rstd = rsqrtf(var + 1e-5f);
    float4 g4 = *(const float4*)&n1g[c];
    float4 b4 = *(const float4*)&n1b[c];
    float4 o;
    o.x = (v.x - mean) * rstd * g4.x + b4.x; o.y = (v.y - mean) * rstd * g4.y + b4.y;
    o.z = (v.z - mean) * rstd * g4.z + b4.z; o.w = (v.w - mean) * rstd * g4.w + b4.w;
    uint2 pk;
    pk.x = pk2(f2bf(o.x), f2bf(o.y));
    pk.y = pk2(f2bf(o.z), f2bf(o.w));
    *(uint2*)&y1b[(size_t)row * 512 + c] = pk;
}

// f32 -> bf16 (RNE), 8 elems/thread.
__global__ __launch_bounds__(256) void f32_to_bf16(const float* __restrict__ in,
                                                   unsigned short* __restrict__ out,
                                                   int n8) {
    int i = blockIdx.x * 256 + threadIdx.x;
    if (i >= n8) return;
    float4 a = ((const float4*)in)[2 * i];
    float4 b = ((const float4*)in)[2 * i + 1];
    uint4 o;
    o.x = pk2(f2bf(a.x), f2bf(a.y));
    o.y = pk2(f2bf(a.z), f2bf(a.w));
    o.z = pk2(f2bf(b.x), f2bf(b.y));
    o.w = pk2(f2bf(b.z), f2bf(b.w));
    *(uint4*)&out[(size_t)i * 8] = o;
}

__device__ __forceinline__ int swz_slot(int slot, int row) {
    return slot ^ (row & 3) ^ ((row >> 2) & 3);
}

// ---------------------------------------------------------------------------
// GEMM1 + GLU (bf16 MFMA). BM=128, out cols 64/block.
// ---------------------------------------------------------------------------
__global__ __launch_bounds__(256) void gemm_glu(const unsigned short* __restrict__ A,
                                                const unsigned short* __restrict__ W,
                                                const float* __restrict__ bias,
                                                unsigned short* __restrict__ act) {
    const int K = 512;
    int m0 = blockIdx.x * 128, n0 = blockIdx.y * 64;
    int tid = threadIdx.x, w = tid >> 6, l = tid & 63;
    __shared__ short As[4096];
    __shared__ short Bs[4096];
    int idA0 = tid, idA1 = tid + 256;
    int rA0 = idA0 >> 2, sA0 = idA0 & 3, rA1 = idA1 >> 2, sA1 = idA1 & 3;
    int ldsA0 = rA0 * 32 + swz_slot(sA0, rA0) * 8;
    int ldsA1 = rA1 * 32 + swz_slot(sA1, rA1) * 8;
    const unsigned short* pA0 = A + (size_t)(m0 + rA0) * K + sA0 * 8;
    const unsigned short* pA1 = A + (size_t)(m0 + rA1) * K + sA1 * 8;
    int gB0 = (rA0 < 64) ? (n0 + rA0) : (1024 + n0 + rA0 - 64);
    int gB1 = (rA1 < 64) ? (n0 + rA1) : (1024 + n0 + rA1 - 64);
    const unsigned short* pB0 = W + (size_t)gB0 * K + sA0 * 8;
    const unsigned short* pB1 = W + (size_t)gB1 * K + sA1 * 8;
    int p = l >> 4, lr = l & 15;
    int aoff[2], bAoff[4], bGoff[4];
#pragma unroll
    for (int rt = 0; rt < 2; ++rt) {
        int r = w * 32 + rt * 16 + lr;
        aoff[rt] = r * 32 + swz_slot(p, r) * 8;
    }
#pragma unroll
    for (int ct = 0; ct < 4; ++ct) {
        int ca = ct * 16 + lr, cg = 64 + ct * 16 + lr;
        bAoff[ct] = ca * 32 + swz_slot(p, ca) * 8;
        bGoff[ct] = cg * 32 + swz_slot(p, cg) * 8;
    }
    f32x4 accA[2][4], accG[2][4];
#pragma unroll
    for (int rt = 0; rt < 2; ++rt)
#pragma unroll
        for (int ct = 0; ct < 4; ++ct) {
            accA[rt][ct] = (f32x4)0.0f;
            accG[rt][ct] = (f32x4)0.0f;
        }
    for (int kt = 0; kt < K; kt += 32) {
        uint4 va0 = *(const uint4*)pA0;
        uint4 va1 = *(const uint4*)pA1;
        uint4 vb0 = *(const uint4*)pB0;
        uint4 vb1 = *(const uint4*)pB1;
        __syncthreads();
        *(uint4*)&As[ldsA0] = va0;
        *(uint4*)&As[ldsA1] = va1;
        *(uint4*)&Bs[ldsA0] = vb0;
        *(uint4*)&Bs[ldsA1] = vb1;
        __syncthreads();
        bf16x8 af[2], bA[4], bG[4];
#pragma unroll
        for (int rt = 0; rt < 2; ++rt) af[rt] = *(bf16x8*)&As[aoff[rt]];
#pragma unroll
        for (int ct = 0; ct < 4; ++ct) {
            bA[ct] = *(bf16x8*)&Bs[bAoff[ct]];
            bG[ct] = *(bf16x8*)&Bs[bGoff[ct]];
        }
#pragma unroll
        for (int rt = 0; rt < 2; ++rt)
#pragma unroll
            for (int ct = 0; ct < 4; ++ct) {
                accA[rt][ct] = __builtin_amdgcn_mfma_f32_16x16x32_bf16(af[rt], bA[ct], accA[rt][ct], 0, 0, 0);
                accG[rt][ct] = __builtin_amdgcn_mfma_f32_16x16x32_bf16(af[rt], bG[ct], accG[rt][ct], 0, 0, 0);
            }
        pA0 += 32; pA1 += 32; pB0 += 32; pB1 += 32;
    }
#pragma unroll
    for (int rt = 0; rt < 2; ++rt)
#pragma unroll
        for (int ct = 0; ct < 4; ++ct) {
            int col = n0 + ct * 16 + lr;
            float ba = bias[col], bg = bias[1024 + col];
#pragma unroll
            for (int reg = 0; reg < 4; ++reg) {
                int row = m0 + w * 32 + rt * 16 + p * 4 + reg;
                float a = accA[rt][ct][reg] + ba;
                float g = accG[rt][ct][reg] + bg;
                act[(size_t)row * 1024 + col] = f2bf(geluf_(a) * sigmoidf_(g));
            }
        }
}

// ---------------------------------------------------------------------------
// GEMM2 (bf16 MFMA): BM=128, BN=128, 2x2 waves, 4x4 frags. C = A@W^T + bias.
// ---------------------------------------------------------------------------
__global__ __launch_bounds__(256) void gemm_plain(const unsigned short* __restrict__ A,
                                                  const unsigned short* __restrict__ W,
                                                  const float* __restrict__ bias,
                                                  float* __restrict__ Cout) {
    const int K = 1024, N = 512;
    int m0 = blockIdx.x * 128, n0 = blockIdx.y * 128;
    int tid = threadIdx.x, w = tid >> 6, l = tid & 63;
    int wr = w >> 1, wc = w & 1;
    __shared__ short As[4096];
    __shared__ short Bs[4096];
    int idA0 = tid, idA1 = tid + 256;
    int rA0 = idA0 >> 2, sA0 = idA0 & 3, rA1 = idA1 >> 2, sA1 = idA1 & 3;
    int ldsA0 = rA0 * 32 + swz_slot(sA0, rA0) * 8;
    int ldsA1 = rA1 * 32 + swz_slot(sA1, rA1) * 8;
    const unsigned short* pA0 = A + (size_t)(m0 + rA0) * K + sA0 * 8;
    const unsigned short* pA1 = A + (size_t)(m0 + rA1) * K + sA1 * 8;
    const unsigned short* pB0 = W + (size_t)(n0 + rA0) * K + sA0 * 8;
    const unsigned short* pB1 = W + (size_t)(n0 + rA1) * K + sA1 * 8;
    int p = l >> 4, lr = l & 15;
    int aoff[4], boff[4];
#pragma unroll
    for (int t = 0; t < 4; ++t) {
        int r = wr * 64 + t * 16 + lr;
        aoff[t] = r * 32 + swz_slot(p, r) * 8;
        int cq = wc * 64 + t * 16 + lr;
        boff[t] = cq * 32 + swz_slot(p, cq) * 8;
    }
    f32x4 acc[4][4];
#pragma unroll
    for (int i = 0; i < 4; ++i)
#pragma unroll
        for (int j = 0; j < 4; ++j) acc[i][j] = (f32x4)0.0f;
    for (int kt = 0; kt < K; kt += 32) {
        uint4 va0 = *(const uint4*)pA0;
        uint4 va1 = *(const uint4*)pA1;
        uint4 vb0 = *(const uint4*)pB0;
        uint4 vb1 = *(const uint4*)pB1;
        __syncthreads();
        *(uint4*)&As[ldsA0] = va0;
        *(uint4*)&As[ldsA1] = va1;
        *(uint4*)&Bs[ldsA0] = vb0;
        *(uint4*)&Bs[ldsA1] = vb1;
        __syncthreads();
        bf16x8 af[4], bfr[4];
#pragma unroll
        for (int t = 0; t < 4; ++t) {
            af[t] = *(bf16x8*)&As[aoff[t]];
            bfr[t] = *(bf16x8*)&Bs[boff[t]];
        }
#pragma unroll
        for (int i = 0; i < 4; ++i)
#pragma unroll
            for (int j = 0; j < 4; ++j)
                acc[i][j] = __builtin_amdgcn_mfma_f32_16x16x32_bf16(af[i], bfr[j], acc[i][j], 0, 0, 0);
        pA0 += 32; pA1 += 32; pB0 += 32; pB1 += 32;
    }
#pragma unroll
    for (int i = 0; i < 4; ++i)
#pragma unroll
        for (int j = 0; j < 4; ++j) {
            int col = n0 + wc * 64 + j * 16 + lr;
            float bb = bias[col];
#pragma unroll
            for (int reg = 0; reg < 4; ++reg) {
                int row = m0 + wr * 64 + i * 16 + p * 4 + reg;
                Cout[(size_t)row * N + col] = acc[i][j][reg] + bb;
            }
        }
}

// fuse2: z2 = LN(y1+z, mixn); out = LN(y1+z2, n2). y1 read as bf16.
__global__ __launch_bounds__(128) void fuse2_kernel(const unsigned short* __restrict__ y1b,
                                                    const float* __restrict__ z,
                                                    const float* __restrict__ mg,
                                                    const float* __restrict__ mb,
                                                    const float* __restrict__ g2,
                                                    const float* __restrict__ b2v,
                                                    float* __restrict__ out) {
    int row = blockIdx.x, tid = threadIdx.x, c = tid * 4;
    __shared__ float r1[2], r2[2];
    uint2 yu = *(const uint2*)&y1b[(size_t)row * 512 + c];
    float4 a;
    a.x = __uint_as_float(yu.x << 16);
    a.y = __uint_as_float(yu.x & 0xffff0000u);
    a.z = __uint_as_float(yu.y << 16);
    a.w = __uint_as_float(yu.y & 0xffff0000u);
    float4 zv = *(const float4*)&z[(size_t)row * 512 + c];
    float4 t1;
    t1.x = a.x + zv.x; t1.y = a.y + zv.y; t1.z = a.z + zv.z; t1.w = a.w + zv.w;
    float s1 = t1.x + t1.y + t1.z + t1.w;
    float s2 = t1.x * t1.x + t1.y * t1.y + t1.z * t1.z + t1.w * t1.w;
#pragma unroll
    for (int off = 32; off > 0; off >>= 1) {
        s1 += __shfl_down(s1, off, 64);
        s2 += __shfl_down(s2, off, 64);
    }
    if ((tid & 63) == 0) { r1[tid >> 6] = s1; r2[tid >> 6] = s2; }
    __syncthreads();
    float mean = (r1[0] + r1[1]) * (1.0f / 512.0f);
    float var = (r2[0] + r2[1]) * (1.0f / 512.0f) - mean * mean;
    float rstd = rsqrtf(var + 1e-5f);
    float4 mg4 = *(const float4*)&mg[c];
    float4 mb4 = *(const float4*)&mb[c];
    float4 t2;
    t2.x = a.x + ((t1.x - mean) * rstd * mg4.x + mb4.x);
    t2.y = a.y + ((t1.y - mean) * rstd * mg4.y + mb4.y);
    t2.z = a.z + ((t1.z - mean) * rstd * mg4.z + mb4.z);
    t2.w = a.w + ((t1.w - mean) * rstd * mg4.w + mb4.w);
    __syncthreads();
    s1 = t2.x + t2.y + t2.z + t2.w;
    s2 = t2.x * t2.x + t2.y * t2.y + t2.z * t2.z + t2.w * t2.w;
#pragma unroll
    for (int off = 32; off > 0; off >>= 1) {
        s1 += __shfl_down(s1, off, 64);
        s2 += __shfl_down(s2, off, 64);
    }
    if ((tid & 63) == 0) { r1[tid >> 6] = s1; r2[tid >> 6] = s2; }
    __syncthreads();
    float mean2 = (r1[0] + r1[1]) * (1.0f / 512.0f);
    float var2 = (r2[0] + r2[1]) * (1.0f / 512.0f) - mean2 * mean2;
    float rstd2 = rsqrtf(var2 + 1e-5f);
    float4 gg = *(const float4*)&g2[c];
    float4 bb = *(const float4*)&b2v[c];
    float4 o;
    o.x = (t2.x - mean2) * rstd2 * gg.x + bb.x;
    o.y = (t2.y - mean2) * rstd2 * gg.y + bb.y;
    o.z = (t2.z - mean2) * rstd2 * gg.z + bb.z;
    o.w = (t2.w - mean2) * rstd2 * gg.w + bb.w;
    *(float4*)&out[(size_t)row * 512 + c] = o;
}

// ---------------------------------------------------------------------------
// Workspace (floats), total 19,570,752 = ~78.3 MB.
// Timeline aliases: up_wb/dn_wb in Kpart (dead after reduce_K); act(bf16) in
// xT (dead after conv); yT -> transpose_y -> y; y1b overlays dead yT slot.
// ---------------------------------------------------------------------------
extern "C" void kernel_launch(void* const* d_in, const int* in_sizes, int n_in,
                              void* d_out, int out_size, void* d_ws, size_t ws_size,
                              hipStream_t stream) {
    (void)in_sizes; (void)n_in; (void)out_size; (void)ws_size;
    const float* x      = (const float*)d_in[0];
    const float* Bp     = (const float*)d_in[1];
    const float* Cp     = (const float*)d_in[2];
    const float* Dp     = (const float*)d_in[3];
    const float* log_dt = (const float*)d_in[4];
    const float* se_w1  = (const float*)d_in[5];
    const float* se_b1  = (const float*)d_in[6];
    const float* se_w2  = (const float*)d_in[7];
    const float* se_b2  = (const float*)d_in[8];
    const float* n1g    = (const float*)d_in[9];
    const float* n1b    = (const float*)d_in[10];
    const float* up_w   = (const float*)d_in[11];
    const float* up_b   = (const float*)d_in[12];
    const float* dn_w   = (const float*)d_in[13];
    const float* dn_b   = (const float*)d_in[14];
    const float* mxg    = (const float*)d_in[15];
    const float* mxb    = (const float*)d_in[16];
    const float* n2g    = (const float*)d_in[17];
    const float* n2b    = (const float*)d_in[18];

    float* ws    = (float*)d_ws;
    float* Kr    = ws + 0;         //   524288
    float* AbarT = ws + 524288;    //    16384
    float* A32   = ws + 540672;    //    16384
    float* Bbar  = ws + 557056;    //   131072
    float* dtb   = ws + 688128;    //       64
    float* Kpart = ws + 688192;    //  2097152
    float* xT    = ws + 2785344;   //  4194304
    float* yb    = ws + 6979648;   //  4194304  (y in [b][t][c])
    float* ssum  = ws + 11173952;  //     4096
    float* gbuf  = ws + 11178048;  //     4096
    float* yT    = ws + 11182144;  //  4194304  (conv out [b][c][t]; later y1b)
    float* zb    = ws + 15376448;  //  4194304
    unsigned short* up_wb = (unsigned short*)(ws + 688192);
    unsigned short* dn_wb = (unsigned short*)(ws + 950336);
    unsigned short* act   = (unsigned short*)(ws + 2785344);   // aliases xT
    unsigned short* y1b   = (unsigned short*)(ws + 11182144);  // aliases yT
    float* outp  = (float*)d_out;

    hipLaunchKernelGGL(prep_comp, dim3(4), dim3(256), 0, stream, log_dt, AbarT, A32, dtb);
    hipLaunchKernelGGL(compute_bbar, dim3(8), dim3(256), 0, stream, Bp, dtb, Bbar);
    hipLaunchKernelGGL(compute_K, dim3(512, 4), dim3(256), 0, stream, Cp, Bbar, AbarT, A32, Dp, Kpart);
    hipLaunchKernelGGL(reduce_K, dim3(2048), dim3(256), 0, stream, Kpart, Kr);
    hipLaunchKernelGGL(f32_to_bf16, dim3(512), dim3(256), 0, stream, up_w, up_wb, 131072);
    hipLaunchKernelGGL(f32_to_bf16, dim3(256), dim3(256), 0, stream, dn_w, dn_wb, 65536);
    hipLaunchKernelGGL(transpose_bmat, dim3(32, 16, 8), dim3(256), 0, stream, x, xT, 1024, 512);
    hipLaunchKernelGGL(conv_mfma, dim3(512), dim3(256), 0, stream, xT, Kr, yT, ssum);
    hipLaunchKernelGGL(se_kernel, dim3(8), dim3(256), 0, stream, ssum, se_w1, se_b1, se_w2, se_b2, gbuf);
    hipLaunchKernelGGL(transpose_bmat, dim3(16, 32, 8), dim3(256), 0, stream, yT, yb, 512, 1024);
    hipLaunchKernelGGL(fuse1_kernel, dim3(8192), dim3(128), 0, stream, x, yb, gbuf, n1g, n1b, y1b);
    hipLaunchKernelGGL(gemm_glu, dim3(64, 16), dim3(256), 0, stream, y1b, up_wb, up_b, act);
    hipLaunchKernelGGL(gemm_plain, dim3(64, 4), dim3(256), 0, stream, act, dn_wb, dn_b, zb);
    hipLaunchKernelGGL(fuse2_kernel, dim3(8192), dim3(128), 0, stream, y1b, zb, mxg, mxb, n2g, n2b, outp);
}

// Round 4
// 337.087 us; speedup vs baseline: 2.5323x; 1.3957x over previous
//
#include <hip/hip_runtime.h>
#include <math.h>

// Sizes: B=8, L=1024, D=512, N=64, NC=4, HIDDEN=1024, up rows=2048, R=64

typedef short bf16x8 __attribute__((ext_vector_type(8)));
typedef float f32x4 __attribute__((ext_vector_type(4)));

__device__ __forceinline__ float sigmoidf_(float x) { return 1.0f / (1.0f + expf(-x)); }
__device__ __forceinline__ float geluf_(float x) { return 0.5f * x * (1.0f + erff(x * 0.70710678118654752f)); }
__device__ __forceinline__ unsigned short f2bf(float f) {
    unsigned u = __float_as_uint(f);
    unsigned r = (u + 0x7FFFu + ((u >> 16) & 1u)) >> 16;
    return (unsigned short)r;
}
__device__ __forceinline__ unsigned pk2(unsigned short a, unsigned short b) {
    return (unsigned)a | ((unsigned)b << 16);
}

// ---------------------------------------------------------------------------
// P1: per-component A_bar + A32 = A_bar^32.
// KEY: the HiPPO lhs L = I - hdt*A is rank-1 below the diagonal
// (L[i][k] = hdt*sq_i*sq_k, k<i), so forward substitution is O(N) with one
// running sum (64-step chain, ~1us, vs 2016-step chain before).
// Squarings: 4x4 register tiles, float4 LDS reads via maintained transpose.
// ---------------------------------------------------------------------------
__global__ __launch_bounds__(256) void prep_comp(const float* __restrict__ log_dt,
                                                 float* __restrict__ AbarT,
                                                 float* __restrict__ A32,
                                                 float* __restrict__ dtbuf) {
    int comp = blockIdx.x, tid = threadIdx.x;
    __shared__ __align__(16) float M1[4096];
    __shared__ __align__(16) float M1T[4096];
    __shared__ __align__(16) float M2[4096];
    __shared__ __align__(16) float M2T[4096];
    float ldt = log_dt[comp];
    float dt = log1pf(expf(ldt)) + 1e-6f;
    float hdt = 0.5f * dt;
    // rank-1 forward substitution: lane j computes column j of A_bar
    if (tid < 64) {
        int j = tid;
        float sqj = sqrtf(2.0f * (float)j + 1.0f);
        float S = 0.0f;
        for (int i = 0; i < 64; ++i) {
            float sqi = sqrtf(2.0f * (float)i + 1.0f);
            float r = (i == j) ? (1.0f - hdt * (float)(i + 1))
                               : ((i > j) ? (-hdt * sqi * sqj) : 0.0f);
            float X = (r - hdt * sqi * S) / (1.0f + hdt * (float)(i + 1));
            M1[i * 64 + j] = X;
            M1T[j * 64 + i] = X;
            S += sqi * X;
        }
    }
    __syncthreads();
    for (int idx = tid; idx < 4096; idx += 256) AbarT[comp * 4096 + idx] = M1T[idx];
    // 5 squarings, ping-pong (M1,M1T)<->(M2,M2T). Upper triangles stay zero.
    float* cur = M1; float* curT = M1T; float* nxt = M2; float* nxtT = M2T;
    int ti = tid >> 4, tj = tid & 15;  // 4x4 tile (rows ti*4.., cols tj*4..)
    for (int s = 0; s < 5; ++s) {
        float c[4][4] = {{0}};
        if (ti >= tj) {
            for (int k = tj * 4; k < ti * 4 + 4; ++k) {
                float4 a = *(const float4*)&curT[k * 64 + ti * 4];  // cur[ti*4..][k]
                float4 b = *(const float4*)&cur[k * 64 + tj * 4];   // cur[k][tj*4..]
                c[0][0] += a.x * b.x; c[0][1] += a.x * b.y; c[0][2] += a.x * b.z; c[0][3] += a.x * b.w;
                c[1][0] += a.y * b.x; c[1][1] += a.y * b.y; c[1][2] += a.y * b.z; c[1][3] += a.y * b.w;
                c[2][0] += a.z * b.x; c[2][1] += a.z * b.y; c[2][2] += a.z * b.z; c[2][3] += a.z * b.w;
                c[3][0] += a.w * b.x; c[3][1] += a.w * b.y; c[3][2] += a.w * b.z; c[3][3] += a.w * b.w;
            }
        }
#pragma unroll
        for (int r = 0; r < 4; ++r) {
            float4 row; row.x = c[r][0]; row.y = c[r][1]; row.z = c[r][2]; row.w = c[r][3];
            *(float4*)&nxt[(ti * 4 + r) * 64 + tj * 4] = row;
            float4 colv; colv.x = c[0][r]; colv.y = c[1][r]; colv.z = c[2][r]; colv.w = c[3][r];
            *(float4*)&nxtT[(tj * 4 + r) * 64 + ti * 4] = colv;
        }
        __syncthreads();
        float* t0 = cur; cur = nxt; nxt = t0;
        float* t1 = curT; curT = nxtT; nxtT = t1;
    }
    for (int idx = tid; idx < 4096; idx += 256) A32[comp * 4096 + idx] = cur[idx];
    if (tid == 0) dtbuf[comp] = dt;
}

// ---------------------------------------------------------------------------
// P2: B_bar rows — same rank-1 trick, O(N) per thread.
// ---------------------------------------------------------------------------
__global__ __launch_bounds__(256) void compute_bbar(const float* __restrict__ Bp,
                                                    const float* __restrict__ dtbuf,
                                                    float* __restrict__ Bbar) {
    int gid = blockIdx.x * 256 + threadIdx.x;
    int comp = gid >> 9;
    float dt = dtbuf[comp];
    float hdt = 0.5f * dt;
    const float* bp = Bp + (size_t)gid * 64;
    float* out = Bbar + (size_t)gid * 64;
    float S = 0.0f;
    for (int i = 0; i < 64; ++i) {
        float sqi = sqrtf(2.0f * (float)i + 1.0f);
        float y = (dt * bp[i] - hdt * sqi * S) / (1.0f + hdt * (float)(i + 1));
        out[i] = y;
        S += sqi * y;
    }
}

__global__ __launch_bounds__(256) void compute_K(const float* __restrict__ Cp,
                                                 const float* __restrict__ Bbar,
                                                 const float* __restrict__ AbarT,
                                                 const float* __restrict__ A32,
                                                 const float* __restrict__ Dp,
                                                 float* __restrict__ Kpart) {
    int d = blockIdx.x, comp = blockIdx.y, tid = threadIdx.x;
    __shared__ float Ms1[64 * 65];
    __shared__ float Ms2[64 * 65];
    __shared__ float uvv[32 * 65];
    __shared__ float uvu[32 * 65];
    for (int idx = tid; idx < 4096; idx += 256) {
        int k = idx >> 6, i = idx & 63;
        Ms1[k * 65 + i] = AbarT[comp * 4096 + idx];
        Ms2[k * 65 + i] = A32[comp * 4096 + idx];
    }
    if (tid < 64) {
        uvv[tid] = Bbar[((size_t)comp * 512 + d) * 64 + tid];
        uvu[tid] = Cp[((size_t)comp * 512 + d) * 64 + tid];
    }
    __syncthreads();
    int half = tid >> 7, hh = tid & 1, idx = (tid >> 1) & 63;
    for (int r = 1; r < 32; ++r) {
        float s = 0.0f;
        if (half == 0) {
            int i = idx;
            int k0 = hh * 32, k1 = min(k0 + 32, i + 1);
            for (int k = k0; k < k1; ++k) s += Ms1[k * 65 + i] * uvv[(r - 1) * 65 + k];
        } else {
            int n = idx;
            int m0 = max(hh * 32, n), m1 = hh * 32 + 32;
            for (int m = m0; m < m1; ++m) s += Ms2[m * 65 + n] * uvu[(r - 1) * 65 + m];
        }
        s += __shfl_xor(s, 1, 64);
        if (hh == 0) {
            if (half == 0) uvv[r * 65 + idx] = s;
            else uvu[r * 65 + idx] = s;
        }
        __syncthreads();
    }
    float dval = Dp[comp * 512 + d];
    int l0 = tid * 4;
    float ov[4];
#pragma unroll
    for (int j = 0; j < 4; ++j) {
        int l = l0 + j, q = l >> 5, rr = l & 31;
        float s = 0.0f;
#pragma unroll 8
        for (int n = 0; n < 64; ++n) s += uvu[q * 65 + n] * uvv[rr * 65 + n];
        if (l == 0) s += dval;
        ov[j] = s;
    }
    float4 o; o.x = ov[0]; o.y = ov[1]; o.z = ov[2]; o.w = ov[3];
    *(float4*)&Kpart[((size_t)comp * 512 + d) * 1024 + l0] = o;
}

__global__ __launch_bounds__(256) void reduce_K(const float* __restrict__ Kpart,
                                                float* __restrict__ Kr) {
    int idx = blockIdx.x * 256 + threadIdx.x;
    int d = idx >> 10, l = idx & 1023;
    float s = Kpart[idx] + Kpart[524288 + idx] + Kpart[2 * 524288 + idx] + Kpart[3 * 524288 + idx];
    Kr[(size_t)d * 1024 + (1023 - l)] = s;
}

// Generic batched transpose: in [B][R][C] -> out [B][C][R]
__global__ __launch_bounds__(256) void transpose_bmat(const float* __restrict__ in,
                                                      float* __restrict__ out,
                                                      int R, int C) {
    __shared__ float tile[32][33];
    int r0 = blockIdx.x * 32, c0 = blockIdx.y * 32, b = blockIdx.z;
    int tx = threadIdx.x & 31, ty = threadIdx.x >> 5;
#pragma unroll
    for (int m = 0; m < 4; ++m)
        tile[ty + 8 * m][tx] = in[((size_t)b * R + r0 + ty + 8 * m) * C + c0 + tx];
    __syncthreads();
#pragma unroll
    for (int m = 0; m < 4; ++m)
        out[((size_t)b * C + c0 + ty + 8 * m) * R + r0 + tx] = tile[tx][ty + 8 * m];
}

// ---------------------------------------------------------------------------
// MFMA depthwise conv (unchanged from round 3).
// ---------------------------------------------------------------------------
__global__ __launch_bounds__(256) void conv_mfma(const float* __restrict__ xT,
                                                 const float* __restrict__ Kr,
                                                 float* __restrict__ yT,
                                                 float* __restrict__ ssum) {
    int c = blockIdx.x, tid = threadIdx.x;
    int w = tid >> 6, l = tid & 63;
    __shared__ __align__(16) float krp[1088];
    __shared__ __align__(16) short xh[8512], xl[8512];
    __shared__ __align__(16) short gh[10240], gl[10240];
    __shared__ float ssh[64];

    {
        float4 kv = *(const float4*)&Kr[(size_t)c * 1024 + tid * 4];
        *(float4*)&krp[32 + tid * 4] = kv;
        if (tid < 8) *(float4*)&krp[tid * 4] = make_float4(0, 0, 0, 0);
        else if (tid < 16) *(float4*)&krp[1056 + (tid - 8) * 4] = make_float4(0, 0, 0, 0);
    }
    if (tid < 32) {
        int b = tid >> 2, g = tid & 3;
        uint4 z = {0, 0, 0, 0};
        *(uint4*)&xh[(b * 133 + g) * 8] = z;
    } else if (tid < 64) {
        int t2 = tid - 32; int b = t2 >> 2, g = t2 & 3;
        uint4 z = {0, 0, 0, 0};
        *(uint4*)&xl[(b * 133 + g) * 8] = z;
    }
#pragma unroll
    for (int i = 0; i < 4; ++i) {
        int gid = tid + 256 * i;
        int b = gid >> 7, gt = gid & 127;
        const float* src = &xT[((size_t)(b * 512 + c)) * 1024 + gt * 8];
        float4 v0 = *(const float4*)src;
        float4 v1 = *(const float4*)(src + 4);
        float vv[8] = {v0.x, v0.y, v0.z, v0.w, v1.x, v1.y, v1.z, v1.w};
        unsigned short hsv[8], lsv[8];
#pragma unroll
        for (int j2 = 0; j2 < 8; ++j2) {
            unsigned short h = f2bf(vv[j2]);
            hsv[j2] = h;
            lsv[j2] = f2bf(vv[j2] - __uint_as_float((unsigned)h << 16));
        }
        uint4 hh, ll;
        hh.x = pk2(hsv[0], hsv[1]); hh.y = pk2(hsv[2], hsv[3]);
        hh.z = pk2(hsv[4], hsv[5]); hh.w = pk2(hsv[6], hsv[7]);
        ll.x = pk2(lsv[0], lsv[1]); ll.y = pk2(lsv[2], lsv[3]);
        ll.z = pk2(lsv[4], lsv[5]); ll.w = pk2(lsv[6], lsv[7]);
        int off = (b * 133 + 4 + gt) * 8;
        *(uint4*)&xh[off] = hh;
        *(uint4*)&xl[off] = ll;
    }
    __syncthreads();

    f32x4 acc[4][2];
#pragma unroll
    for (int i = 0; i < 4; ++i) { acc[i][0] = (f32x4)0.0f; acc[i][1] = (f32x4)0.0f; }

    int lr = l & 15, kg4 = l >> 4;
    for (int ch = 0; ch < 4; ++ch) {
        int dq0 = ch * 8;
        {
            int dqloc = tid >> 5, n = tid & 31, dq = dq0 + dqloc;
            int s0 = 32 * dq + n + 1;
            int a0 = s0 & ~3, sh = s0 & 3;
            float ff[36];
#pragma unroll
            for (int i = 0; i < 9; ++i) *(float4*)&ff[i * 4] = *(const float4*)&krp[a0 + i * 4];
            unsigned short hsv[32], lsv[32];
#pragma unroll
            for (int k = 0; k < 32; ++k) {
                int j2 = 31 - k;
                float v = (sh == 0) ? ff[j2] : (sh == 1) ? ff[j2 + 1] : (sh == 2) ? ff[j2 + 2] : ff[j2 + 3];
                unsigned short h = f2bf(v);
                hsv[k] = h;
                lsv[k] = f2bf(v - __uint_as_float((unsigned)h << 16));
            }
            int gbase = (dqloc * 32 + n) * 5 * 8;
#pragma unroll
            for (int kg = 0; kg < 4; ++kg) {
                uint4 hh, ll;
                hh.x = pk2(hsv[8 * kg + 0], hsv[8 * kg + 1]);
                hh.y = pk2(hsv[8 * kg + 2], hsv[8 * kg + 3]);
                hh.z = pk2(hsv[8 * kg + 4], hsv[8 * kg + 5]);
                hh.w = pk2(hsv[8 * kg + 6], hsv[8 * kg + 7]);
                ll.x = pk2(lsv[8 * kg + 0], lsv[8 * kg + 1]);
                ll.y = pk2(lsv[8 * kg + 2], lsv[8 * kg + 3]);
                ll.z = pk2(lsv[8 * kg + 4], lsv[8 * kg + 5]);
                ll.w = pk2(lsv[8 * kg + 6], lsv[8 * kg + 7]);
                *(uint4*)&gh[gbase + kg * 8] = hh;
                *(uint4*)&gl[gbase + kg * 8] = ll;
            }
        }
        __syncthreads();
        for (int dqloc = 0; dqloc < 8; ++dqloc) {
            int dq = dq0 + dqloc;
            bf16x8 bh[2], bl[2];
#pragma unroll
            for (int nf = 0; nf < 2; ++nf) {
                int go = ((dqloc * 32 + nf * 16 + lr) * 5 + kg4) * 8;
                bh[nf] = *(bf16x8*)&gh[go];
                bl[nf] = *(bf16x8*)&gl[go];
            }
#pragma unroll
            for (int ffi = 0; ffi < 4; ++ffi) {
                int F = w + 4 * ffi;
                if (2 * F + 1 < dq) continue;
                int b = lr & 7, qoff = lr >> 3;
                int q = 2 * F + qoff;
                int j = 4 * (q - dq) + kg4 + 4;
                int xo = (b * 133 + j) * 8;
                bf16x8 ah = *(bf16x8*)&xh[xo];
                bf16x8 al = *(bf16x8*)&xl[xo];
#pragma unroll
                for (int nf = 0; nf < 2; ++nf) {
                    acc[ffi][nf] = __builtin_amdgcn_mfma_f32_16x16x32_bf16(ah, bh[nf], acc[ffi][nf], 0, 0, 0);
                    acc[ffi][nf] = __builtin_amdgcn_mfma_f32_16x16x32_bf16(al, bh[nf], acc[ffi][nf], 0, 0, 0);
                    acc[ffi][nf] = __builtin_amdgcn_mfma_f32_16x16x32_bf16(ah, bl[nf], acc[ffi][nf], 0, 0, 0);
                }
            }
        }
        __syncthreads();
    }

    float bsum[4] = {0, 0, 0, 0};
#pragma unroll
    for (int ffi = 0; ffi < 4; ++ffi) {
        int F = w + 4 * ffi;
#pragma unroll
        for (int nf = 0; nf < 2; ++nf) {
#pragma unroll
            for (int reg = 0; reg < 4; ++reg) {
                int mloc = 4 * kg4 + reg;
                int b = mloc & 7;
                int q = 2 * F + (mloc >> 3);
                int t = 32 * q + nf * 16 + lr;
                yT[((size_t)(b * 512 + c)) * 1024 + t] = acc[ffi][nf][reg];
                bsum[reg] += acc[ffi][nf][reg];
            }
        }
    }
#pragma unroll
    for (int off = 1; off < 16; off <<= 1) {
#pragma unroll
        for (int reg = 0; reg < 4; ++reg) bsum[reg] += __shfl_xor(bsum[reg], off, 64);
    }
    if (lr == 0) {
#pragma unroll
        for (int reg = 0; reg < 4; ++reg) ssh[w * 16 + kg4 * 4 + reg] = bsum[reg];
    }
    __syncthreads();
    if (tid < 8) {
        float tot = 0.0f;
        for (int w2 = 0; w2 < 4; ++w2) tot += ssh[w2 * 16 + tid] + ssh[w2 * 16 + 8 + tid];
        ssum[tid * 512 + c] = tot;
    }
}

__global__ __launch_bounds__(256) void se_kernel(const float* __restrict__ ssum,
                                                 const float* __restrict__ w1,
                                                 const float* __restrict__ b1,
                                                 const float* __restrict__ w2,
                                                 const float* __restrict__ b2,
                                                 float* __restrict__ g) {
    int b = blockIdx.x, tid = threadIdx.x;
    __shared__ float s_sh[512];
    __shared__ float part[256];
    __shared__ float h_sh[64];
    for (int c = tid; c < 512; c += 256) s_sh[c] = ssum[b * 512 + c] * (1.0f / 1024.0f);
    __syncthreads();
    int r = tid & 63, seg = tid >> 6;
    float p = 0.0f;
    for (int c = seg * 128; c < seg * 128 + 128; ++c) p += s_sh[c] * w1[r * 512 + c];
    part[tid] = p;
    __syncthreads();
    if (tid < 64) {
        float h = part[tid] + part[tid + 64] + part[tid + 128] + part[tid + 192] + b1[tid];
        h_sh[tid] = fmaxf(h, 0.0f);
    }
    __syncthreads();
    for (int c = tid; c < 512; c += 256) {
        float acc = b2[c];
#pragma unroll 8
        for (int rr = 0; rr < 64; ++rr) acc += h_sh[rr] * w2[c * 64 + rr];
        g[b * 512 + c] = 1.0f / (1.0f + expf(-acc));
    }
}

// fuse1: y1b = bf16(LN(x + y*g, n1))
__global__ __launch_bounds__(128) void fuse1_kernel(const float* __restrict__ x,
                                                    const float* __restrict__ y,
                                                    const float* __restrict__ g,
                                                    const float* __restrict__ n1g,
                                                    const float* __restrict__ n1b,
                                                    unsigned short* __restrict__ y1b) {
    int row = blockIdx.x, b = row >> 10, tid = threadIdx.x, c = tid * 4;
    __shared__ float r1[2], r2[2];
    float4 xv = *(const float4*)&x[(size_t)row * 512 + c];
    float4 yv = *(const float4*)&y[(size_t)row * 512 + c];
    float4 gv = *(const float4*)&g[b * 512 + c];
    float4 v;
    v.x = xv.x + yv.x * gv.x; v.y = xv.y + yv.y * gv.y;
    v.z = xv.z + yv.z * gv.z; v.w = xv.w + yv.w * gv.w;
    float s1 = v.x + v.y + v.z + v.w;
    float s2 = v.x * v.x + v.y * v.y + v.z * v.z + v.w * v.w;
#pragma unroll
    for (int off = 32; off > 0; off >>= 1) {
        s1 += __shfl_down(s1, off, 64);
        s2 += __shfl_down(s2, off, 64);
    }
    if ((tid & 63) == 0) { r1[tid >> 6] = s1; r2[tid >> 6] = s2; }
    __syncthreads();
    float mean = (r1[0] + r1[1]) * (1.0f / 512.0f);
    float var = (r2[0] + r2[1]) * (1.0f / 512.0f) - mean * mean;
    float rstd = rsqrtf(var + 1e-5f);
    float4 g4 = *(const float4*)&n1g[c];
    float4 b4 = *(const float4*)&n1b[c];
    float4 o;
    o.x = (v.x - mean) * rstd * g4.x + b4.x; o.y = (v.y - mean) * rstd * g4.y + b4.y;
    o.z = (v.z - mean) * rstd * g4.z + b4.z; o.w = (v.w - mean) * rstd * g4.w + b4.w;
    uint2 pk;
    pk.x = pk2(f2bf(o.x), f2bf(o.y));
    pk.y = pk2(f2bf(o.z), f2bf(o.w));
    *(uint2*)&y1b[(size_t)row * 512 + c] = pk;
}

// f32 -> bf16 (RNE), 8 elems/thread.
__global__ __launch_bounds__(256) void f32_to_bf16(const float* __restrict__ in,
                                                   unsigned short* __restrict__ out,
                                                   int n8) {
    int i = blockIdx.x * 256 + threadIdx.x;
    if (i >= n8) return;
    float4 a = ((const float4*)in)[2 * i];
    float4 b = ((const float4*)in)[2 * i + 1];
    uint4 o;
    o.x = pk2(f2bf(a.x), f2bf(a.y));
    o.y = pk2(f2bf(a.z), f2bf(a.w));
    o.z = pk2(f2bf(b.x), f2bf(b.y));
    o.w = pk2(f2bf(b.z), f2bf(b.w));
    *(uint4*)&out[(size_t)i * 8] = o;
}

__device__ __forceinline__ int swz_slot(int slot, int row) {
    return slot ^ (row & 3) ^ ((row >> 2) & 3);
}

// ---------------------------------------------------------------------------
// GEMM1 + GLU (bf16 MFMA). BM=128, out cols 64/block.
// ---------------------------------------------------------------------------
__global__ __launch_bounds__(256) void gemm_glu(const unsigned short* __restrict__ A,
                                                const unsigned short* __restrict__ W,
                                                const float* __restrict__ bias,
                                                unsigned short* __restrict__ act) {
    const int K = 512;
    int m0 = blockIdx.x * 128, n0 = blockIdx.y * 64;
    int tid = threadIdx.x, w = tid >> 6, l = tid & 63;
    __shared__ short As[4096];
    __shared__ short Bs[4096];
    int idA0 = tid, idA1 = tid + 256;
    int rA0 = idA0 >> 2, sA0 = idA0 & 3, rA1 = idA1 >> 2, sA1 = idA1 & 3;
    int ldsA0 = rA0 * 32 + swz_slot(sA0, rA0) * 8;
    int ldsA1 = rA1 * 32 + swz_slot(sA1, rA1) * 8;
    const unsigned short* pA0 = A + (size_t)(m0 + rA0) * K + sA0 * 8;
    const unsigned short* pA1 = A + (size_t)(m0 + rA1) * K + sA1 * 8;
    int gB0 = (rA0 < 64) ? (n0 + rA0) : (1024 + n0 + rA0 - 64);
    int gB1 = (rA1 < 64) ? (n0 + rA1) : (1024 + n0 + rA1 - 64);
    const unsigned short* pB0 = W + (size_t)gB0 * K + sA0 * 8;
    const unsigned short* pB1 = W + (size_t)gB1 * K + sA1 * 8;
    int p = l >> 4, lr = l & 15;
    int aoff[2], bAoff[4], bGoff[4];
#pragma unroll
    for (int rt = 0; rt < 2; ++rt) {
        int r = w * 32 + rt * 16 + lr;
        aoff[rt] = r * 32 + swz_slot(p, r) * 8;
    }
#pragma unroll
    for (int ct = 0; ct < 4; ++ct) {
        int ca = ct * 16 + lr, cg = 64 + ct * 16 + lr;
        bAoff[ct] = ca * 32 + swz_slot(p, ca) * 8;
        bGoff[ct] = cg * 32 + swz_slot(p, cg) * 8;
    }
    f32x4 accA[2][4], accG[2][4];
#pragma unroll
    for (int rt = 0; rt < 2; ++rt)
#pragma unroll
        for (int ct = 0; ct < 4; ++ct) {
            accA[rt][ct] = (f32x4)0.0f;
            accG[rt][ct] = (f32x4)0.0f;
        }
    for (int kt = 0; kt < K; kt += 32) {
        uint4 va0 = *(const uint4*)pA0;
        uint4 va1 = *(const uint4*)pA1;
        uint4 vb0 = *(const uint4*)pB0;
        uint4 vb1 = *(const uint4*)pB1;
        __syncthreads();
        *(uint4*)&As[ldsA0] = va0;
        *(uint4*)&As[ldsA1] = va1;
        *(uint4*)&Bs[ldsA0] = vb0;
        *(uint4*)&Bs[ldsA1] = vb1;
        __syncthreads();
        bf16x8 af[2], bA[4], bG[4];
#pragma unroll
        for (int rt = 0; rt < 2; ++rt) af[rt] = *(bf16x8*)&As[aoff[rt]];
#pragma unroll
        for (int ct = 0; ct < 4; ++ct) {
            bA[ct] = *(bf16x8*)&Bs[bAoff[ct]];
            bG[ct] = *(bf16x8*)&Bs[bGoff[ct]];
        }
#pragma unroll
        for (int rt = 0; rt < 2; ++rt)
#pragma unroll
            for (int ct = 0; ct < 4; ++ct) {
                accA[rt][ct] = __builtin_amdgcn_mfma_f32_16x16x32_bf16(af[rt], bA[ct], accA[rt][ct], 0, 0, 0);
                accG[rt][ct] = __builtin_amdgcn_mfma_f32_16x16x32_bf16(af[rt], bG[ct], accG[rt][ct], 0, 0, 0);
            }
        pA0 += 32; pA1 += 32; pB0 += 32; pB1 += 32;
    }
#pragma unroll
    for (int rt = 0; rt < 2; ++rt)
#pragma unroll
        for (int ct = 0; ct < 4; ++ct) {
            int col = n0 + ct * 16 + lr;
            float ba = bias[col], bg = bias[1024 + col];
#pragma unroll
            for (int reg = 0; reg < 4; ++reg) {
                int row = m0 + w * 32 + rt * 16 + p * 4 + reg;
                float a = accA[rt][ct][reg] + ba;
                float g = accG[rt][ct][reg] + bg;
                act[(size_t)row * 1024 + col] = f2bf(geluf_(a) * sigmoidf_(g));
            }
        }
}

// ---------------------------------------------------------------------------
// GEMM2 (bf16 MFMA): BM=128, BN=128, 2x2 waves, 4x4 frags. C = A@W^T + bias.
// ---------------------------------------------------------------------------
__global__ __launch_bounds__(256) void gemm_plain(const unsigned short* __restrict__ A,
                                                  const unsigned short* __restrict__ W,
                                                  const float* __restrict__ bias,
                                                  float* __restrict__ Cout) {
    const int K = 1024, N = 512;
    int m0 = blockIdx.x * 128, n0 = blockIdx.y * 128;
    int tid = threadIdx.x, w = tid >> 6, l = tid & 63;
    int wr = w >> 1, wc = w & 1;
    __shared__ short As[4096];
    __shared__ short Bs[4096];
    int idA0 = tid, idA1 = tid + 256;
    int rA0 = idA0 >> 2, sA0 = idA0 & 3, rA1 = idA1 >> 2, sA1 = idA1 & 3;
    int ldsA0 = rA0 * 32 + swz_slot(sA0, rA0) * 8;
    int ldsA1 = rA1 * 32 + swz_slot(sA1, rA1) * 8;
    const unsigned short* pA0 = A + (size_t)(m0 + rA0) * K + sA0 * 8;
    const unsigned short* pA1 = A + (size_t)(m0 + rA1) * K + sA1 * 8;
    const unsigned short* pB0 = W + (size_t)(n0 + rA0) * K + sA0 * 8;
    const unsigned short* pB1 = W + (size_t)(n0 + rA1) * K + sA1 * 8;
    int p = l >> 4, lr = l & 15;
    int aoff[4], boff[4];
#pragma unroll
    for (int t = 0; t < 4; ++t) {
        int r = wr * 64 + t * 16 + lr;
        aoff[t] = r * 32 + swz_slot(p, r) * 8;
        int cq = wc * 64 + t * 16 + lr;
        boff[t] = cq * 32 + swz_slot(p, cq) * 8;
    }
    f32x4 acc[4][4];
#pragma unroll
    for (int i = 0; i < 4; ++i)
#pragma unroll
        for (int j = 0; j < 4; ++j) acc[i][j] = (f32x4)0.0f;
    for (int kt = 0; kt < K; kt += 32) {
        uint4 va0 = *(const uint4*)pA0;
        uint4 va1 = *(const uint4*)pA1;
        uint4 vb0 = *(const uint4*)pB0;
        uint4 vb1 = *(const uint4*)pB1;
        __syncthreads();
        *(uint4*)&As[ldsA0] = va0;
        *(uint4*)&As[ldsA1] = va1;
        *(uint4*)&Bs[ldsA0] = vb0;
        *(uint4*)&Bs[ldsA1] = vb1;
        __syncthreads();
        bf16x8 af[4], bfr[4];
#pragma unroll
        for (int t = 0; t < 4; ++t) {
            af[t] = *(bf16x8*)&As[aoff[t]];
            bfr[t] = *(bf16x8*)&Bs[boff[t]];
        }
#pragma unroll
        for (int i = 0; i < 4; ++i)
#pragma unroll
            for (int j = 0; j < 4; ++j)
                acc[i][j] = __builtin_amdgcn_mfma_f32_16x16x32_bf16(af[i], bfr[j], acc[i][j], 0, 0, 0);
        pA0 += 32; pA1 += 32; pB0 += 32; pB1 += 32;
    }
#pragma unroll
    for (int i = 0; i < 4; ++i)
#pragma unroll
        for (int j = 0; j < 4; ++j) {
            int col = n0 + wc * 64 + j * 16 + lr;
            float bb = bias[col];
#pragma unroll
            for (int reg = 0; reg < 4; ++reg) {
                int row = m0 + wr * 64 + i * 16 + p * 4 + reg;
                Cout[(size_t)row * N + col] = acc[i][j][reg] + bb;
            }
        }
}

// fuse2: z2 = LN(y1+z, mixn); out = LN(y1+z2, n2). y1 read as bf16.
__global__ __launch_bounds__(128) void fuse2_kernel(const unsigned short* __restrict__ y1b,
                                                    const float* __restrict__ z,
                                                    const float* __restrict__ mg,
                                                    const float* __restrict__ mb,
                                                    const float* __restrict__ g2,
                                                    const float* __restrict__ b2v,
                                                    float* __restrict__ out) {
    int row = blockIdx.x, tid = threadIdx.x, c = tid * 4;
    __shared__ float r1[2], r2[2];
    uint2 yu = *(const uint2*)&y1b[(size_t)row * 512 + c];
    float4 a;
    a.x = __uint_as_float(yu.x << 16);
    a.y = __uint_as_float(yu.x & 0xffff0000u);
    a.z = __uint_as_float(yu.y << 16);
    a.w = __uint_as_float(yu.y & 0xffff0000u);
    float4 zv = *(const float4*)&z[(size_t)row * 512 + c];
    float4 t1;
    t1.x = a.x + zv.x; t1.y = a.y + zv.y; t1.z = a.z + zv.z; t1.w = a.w + zv.w;
    float s1 = t1.x + t1.y + t1.z + t1.w;
    float s2 = t1.x * t1.x + t1.y * t1.y + t1.z * t1.z + t1.w * t1.w;
#pragma unroll
    for (int off = 32; off > 0; off >>= 1) {
        s1 += __shfl_down(s1, off, 64);
        s2 += __shfl_down(s2, off, 64);
    }
    if ((tid & 63) == 0) { r1[tid >> 6] = s1; r2[tid >> 6] = s2; }
    __syncthreads();
    float mean = (r1[0] + r1[1]) * (1.0f / 512.0f);
    float var = (r2[0] + r2[1]) * (1.0f / 512.0f) - mean * mean;
    float rstd = rsqrtf(var + 1e-5f);
    float4 mg4 = *(const float4*)&mg[c];
    float4 mb4 = *(const float4*)&mb[c];
    float4 t2;
    t2.x = a.x + ((t1.x - mean) * rstd * mg4.x + mb4.x);
    t2.y = a.y + ((t1.y - mean) * rstd * mg4.y + mb4.y);
    t2.z = a.z + ((t1.z - mean) * rstd * mg4.z + mb4.z);
    t2.w = a.w + ((t1.w - mean) * rstd * mg4.w + mb4.w);
    __syncthreads();
    s1 = t2.x + t2.y + t2.z + t2.w;
    s2 = t2.x * t2.x + t2.y * t2.y + t2.z * t2.z + t2.w * t2.w;
#pragma unroll
    for (int off = 32; off > 0; off >>= 1) {
        s1 += __shfl_down(s1, off, 64);
        s2 += __shfl_down(s2, off, 64);
    }
    if ((tid & 63) == 0) { r1[tid >> 6] = s1; r2[tid >> 6] = s2; }
    __syncthreads();
    float mean2 = (r1[0] + r1[1]) * (1.0f / 512.0f);
    float var2 = (r2[0] + r2[1]) * (1.0f / 512.0f) - mean2 * mean2;
    float rstd2 = rsqrtf(var2 + 1e-5f);
    float4 gg = *(const float4*)&g2[c];
    float4 bb = *(const float4*)&b2v[c];
    float4 o;
    o.x = (t2.x - mean2) * rstd2 * gg.x + bb.x;
    o.y = (t2.y - mean2) * rstd2 * gg.y + bb.y;
    o.z = (t2.z - mean2) * rstd2 * gg.z + bb.z;
    o.w = (t2.w - mean2) * rstd2 * gg.w + bb.w;
    *(float4*)&out[(size_t)row * 512 + c] = o;
}

// ---------------------------------------------------------------------------
// Workspace (floats), total 19,570,752 = ~78.3 MB. Aliases as before.
// ---------------------------------------------------------------------------
extern "C" void kernel_launch(void* const* d_in, const int* in_sizes, int n_in,
                              void* d_out, int out_size, void* d_ws, size_t ws_size,
                              hipStream_t stream) {
    (void)in_sizes; (void)n_in; (void)out_size; (void)ws_size;
    const float* x      = (const float*)d_in[0];
    const float* Bp     = (const float*)d_in[1];
    const float* Cp     = (const float*)d_in[2];
    const float* Dp     = (const float*)d_in[3];
    const float* log_dt = (const float*)d_in[4];
    const float* se_w1  = (const float*)d_in[5];
    const float* se_b1  = (const float*)d_in[6];
    const float* se_w2  = (const float*)d_in[7];
    const float* se_b2  = (const float*)d_in[8];
    const float* n1g    = (const float*)d_in[9];
    const float* n1b    = (const float*)d_in[10];
    const float* up_w   = (const float*)d_in[11];
    const float* up_b   = (const float*)d_in[12];
    const float* dn_w   = (const float*)d_in[13];
    const float* dn_b   = (const float*)d_in[14];
    const float* mxg    = (const float*)d_in[15];
    const float* mxb    = (const float*)d_in[16];
    const float* n2g    = (const float*)d_in[17];
    const float* n2b    = (const float*)d_in[18];

    float* ws    = (float*)d_ws;
    float* Kr    = ws + 0;         //   524288
    float* AbarT = ws + 524288;    //    16384
    float* A32   = ws + 540672;    //    16384
    float* Bbar  = ws + 557056;    //   131072
    float* dtb   = ws + 688128;    //       64
    float* Kpart = ws + 688192;    //  2097152
    float* xT    = ws + 2785344;   //  4194304
    float* yb    = ws + 6979648;   //  4194304  (y in [b][t][c])
    float* ssum  = ws + 11173952;  //     4096
    float* gbuf  = ws + 11178048;  //     4096
    float* yT    = ws + 11182144;  //  4194304  (conv out [b][c][t]; later y1b)
    float* zb    = ws + 15376448;  //  4194304
    unsigned short* up_wb = (unsigned short*)(ws + 688192);
    unsigned short* dn_wb = (unsigned short*)(ws + 950336);
    unsigned short* act   = (unsigned short*)(ws + 2785344);   // aliases xT
    unsigned short* y1b   = (unsigned short*)(ws + 11182144);  // aliases yT
    float* outp  = (float*)d_out;

    hipLaunchKernelGGL(prep_comp, dim3(4), dim3(256), 0, stream, log_dt, AbarT, A32, dtb);
    hipLaunchKernelGGL(compute_bbar, dim3(8), dim3(256), 0, stream, Bp, dtb, Bbar);
    hipLaunchKernelGGL(compute_K, dim3(512, 4), dim3(256), 0, stream, Cp, Bbar, AbarT, A32, Dp, Kpart);
    hipLaunchKernelGGL(reduce_K, dim3(2048), dim3(256), 0, stream, Kpart, Kr);
    hipLaunchKernelGGL(f32_to_bf16, dim3(512), dim3(256), 0, stream, up_w, up_wb, 131072);
    hipLaunchKernelGGL(f32_to_bf16, dim3(256), dim3(256), 0, stream, dn_w, dn_wb, 65536);
    hipLaunchKernelGGL(transpose_bmat, dim3(32, 16, 8), dim3(256), 0, stream, x, xT, 1024, 512);
    hipLaunchKernelGGL(conv_mfma, dim3(512), dim3(256), 0, stream, xT, Kr, yT, ssum);
    hipLaunchKernelGGL(se_kernel, dim3(8), dim3(256), 0, stream, ssum, se_w1, se_b1, se_w2, se_b2, gbuf);
    hipLaunchKernelGGL(transpose_bmat, dim3(16, 32, 8), dim3(256), 0, stream, yT, yb, 512, 1024);
    hipLaunchKernelGGL(fuse1_kernel, dim3(8192), dim3(128), 0, stream, x, yb, gbuf, n1g, n1b, y1b);
    hipLaunchKernelGGL(gemm_glu, dim3(64, 16), dim3(256), 0, stream, y1b, up_wb, up_b, act);
    hipLaunchKernelGGL(gemm_plain, dim3(64, 4), dim3(256), 0, stream, act, dn_wb, dn_b, zb);
    hipLaunchKernelGGL(fuse2_kernel, dim3(8192), dim3(128), 0, stream, y1b, zb, mxg, mxb, n2g, n2b, outp);
}

// Round 5
// 263.466 us; speedup vs baseline: 3.2399x; 1.2794x over previous
//
#include <hip/hip_runtime.h>
#include <math.h>

// Sizes: B=8, L=1024, D=512, N=64, NC=4, HIDDEN=1024, up rows=2048, R=64

typedef short bf16x8 __attribute__((ext_vector_type(8)));
typedef float f32x4 __attribute__((ext_vector_type(4)));

__device__ __forceinline__ float sigmoidf_(float x) { return 1.0f / (1.0f + expf(-x)); }
__device__ __forceinline__ float geluf_(float x) { return 0.5f * x * (1.0f + erff(x * 0.70710678118654752f)); }
__device__ __forceinline__ unsigned short f2bf(float f) {
    unsigned u = __float_as_uint(f);
    unsigned r = (u + 0x7FFFu + ((u >> 16) & 1u)) >> 16;
    return (unsigned short)r;
}
__device__ __forceinline__ unsigned pk2(unsigned short a, unsigned short b) {
    return (unsigned)a | ((unsigned)b << 16);
}

// ---------------------------------------------------------------------------
// P1: A_bar via rank-1 O(N) forward substitution, then 9 squarings storing
// Pow[comp][s] = Abar^(2^s), s=0..9 (f32). 4 blocks.
// ---------------------------------------------------------------------------
__global__ __launch_bounds__(256) void prep_comp(const float* __restrict__ log_dt,
                                                 float* __restrict__ Pow,
                                                 float* __restrict__ dtbuf) {
    int comp = blockIdx.x, tid = threadIdx.x;
    __shared__ __align__(16) float M1[4096];
    __shared__ __align__(16) float M1T[4096];
    __shared__ __align__(16) float M2[4096];
    __shared__ __align__(16) float M2T[4096];
    float ldt = log_dt[comp];
    float dt = log1pf(expf(ldt)) + 1e-6f;
    float hdt = 0.5f * dt;
    if (tid < 64) {
        int j = tid;
        float sqj = sqrtf(2.0f * (float)j + 1.0f);
        float S = 0.0f;
        for (int i = 0; i < 64; ++i) {
            float sqi = sqrtf(2.0f * (float)i + 1.0f);
            float r = (i == j) ? (1.0f - hdt * (float)(i + 1))
                               : ((i > j) ? (-hdt * sqi * sqj) : 0.0f);
            float X = (r - hdt * sqi * S) / (1.0f + hdt * (float)(i + 1));
            M1[i * 64 + j] = X;
            M1T[j * 64 + i] = X;
            S += sqi * X;
        }
    }
    __syncthreads();
    for (int ii = tid; ii < 4096; ii += 256) Pow[(size_t)comp * 40960 + ii] = M1[ii];
    float* cur = M1; float* curT = M1T; float* nxt = M2; float* nxtT = M2T;
    int ti = tid >> 4, tj = tid & 15;
    for (int s = 1; s <= 9; ++s) {
        float c[4][4] = {{0}};
        if (ti >= tj) {
            for (int k = tj * 4; k < ti * 4 + 4; ++k) {
                float4 a = *(const float4*)&curT[k * 64 + ti * 4];
                float4 b = *(const float4*)&cur[k * 64 + tj * 4];
                c[0][0] += a.x * b.x; c[0][1] += a.x * b.y; c[0][2] += a.x * b.z; c[0][3] += a.x * b.w;
                c[1][0] += a.y * b.x; c[1][1] += a.y * b.y; c[1][2] += a.y * b.z; c[1][3] += a.y * b.w;
                c[2][0] += a.z * b.x; c[2][1] += a.z * b.y; c[2][2] += a.z * b.z; c[2][3] += a.z * b.w;
                c[3][0] += a.w * b.x; c[3][1] += a.w * b.y; c[3][2] += a.w * b.z; c[3][3] += a.w * b.w;
            }
        }
#pragma unroll
        for (int r = 0; r < 4; ++r) {
            float4 row; row.x = c[r][0]; row.y = c[r][1]; row.z = c[r][2]; row.w = c[r][3];
            *(float4*)&nxt[(ti * 4 + r) * 64 + tj * 4] = row;
            float4 colv; colv.x = c[0][r]; colv.y = c[1][r]; colv.z = c[2][r]; colv.w = c[3][r];
            *(float4*)&nxtT[(tj * 4 + r) * 64 + ti * 4] = colv;
        }
        __syncthreads();
        for (int ii = tid; ii < 4096; ii += 256) Pow[(size_t)comp * 40960 + s * 4096 + ii] = nxt[ii];
        float* t0 = cur; cur = nxt; nxt = t0;
        float* t1 = curT; curT = nxtT; nxtT = t1;
        __syncthreads();
    }
    if (tid == 0) dtbuf[comp] = dt;
}

// ---------------------------------------------------------------------------
// P2: B_bar rows, rank-1 O(N) per thread.
// ---------------------------------------------------------------------------
__global__ __launch_bounds__(256) void compute_bbar(const float* __restrict__ Bp,
                                                    const float* __restrict__ dtbuf,
                                                    float* __restrict__ Bbar) {
    int gid = blockIdx.x * 256 + threadIdx.x;
    int comp = gid >> 9;
    float dt = dtbuf[comp];
    float hdt = 0.5f * dt;
    const float* bp = Bp + (size_t)gid * 64;
    float* out = Bbar + (size_t)gid * 64;
    float S = 0.0f;
    for (int i = 0; i < 64; ++i) {
        float sqi = sqrtf(2.0f * (float)i + 1.0f);
        float y = (dt * bp[i] - hdt * sqi * S) / (1.0f + hdt * (float)(i + 1));
        out[i] = y;
        S += sqi * y;
    }
}

// f32 -> (hi, lo) bf16 split, 8 elems/thread.
__global__ __launch_bounds__(256) void f32_to_bf16_hl(const float* __restrict__ in,
                                                      unsigned short* __restrict__ oh,
                                                      unsigned short* __restrict__ ol,
                                                      int n8) {
    int i = blockIdx.x * 256 + threadIdx.x;
    if (i >= n8) return;
    float4 a = ((const float4*)in)[2 * i];
    float4 b = ((const float4*)in)[2 * i + 1];
    float vv[8] = {a.x, a.y, a.z, a.w, b.x, b.y, b.z, b.w};
    unsigned short hs[8], ls[8];
#pragma unroll
    for (int j = 0; j < 8; ++j) {
        unsigned short h = f2bf(vv[j]);
        hs[j] = h;
        ls[j] = f2bf(vv[j] - __uint_as_float((unsigned)h << 16));
    }
    uint4 ho, lo;
    ho.x = pk2(hs[0], hs[1]); ho.y = pk2(hs[2], hs[3]); ho.z = pk2(hs[4], hs[5]); ho.w = pk2(hs[6], hs[7]);
    lo.x = pk2(ls[0], ls[1]); lo.y = pk2(ls[2], ls[3]); lo.z = pk2(ls[4], ls[5]); lo.w = pk2(ls[6], ls[7]);
    *(uint4*)&oh[(size_t)i * 8] = ho;
    *(uint4*)&ol[(size_t)i * 8] = lo;
}

// ---------------------------------------------------------------------------
// power_mats: block (idx, comp). idx<32: P_r = Abar^idx -> Pst[(r,n)][k]=P[n][k].
// idx>=32: Q_q = Abar^(32q) -> Qst[(q,n)][m]=Q[m][n]. Binary exponentiation
// from Pow squarings (matrix powers commute). f32 in LDS; bf16 hi/lo out.
// ---------------------------------------------------------------------------
__global__ __launch_bounds__(256) void power_mats(const float* __restrict__ Pow,
                                                  unsigned short* __restrict__ Pst_h,
                                                  unsigned short* __restrict__ Pst_l,
                                                  unsigned short* __restrict__ Qst_h,
                                                  unsigned short* __restrict__ Qst_l) {
    int idx = blockIdx.x, comp = blockIdx.y, tid = threadIdx.x;
    __shared__ __align__(16) float R[4096], RT[4096], R2[4096], R2T[4096], SbT[4096];
    int isP = (idx < 32) ? 1 : 0;
    int f = isP ? idx : (idx - 32);
    int base_s = isP ? 0 : 5;
    const float* PowC = Pow + (size_t)comp * 40960;
    int i_ = tid & 63, kc = (tid >> 6) * 16;
    float* cur = R; float* curT = RT; float* nx = R2; float* nxT = R2T;
    if (f == 0) {
        for (int ii = tid; ii < 4096; ii += 256) {
            float v = ((ii >> 6) == (ii & 63)) ? 1.0f : 0.0f;
            R[ii] = v; RT[ii] = v;
        }
        __syncthreads();
    } else {
        int b0 = __ffs(f) - 1;
        const float* S0 = PowC + (size_t)(base_s + b0) * 4096;
#pragma unroll
        for (int j = 0; j < 16; j += 4) {
            float4 v = *(const float4*)&S0[i_ * 64 + kc + j];
            *(float4*)&R[i_ * 64 + kc + j] = v;
            RT[(kc + j + 0) * 64 + i_] = v.x;
            RT[(kc + j + 1) * 64 + i_] = v.y;
            RT[(kc + j + 2) * 64 + i_] = v.z;
            RT[(kc + j + 3) * 64 + i_] = v.w;
        }
        int rem = f & ~(1 << b0);
        int ti = tid >> 4, tj = tid & 15;
        __syncthreads();
        while (rem) {
            int b = __ffs(rem) - 1; rem &= rem - 1;
            const float* Sb = PowC + (size_t)(base_s + b) * 4096;
#pragma unroll
            for (int j = 0; j < 16; j += 4) {
                float4 v = *(const float4*)&Sb[i_ * 64 + kc + j];
                SbT[(kc + j + 0) * 64 + i_] = v.x;
                SbT[(kc + j + 1) * 64 + i_] = v.y;
                SbT[(kc + j + 2) * 64 + i_] = v.z;
                SbT[(kc + j + 3) * 64 + i_] = v.w;
            }
            __syncthreads();
            float c[4][4] = {{0}};
            if (ti >= tj) {
                for (int k = tj * 4; k < ti * 4 + 4; ++k) {
                    float4 a = *(const float4*)&SbT[k * 64 + ti * 4];
                    float4 b4 = *(const float4*)&cur[k * 64 + tj * 4];
                    c[0][0] += a.x * b4.x; c[0][1] += a.x * b4.y; c[0][2] += a.x * b4.z; c[0][3] += a.x * b4.w;
                    c[1][0] += a.y * b4.x; c[1][1] += a.y * b4.y; c[1][2] += a.y * b4.z; c[1][3] += a.y * b4.w;
                    c[2][0] += a.z * b4.x; c[2][1] += a.z * b4.y; c[2][2] += a.z * b4.z; c[2][3] += a.z * b4.w;
                    c[3][0] += a.w * b4.x; c[3][1] += a.w * b4.y; c[3][2] += a.w * b4.z; c[3][3] += a.w * b4.w;
                }
            }
#pragma unroll
            for (int r = 0; r < 4; ++r) {
                float4 row; row.x = c[r][0]; row.y = c[r][1]; row.z = c[r][2]; row.w = c[r][3];
                *(float4*)&nx[(ti * 4 + r) * 64 + tj * 4] = row;
                float4 colv; colv.x = c[0][r]; colv.y = c[1][r]; colv.z = c[2][r]; colv.w = c[3][r];
                *(float4*)&nxT[(tj * 4 + r) * 64 + ti * 4] = colv;
            }
            __syncthreads();
            float* t0 = cur; cur = nx; nx = t0;
            float* t1 = curT; curT = nxT; nxT = t1;
        }
    }
    const float* src = isP ? cur : curT;
    int outrow = isP ? idx : (idx - 32);
    unsigned short* dh = (isP ? Pst_h : Qst_h) + (size_t)comp * 131072 + (size_t)outrow * 4096;
    unsigned short* dl = (isP ? Pst_l : Qst_l) + (size_t)comp * 131072 + (size_t)outrow * 4096;
    for (int ii = tid * 8; ii < 4096; ii += 2048) {
        float4 v0 = *(const float4*)&src[ii];
        float4 v1 = *(const float4*)&src[ii + 4];
        float vv[8] = {v0.x, v0.y, v0.z, v0.w, v1.x, v1.y, v1.z, v1.w};
        unsigned short hs[8], ls[8];
#pragma unroll
        for (int j = 0; j < 8; ++j) {
            unsigned short h = f2bf(vv[j]);
            hs[j] = h;
            ls[j] = f2bf(vv[j] - __uint_as_float((unsigned)h << 16));
        }
        uint4 ho, lo;
        ho.x = pk2(hs[0], hs[1]); ho.y = pk2(hs[2], hs[3]); ho.z = pk2(hs[4], hs[5]); ho.w = pk2(hs[6], hs[7]);
        lo.x = pk2(ls[0], ls[1]); lo.y = pk2(ls[2], ls[3]); lo.z = pk2(ls[4], ls[5]); lo.w = pk2(ls[6], ls[7]);
        *(uint4*)&dh[ii] = ho;
        *(uint4*)&dl[ii] = lo;
    }
}

// ---------------------------------------------------------------------------
// kgemm_uv: C[comp] = A[comp] (512x64) @ B[comp]^T (2048x64), hi/lo bf16
// 3-product MFMA, K=64 single shot in LDS. Out bf16 hi/lo [comp][512][2048].
// Grid (4, 32, 4), 256 threads.
// ---------------------------------------------------------------------------
__global__ __launch_bounds__(256) void kgemm_uv(const unsigned short* __restrict__ Ah,
                                                const unsigned short* __restrict__ Al,
                                                const unsigned short* __restrict__ Bh,
                                                const unsigned short* __restrict__ Bl,
                                                unsigned short* __restrict__ Ch,
                                                unsigned short* __restrict__ Cl) {
    int m0 = blockIdx.x * 128, n0 = blockIdx.y * 64, comp = blockIdx.z;
    int tid = threadIdx.x, w = tid >> 6, l = tid & 63;
    __shared__ __align__(16) short Ash[8192], Asl[8192], Bsh[4096], Bsl[4096];
    const unsigned short* Abh = Ah + (size_t)comp * 32768;
    const unsigned short* Abl = Al + (size_t)comp * 32768;
    const unsigned short* Bbh = Bh + (size_t)comp * 131072;
    const unsigned short* Bbl = Bl + (size_t)comp * 131072;
#pragma unroll
    for (int i = 0; i < 4; ++i) {
        int cid = tid + 256 * i;
        int row = cid >> 3, slot = cid & 7;
        int goff = (m0 + row) * 64 + slot * 8;
        int loff = row * 64 + (slot ^ (row & 7)) * 8;
        *(uint4*)&Ash[loff] = *(const uint4*)(Abh + goff);
        *(uint4*)&Asl[loff] = *(const uint4*)(Abl + goff);
    }
#pragma unroll
    for (int i = 0; i < 2; ++i) {
        int cid = tid + 256 * i;
        int row = cid >> 3, slot = cid & 7;
        int goff = (n0 + row) * 64 + slot * 8;
        int loff = row * 64 + (slot ^ (row & 7)) * 8;
        *(uint4*)&Bsh[loff] = *(const uint4*)(Bbh + goff);
        *(uint4*)&Bsl[loff] = *(const uint4*)(Bbl + goff);
    }
    __syncthreads();
    int p = l >> 4, lr = l & 15;
    f32x4 acc[2][4];
#pragma unroll
    for (int rt = 0; rt < 2; ++rt)
#pragma unroll
        for (int ct = 0; ct < 4; ++ct) acc[rt][ct] = (f32x4)0.0f;
#pragma unroll
    for (int ks = 0; ks < 2; ++ks) {
        bf16x8 ah2[2], al2[2], bh2[4], bl2[4];
#pragma unroll
        for (int rt = 0; rt < 2; ++rt) {
            int row = w * 32 + rt * 16 + lr;
            int off = row * 64 + ((ks * 4 + p) ^ (row & 7)) * 8;
            ah2[rt] = *(bf16x8*)&Ash[off];
            al2[rt] = *(bf16x8*)&Asl[off];
        }
#pragma unroll
        for (int ct = 0; ct < 4; ++ct) {
            int cr = ct * 16 + lr;
            int off = cr * 64 + ((ks * 4 + p) ^ (cr & 7)) * 8;
            bh2[ct] = *(bf16x8*)&Bsh[off];
            bl2[ct] = *(bf16x8*)&Bsl[off];
        }
#pragma unroll
        for (int rt = 0; rt < 2; ++rt)
#pragma unroll
            for (int ct = 0; ct < 4; ++ct) {
                acc[rt][ct] = __builtin_amdgcn_mfma_f32_16x16x32_bf16(ah2[rt], bh2[ct], acc[rt][ct], 0, 0, 0);
                acc[rt][ct] = __builtin_amdgcn_mfma_f32_16x16x32_bf16(ah2[rt], bl2[ct], acc[rt][ct], 0, 0, 0);
                acc[rt][ct] = __builtin_amdgcn_mfma_f32_16x16x32_bf16(al2[rt], bh2[ct], acc[rt][ct], 0, 0, 0);
            }
    }
#pragma unroll
    for (int rt = 0; rt < 2; ++rt)
#pragma unroll
        for (int ct = 0; ct < 4; ++ct) {
#pragma unroll
            for (int reg = 0; reg < 4; ++reg) {
                int row = m0 + w * 32 + rt * 16 + p * 4 + reg;
                int col = n0 + ct * 16 + lr;
                float v = acc[rt][ct][reg];
                unsigned short h = f2bf(v);
                unsigned short lo2 = f2bf(v - __uint_as_float((unsigned)h << 16));
                size_t o = (size_t)comp * 1048576 + (size_t)row * 2048 + col;
                Ch[o] = h;
                Cl[o] = lo2;
            }
        }
}

// ---------------------------------------------------------------------------
// kgemm_k: per (comp,d): Kpart[g][32q+r] = sum_n U[g][q*64+n] * V[g][r*64+n].
// One wave per g, 4 g per block, operands straight from global.
// ---------------------------------------------------------------------------
__global__ __launch_bounds__(256) void kgemm_k(const unsigned short* __restrict__ Uh,
                                               const unsigned short* __restrict__ Ul,
                                               const unsigned short* __restrict__ Vh,
                                               const unsigned short* __restrict__ Vl,
                                               float* __restrict__ Kpart) {
    int tid = threadIdx.x, w = tid >> 6, l = tid & 63;
    int g = blockIdx.x * 4 + w;
    int p = l >> 4, lr = l & 15;
    const unsigned short* ubh = Uh + (size_t)g * 2048;
    const unsigned short* ubl = Ul + (size_t)g * 2048;
    const unsigned short* vbh = Vh + (size_t)g * 2048;
    const unsigned short* vbl = Vl + (size_t)g * 2048;
    f32x4 acc[2][2];
    acc[0][0] = (f32x4)0.0f; acc[0][1] = (f32x4)0.0f;
    acc[1][0] = (f32x4)0.0f; acc[1][1] = (f32x4)0.0f;
#pragma unroll
    for (int ks = 0; ks < 2; ++ks) {
        bf16x8 uh2[2], ul2[2], vh2[2], vl2[2];
#pragma unroll
        for (int mt = 0; mt < 2; ++mt) {
            int off = (mt * 16 + lr) * 64 + ks * 32 + p * 8;
            uh2[mt] = *(const bf16x8*)(ubh + off);
            ul2[mt] = *(const bf16x8*)(ubl + off);
            vh2[mt] = *(const bf16x8*)(vbh + off);
            vl2[mt] = *(const bf16x8*)(vbl + off);
        }
#pragma unroll
        for (int mt = 0; mt < 2; ++mt)
#pragma unroll
            for (int nt = 0; nt < 2; ++nt) {
                acc[mt][nt] = __builtin_amdgcn_mfma_f32_16x16x32_bf16(uh2[mt], vh2[nt], acc[mt][nt], 0, 0, 0);
                acc[mt][nt] = __builtin_amdgcn_mfma_f32_16x16x32_bf16(uh2[mt], vl2[nt], acc[mt][nt], 0, 0, 0);
                acc[mt][nt] = __builtin_amdgcn_mfma_f32_16x16x32_bf16(ul2[mt], vh2[nt], acc[mt][nt], 0, 0, 0);
            }
    }
#pragma unroll
    for (int mt = 0; mt < 2; ++mt)
#pragma unroll
        for (int nt = 0; nt < 2; ++nt)
#pragma unroll
            for (int reg = 0; reg < 4; ++reg) {
                int q = mt * 16 + p * 4 + reg;
                int r = nt * 16 + lr;
                Kpart[(size_t)g * 1024 + q * 32 + r] = acc[mt][nt][reg];
            }
}

// Sum over components + D (at l=0), REVERSE time index.
__global__ __launch_bounds__(256) void reduce_K(const float* __restrict__ Kpart,
                                                const float* __restrict__ Dp,
                                                float* __restrict__ Kr) {
    int idx = blockIdx.x * 256 + threadIdx.x;
    int d = idx >> 10, l = idx & 1023;
    float s = Kpart[idx] + Kpart[524288 + idx] + Kpart[1048576 + idx] + Kpart[1572864 + idx];
    if (l == 0) s += Dp[d] + Dp[512 + d] + Dp[1024 + d] + Dp[1536 + d];
    Kr[(size_t)d * 1024 + (1023 - l)] = s;
}

// Generic batched transpose: in [B][R][C] -> out [B][C][R]
__global__ __launch_bounds__(256) void transpose_bmat(const float* __restrict__ in,
                                                      float* __restrict__ out,
                                                      int R, int C) {
    __shared__ float tile[32][33];
    int r0 = blockIdx.x * 32, c0 = blockIdx.y * 32, b = blockIdx.z;
    int tx = threadIdx.x & 31, ty = threadIdx.x >> 5;
#pragma unroll
    for (int m = 0; m < 4; ++m)
        tile[ty + 8 * m][tx] = in[((size_t)b * R + r0 + ty + 8 * m) * C + c0 + tx];
    __syncthreads();
#pragma unroll
    for (int m = 0; m < 4; ++m)
        out[((size_t)b * C + c0 + ty + 8 * m) * R + r0 + tx] = tile[tx][ty + 8 * m];
}

// ---------------------------------------------------------------------------
// MFMA depthwise conv (unchanged).
// ---------------------------------------------------------------------------
__global__ __launch_bounds__(256) void conv_mfma(const float* __restrict__ xT,
                                                 const float* __restrict__ Kr,
                                                 float* __restrict__ yT,
                                                 float* __restrict__ ssum) {
    int c = blockIdx.x, tid = threadIdx.x;
    int w = tid >> 6, l = tid & 63;
    __shared__ __align__(16) float krp[1088];
    __shared__ __align__(16) short xh[8512], xl[8512];
    __shared__ __align__(16) short gh[10240], gl[10240];
    __shared__ float ssh[64];

    {
        float4 kv = *(const float4*)&Kr[(size_t)c * 1024 + tid * 4];
        *(float4*)&krp[32 + tid * 4] = kv;
        if (tid < 8) *(float4*)&krp[tid * 4] = make_float4(0, 0, 0, 0);
        else if (tid < 16) *(float4*)&krp[1056 + (tid - 8) * 4] = make_float4(0, 0, 0, 0);
    }
    if (tid < 32) {
        int b = tid >> 2, g = tid & 3;
        uint4 z = {0, 0, 0, 0};
        *(uint4*)&xh[(b * 133 + g) * 8] = z;
    } else if (tid < 64) {
        int t2 = tid - 32; int b = t2 >> 2, g = t2 & 3;
        uint4 z = {0, 0, 0, 0};
        *(uint4*)&xl[(b * 133 + g) * 8] = z;
    }
#pragma unroll
    for (int i = 0; i < 4; ++i) {
        int gid = tid + 256 * i;
        int b = gid >> 7, gt = gid & 127;
        const float* src = &xT[((size_t)(b * 512 + c)) * 1024 + gt * 8];
        float4 v0 = *(const float4*)src;
        float4 v1 = *(const float4*)(src + 4);
        float vv[8] = {v0.x, v0.y, v0.z, v0.w, v1.x, v1.y, v1.z, v1.w};
        unsigned short hsv[8], lsv[8];
#pragma unroll
        for (int j2 = 0; j2 < 8; ++j2) {
            unsigned short h = f2bf(vv[j2]);
            hsv[j2] = h;
            lsv[j2] = f2bf(vv[j2] - __uint_as_float((unsigned)h << 16));
        }
        uint4 hh, ll;
        hh.x = pk2(hsv[0], hsv[1]); hh.y = pk2(hsv[2], hsv[3]);
        hh.z = pk2(hsv[4], hsv[5]); hh.w = pk2(hsv[6], hsv[7]);
        ll.x = pk2(lsv[0], lsv[1]); ll.y = pk2(lsv[2], lsv[3]);
        ll.z = pk2(lsv[4], lsv[5]); ll.w = pk2(lsv[6], lsv[7]);
        int off = (b * 133 + 4 + gt) * 8;
        *(uint4*)&xh[off] = hh;
        *(uint4*)&xl[off] = ll;
    }
    __syncthreads();

    f32x4 acc[4][2];
#pragma unroll
    for (int i = 0; i < 4; ++i) { acc[i][0] = (f32x4)0.0f; acc[i][1] = (f32x4)0.0f; }

    int lr = l & 15, kg4 = l >> 4;
    for (int ch = 0; ch < 4; ++ch) {
        int dq0 = ch * 8;
        {
            int dqloc = tid >> 5, n = tid & 31, dq = dq0 + dqloc;
            int s0 = 32 * dq + n + 1;
            int a0 = s0 & ~3, sh = s0 & 3;
            float ff[36];
#pragma unroll
            for (int i = 0; i < 9; ++i) *(float4*)&ff[i * 4] = *(const float4*)&krp[a0 + i * 4];
            unsigned short hsv[32], lsv[32];
#pragma unroll
            for (int k = 0; k < 32; ++k) {
                int j2 = 31 - k;
                float v = (sh == 0) ? ff[j2] : (sh == 1) ? ff[j2 + 1] : (sh == 2) ? ff[j2 + 2] : ff[j2 + 3];
                unsigned short h = f2bf(v);
                hsv[k] = h;
                lsv[k] = f2bf(v - __uint_as_float((unsigned)h << 16));
            }
            int gbase = (dqloc * 32 + n) * 5 * 8;
#pragma unroll
            for (int kg = 0; kg < 4; ++kg) {
                uint4 hh, ll;
                hh.x = pk2(hsv[8 * kg + 0], hsv[8 * kg + 1]);
                hh.y = pk2(hsv[8 * kg + 2], hsv[8 * kg + 3]);
                hh.z = pk2(hsv[8 * kg + 4], hsv[8 * kg + 5]);
                hh.w = pk2(hsv[8 * kg + 6], hsv[8 * kg + 7]);
                ll.x = pk2(lsv[8 * kg + 0], lsv[8 * kg + 1]);
                ll.y = pk2(lsv[8 * kg + 2], lsv[8 * kg + 3]);
                ll.z = pk2(lsv[8 * kg + 4], lsv[8 * kg + 5]);
                ll.w = pk2(lsv[8 * kg + 6], lsv[8 * kg + 7]);
                *(uint4*)&gh[gbase + kg * 8] = hh;
                *(uint4*)&gl[gbase + kg * 8] = ll;
            }
        }
        __syncthreads();
        for (int dqloc = 0; dqloc < 8; ++dqloc) {
            int dq = dq0 + dqloc;
            bf16x8 bh[2], bl[2];
#pragma unroll
            for (int nf = 0; nf < 2; ++nf) {
                int go = ((dqloc * 32 + nf * 16 + lr) * 5 + kg4) * 8;
                bh[nf] = *(bf16x8*)&gh[go];
                bl[nf] = *(bf16x8*)&gl[go];
            }
#pragma unroll
            for (int ffi = 0; ffi < 4; ++ffi) {
                int F = w + 4 * ffi;
                if (2 * F + 1 < dq) continue;
                int b = lr & 7, qoff = lr >> 3;
                int q = 2 * F + qoff;
                int j = 4 * (q - dq) + kg4 + 4;
                int xo = (b * 133 + j) * 8;
                bf16x8 ah = *(bf16x8*)&xh[xo];
                bf16x8 al = *(bf16x8*)&xl[xo];
#pragma unroll
                for (int nf = 0; nf < 2; ++nf) {
                    acc[ffi][nf] = __builtin_amdgcn_mfma_f32_16x16x32_bf16(ah, bh[nf], acc[ffi][nf], 0, 0, 0);
                    acc[ffi][nf] = __builtin_amdgcn_mfma_f32_16x16x32_bf16(al, bh[nf], acc[ffi][nf], 0, 0, 0);
                    acc[ffi][nf] = __builtin_amdgcn_mfma_f32_16x16x32_bf16(ah, bl[nf], acc[ffi][nf], 0, 0, 0);
                }
            }
        }
        __syncthreads();
    }

    float bsum[4] = {0, 0, 0, 0};
#pragma unroll
    for (int ffi = 0; ffi < 4; ++ffi) {
        int F = w + 4 * ffi;
#pragma unroll
        for (int nf = 0; nf < 2; ++nf) {
#pragma unroll
            for (int reg = 0; reg < 4; ++reg) {
                int mloc = 4 * kg4 + reg;
                int b = mloc & 7;
                int q = 2 * F + (mloc >> 3);
                int t = 32 * q + nf * 16 + lr;
                yT[((size_t)(b * 512 + c)) * 1024 + t] = acc[ffi][nf][reg];
                bsum[reg] += acc[ffi][nf][reg];
            }
        }
    }
#pragma unroll
    for (int off = 1; off < 16; off <<= 1) {
#pragma unroll
        for (int reg = 0; reg < 4; ++reg) bsum[reg] += __shfl_xor(bsum[reg], off, 64);
    }
    if (lr == 0) {
#pragma unroll
        for (int reg = 0; reg < 4; ++reg) ssh[w * 16 + kg4 * 4 + reg] = bsum[reg];
    }
    __syncthreads();
    if (tid < 8) {
        float tot = 0.0f;
        for (int w2 = 0; w2 < 4; ++w2) tot += ssh[w2 * 16 + tid] + ssh[w2 * 16 + 8 + tid];
        ssum[tid * 512 + c] = tot;
    }
}

__global__ __launch_bounds__(256) void se_kernel(const float* __restrict__ ssum,
                                                 const float* __restrict__ w1,
                                                 const float* __restrict__ b1,
                                                 const float* __restrict__ w2,
                                                 const float* __restrict__ b2,
                                                 float* __restrict__ g) {
    int b = blockIdx.x, tid = threadIdx.x;
    __shared__ float s_sh[512];
    __shared__ float part[256];
    __shared__ float h_sh[64];
    for (int c = tid; c < 512; c += 256) s_sh[c] = ssum[b * 512 + c] * (1.0f / 1024.0f);
    __syncthreads();
    int r = tid & 63, seg = tid >> 6;
    float p = 0.0f;
    for (int c = seg * 128; c < seg * 128 + 128; ++c) p += s_sh[c] * w1[r * 512 + c];
    part[tid] = p;
    __syncthreads();
    if (tid < 64) {
        float h = part[tid] + part[tid + 64] + part[tid + 128] + part[tid + 192] + b1[tid];
        h_sh[tid] = fmaxf(h, 0.0f);
    }
    __syncthreads();
    for (int c = tid; c < 512; c += 256) {
        float acc = b2[c];
#pragma unroll 8
        for (int rr = 0; rr < 64; ++rr) acc += h_sh[rr] * w2[c * 64 + rr];
        g[b * 512 + c] = 1.0f / (1.0f + expf(-acc));
    }
}

// fuse1: y1b = bf16(LN(x + y*g, n1))
__global__ __launch_bounds__(128) void fuse1_kernel(const float* __restrict__ x,
                                                    const float* __restrict__ y,
                                                    const float* __restrict__ g,
                                                    const float* __restrict__ n1g,
                                                    const float* __restrict__ n1b,
                                                    unsigned short* __restrict__ y1b) {
    int row = blockIdx.x, b = row >> 10, tid = threadIdx.x, c = tid * 4;
    __shared__ float r1[2], r2[2];
    float4 xv = *(const float4*)&x[(size_t)row * 512 + c];
    float4 yv = *(const float4*)&y[(size_t)row * 512 + c];
    float4 gv = *(const float4*)&g[b * 512 + c];
    float4 v;
    v.x = xv.x + yv.x * gv.x; v.y = xv.y + yv.y * gv.y;
    v.z = xv.z + yv.z * gv.z; v.w = xv.w + yv.w * gv.w;
    float s1 = v.x + v.y + v.z + v.w;
    float s2 = v.x * v.x + v.y * v.y + v.z * v.z + v.w * v.w;
#pragma unroll
    for (int off = 32; off > 0; off >>= 1) {
        s1 += __shfl_down(s1, off, 64);
        s2 += __shfl_down(s2, off, 64);
    }
    if ((tid & 63) == 0) { r1[tid >> 6] = s1; r2[tid >> 6] = s2; }
    __syncthreads();
    float mean = (r1[0] + r1[1]) * (1.0f / 512.0f);
    float var = (r2[0] + r2[1]) * (1.0f / 512.0f) - mean * mean;
    float rstd = rsqrtf(var + 1e-5f);
    float4 g4 = *(const float4*)&n1g[c];
    float4 b4 = *(const float4*)&n1b[c];
    float4 o;
    o.x = (v.x - mean) * rstd * g4.x + b4.x; o.y = (v.y - mean) * rstd * g4.y + b4.y;
    o.z = (v.z - mean) * rstd * g4.z + b4.z; o.w = (v.w - mean) * rstd * g4.w + b4.w;
    uint2 pk;
    pk.x = pk2(f2bf(o.x), f2bf(o.y));
    pk.y = pk2(f2bf(o.z), f2bf(o.w));
    *(uint2*)&y1b[(size_t)row * 512 + c] = pk;
}

// f32 -> bf16 (RNE), 8 elems/thread.
__global__ __launch_bounds__(256) void f32_to_bf16(const float* __restrict__ in,
                                                   unsigned short* __restrict__ out,
                                                   int n8) {
    int i = blockIdx.x * 256 + threadIdx.x;
    if (i >= n8) return;
    float4 a = ((const float4*)in)[2 * i];
    float4 b = ((const float4*)in)[2 * i + 1];
    uint4 o;
    o.x = pk2(f2bf(a.x), f2bf(a.y));
    o.y = pk2(f2bf(a.z), f2bf(a.w));
    o.z = pk2(f2bf(b.x), f2bf(b.y));
    o.w = pk2(f2bf(b.z), f2bf(b.w));
    *(uint4*)&out[(size_t)i * 8] = o;
}

__device__ __forceinline__ int swz_slot(int slot, int row) {
    return slot ^ (row & 3) ^ ((row >> 2) & 3);
}

// ---------------------------------------------------------------------------
// GEMM1 + GLU (bf16 MFMA). BM=128, out cols 64/block.
// ---------------------------------------------------------------------------
__global__ __launch_bounds__(256) void gemm_glu(const unsigned short* __restrict__ A,
                                                const unsigned short* __restrict__ W,
                                                const float* __restrict__ bias,
                                                unsigned short* __restrict__ act) {
    const int K = 512;
    int m0 = blockIdx.x * 128, n0 = blockIdx.y * 64;
    int tid = threadIdx.x, w = tid >> 6, l = tid & 63;
    __shared__ short As[4096];
    __shared__ short Bs[4096];
    int idA0 = tid, idA1 = tid + 256;
    int rA0 = idA0 >> 2, sA0 = idA0 & 3, rA1 = idA1 >> 2, sA1 = idA1 & 3;
    int ldsA0 = rA0 * 32 + swz_slot(sA0, rA0) * 8;
    int ldsA1 = rA1 * 32 + swz_slot(sA1, rA1) * 8;
    const unsigned short* pA0 = A + (size_t)(m0 + rA0) * K + sA0 * 8;
    const unsigned short* pA1 = A + (size_t)(m0 + rA1) * K + sA1 * 8;
    int gB0 = (rA0 < 64) ? (n0 + rA0) : (1024 + n0 + rA0 - 64);
    int gB1 = (rA1 < 64) ? (n0 + rA1) : (1024 + n0 + rA1 - 64);
    const unsigned short* pB0 = W + (size_t)gB0 * K + sA0 * 8;
    const unsigned short* pB1 = W + (size_t)gB1 * K + sA1 * 8;
    int p = l >> 4, lr = l & 15;
    int aoff[2], bAoff[4], bGoff[4];
#pragma unroll
    for (int rt = 0; rt < 2; ++rt) {
        int r = w * 32 + rt * 16 + lr;
        aoff[rt] = r * 32 + swz_slot(p, r) * 8;
    }
#pragma unroll
    for (int ct = 0; ct < 4; ++ct) {
        int ca = ct * 16 + lr, cg = 64 + ct * 16 + lr;
        bAoff[ct] = ca * 32 + swz_slot(p, ca) * 8;
        bGoff[ct] = cg * 32 + swz_slot(p, cg) * 8;
    }
    f32x4 accA[2][4], accG[2][4];
#pragma unroll
    for (int rt = 0; rt < 2; ++rt)
#pragma unroll
        for (int ct = 0; ct < 4; ++ct) {
            accA[rt][ct] = (f32x4)0.0f;
            accG[rt][ct] = (f32x4)0.0f;
        }
    for (int kt = 0; kt < K; kt += 32) {
        uint4 va0 = *(const uint4*)pA0;
        uint4 va1 = *(const uint4*)pA1;
        uint4 vb0 = *(const uint4*)pB0;
        uint4 vb1 = *(const uint4*)pB1;
        __syncthreads();
        *(uint4*)&As[ldsA0] = va0;
        *(uint4*)&As[ldsA1] = va1;
        *(uint4*)&Bs[ldsA0] = vb0;
        *(uint4*)&Bs[ldsA1] = vb1;
        __syncthreads();
        bf16x8 af[2], bA[4], bG[4];
#pragma unroll
        for (int rt = 0; rt < 2; ++rt) af[rt] = *(bf16x8*)&As[aoff[rt]];
#pragma unroll
        for (int ct = 0; ct < 4; ++ct) {
            bA[ct] = *(bf16x8*)&Bs[bAoff[ct]];
            bG[ct] = *(bf16x8*)&Bs[bGoff[ct]];
        }
#pragma unroll
        for (int rt = 0; rt < 2; ++rt)
#pragma unroll
            for (int ct = 0; ct < 4; ++ct) {
                accA[rt][ct] = __builtin_amdgcn_mfma_f32_16x16x32_bf16(af[rt], bA[ct], accA[rt][ct], 0, 0, 0);
                accG[rt][ct] = __builtin_amdgcn_mfma_f32_16x16x32_bf16(af[rt], bG[ct], accG[rt][ct], 0, 0, 0);
            }
        pA0 += 32; pA1 += 32; pB0 += 32; pB1 += 32;
    }
#pragma unroll
    for (int rt = 0; rt < 2; ++rt)
#pragma unroll
        for (int ct = 0; ct < 4; ++ct) {
            int col = n0 + ct * 16 + lr;
            float ba = bias[col], bg = bias[1024 + col];
#pragma unroll
            for (int reg = 0; reg < 4; ++reg) {
                int row = m0 + w * 32 + rt * 16 + p * 4 + reg;
                float a = accA[rt][ct][reg] + ba;
                float g = accG[rt][ct][reg] + bg;
                act[(size_t)row * 1024 + col] = f2bf(geluf_(a) * sigmoidf_(g));
            }
        }
}

// ---------------------------------------------------------------------------
// GEMM2 (bf16 MFMA): BM=128, BN=128, 2x2 waves, 4x4 frags. C = A@W^T + bias.
// ---------------------------------------------------------------------------
__global__ __launch_bounds__(256) void gemm_plain(const unsigned short* __restrict__ A,
                                                  const unsigned short* __restrict__ W,
                                                  const float* __restrict__ bias,
                                                  float* __restrict__ Cout) {
    const int K = 1024, N = 512;
    int m0 = blockIdx.x * 128, n0 = blockIdx.y * 128;
    int tid = threadIdx.x, w = tid >> 6, l = tid & 63;
    int wr = w >> 1, wc = w & 1;
    __shared__ short As[4096];
    __shared__ short Bs[4096];
    int idA0 = tid, idA1 = tid + 256;
    int rA0 = idA0 >> 2, sA0 = idA0 & 3, rA1 = idA1 >> 2, sA1 = idA1 & 3;
    int ldsA0 = rA0 * 32 + swz_slot(sA0, rA0) * 8;
    int ldsA1 = rA1 * 32 + swz_slot(sA1, rA1) * 8;
    const unsigned short* pA0 = A + (size_t)(m0 + rA0) * K + sA0 * 8;
    const unsigned short* pA1 = A + (size_t)(m0 + rA1) * K + sA1 * 8;
    const unsigned short* pB0 = W + (size_t)(n0 + rA0) * K + sA0 * 8;
    const unsigned short* pB1 = W + (size_t)(n0 + rA1) * K + sA1 * 8;
    int p = l >> 4, lr = l & 15;
    int aoff[4], boff[4];
#pragma unroll
    for (int t = 0; t < 4; ++t) {
        int r = wr * 64 + t * 16 + lr;
        aoff[t] = r * 32 + swz_slot(p, r) * 8;
        int cq = wc * 64 + t * 16 + lr;
        boff[t] = cq * 32 + swz_slot(p, cq) * 8;
    }
    f32x4 acc[4][4];
#pragma unroll
    for (int i = 0; i < 4; ++i)
#pragma unroll
        for (int j = 0; j < 4; ++j) acc[i][j] = (f32x4)0.0f;
    for (int kt = 0; kt < K; kt += 32) {
        uint4 va0 = *(const uint4*)pA0;
        uint4 va1 = *(const uint4*)pA1;
        uint4 vb0 = *(const uint4*)pB0;
        uint4 vb1 = *(const uint4*)pB1;
        __syncthreads();
        *(uint4*)&As[ldsA0] = va0;
        *(uint4*)&As[ldsA1] = va1;
        *(uint4*)&Bs[ldsA0] = vb0;
        *(uint4*)&Bs[ldsA1] = vb1;
        __syncthreads();
        bf16x8 af[4], bfr[4];
#pragma unroll
        for (int t = 0; t < 4; ++t) {
            af[t] = *(bf16x8*)&As[aoff[t]];
            bfr[t] = *(bf16x8*)&Bs[boff[t]];
        }
#pragma unroll
        for (int i = 0; i < 4; ++i)
#pragma unroll
            for (int j = 0; j < 4; ++j)
                acc[i][j] = __builtin_amdgcn_mfma_f32_16x16x32_bf16(af[i], bfr[j], acc[i][j], 0, 0, 0);
        pA0 += 32; pA1 += 32; pB0 += 32; pB1 += 32;
    }
#pragma unroll
    for (int i = 0; i < 4; ++i)
#pragma unroll
        for (int j = 0; j < 4; ++j) {
            int col = n0 + wc * 64 + j * 16 + lr;
            float bb = bias[col];
#pragma unroll
            for (int reg = 0; reg < 4; ++reg) {
                int row = m0 + wr * 64 + i * 16 + p * 4 + reg;
                Cout[(size_t)row * N + col] = acc[i][j][reg] + bb;
            }
        }
}

// fuse2: z2 = LN(y1+z, mixn); out = LN(y1+z2, n2). y1 read as bf16.
__global__ __launch_bounds__(128) void fuse2_kernel(const unsigned short* __restrict__ y1b,
                                                    const float* __restrict__ z,
                                                    const float* __restrict__ mg,
                                                    const float* __restrict__ mb,
                                                    const float* __restrict__ g2,
                                                    const float* __restrict__ b2v,
                                                    float* __restrict__ out) {
    int row = blockIdx.x, tid = threadIdx.x, c = tid * 4;
    __shared__ float r1[2], r2[2];
    uint2 yu = *(const uint2*)&y1b[(size_t)row * 512 + c];
    float4 a;
    a.x = __uint_as_float(yu.x << 16);
    a.y = __uint_as_float(yu.x & 0xffff0000u);
    a.z = __uint_as_float(yu.y << 16);
    a.w = __uint_as_float(yu.y & 0xffff0000u);
    float4 zv = *(const float4*)&z[(size_t)row * 512 + c];
    float4 t1;
    t1.x = a.x + zv.x; t1.y = a.y + zv.y; t1.z = a.z + zv.z; t1.w = a.w + zv.w;
    float s1 = t1.x + t1.y + t1.z + t1.w;
    float s2 = t1.x * t1.x + t1.y * t1.y + t1.z * t1.z + t1.w * t1.w;
#pragma unroll
    for (int off = 32; off > 0; off >>= 1) {
        s1 += __shfl_down(s1, off, 64);
        s2 += __shfl_down(s2, off, 64);
    }
    if ((tid & 63) == 0) { r1[tid >> 6] = s1; r2[tid >> 6] = s2; }
    __syncthreads();
    float mean = (r1[0] + r1[1]) * (1.0f / 512.0f);
    float var = (r2[0] + r2[1]) * (1.0f / 512.0f) - mean * mean;
    float rstd = rsqrtf(var + 1e-5f);
    float4 mg4 = *(const float4*)&mg[c];
    float4 mb4 = *(const float4*)&mb[c];
    float4 t2;
    t2.x = a.x + ((t1.x - mean) * rstd * mg4.x + mb4.x);
    t2.y = a.y + ((t1.y - mean) * rstd * mg4.y + mb4.y);
    t2.z = a.z + ((t1.z - mean) * rstd * mg4.z + mb4.z);
    t2.w = a.w + ((t1.w - mean) * rstd * mg4.w + mb4.w);
    __syncthreads();
    s1 = t2.x + t2.y + t2.z + t2.w;
    s2 = t2.x * t2.x + t2.y * t2.y + t2.z * t2.z + t2.w * t2.w;
#pragma unroll
    for (int off = 32; off > 0; off >>= 1) {
        s1 += __shfl_down(s1, off, 64);
        s2 += __shfl_down(s2, off, 64);
    }
    if ((tid & 63) == 0) { r1[tid >> 6] = s1; r2[tid >> 6] = s2; }
    __syncthreads();
    float mean2 = (r1[0] + r1[1]) * (1.0f / 512.0f);
    float var2 = (r2[0] + r2[1]) * (1.0f / 512.0f) - mean2 * mean2;
    float rstd2 = rsqrtf(var2 + 1e-5f);
    float4 gg = *(const float4*)&g2[c];
    float4 bb = *(const float4*)&b2v[c];
    float4 o;
    o.x = (t2.x - mean2) * rstd2 * gg.x + bb.x;
    o.y = (t2.y - mean2) * rstd2 * gg.y + bb.y;
    o.z = (t2.z - mean2) * rstd2 * gg.z + bb.z;
    o.w = (t2.w - mean2) * rstd2 * gg.w + bb.w;
    *(float4*)&out[(size_t)row * 512 + c] = o;
}

// ---------------------------------------------------------------------------
// Workspace layout (float offsets). High-water 17,604,672 floats (~70.4 MB),
// within the 19,570,752-float budget used since round 1.
//   K-phase:  Pow/Bb/Cp hi-lo/Pst/Qst/Kpart/U/V
//   Phase 2+: xT over U region, yT over V region, y1b over yT, act over xT,
//             zb over yb. up_wb/dn_wb NON-overlapping (round-3/4 overlap fixed).
// ---------------------------------------------------------------------------
extern "C" void kernel_launch(void* const* d_in, const int* in_sizes, int n_in,
                              void* d_out, int out_size, void* d_ws, size_t ws_size,
                              hipStream_t stream) {
    (void)in_sizes; (void)n_in; (void)out_size; (void)ws_size;
    const float* x      = (const float*)d_in[0];
    const float* Bp     = (const float*)d_in[1];
    const float* Cp     = (const float*)d_in[2];
    const float* Dp     = (const float*)d_in[3];
    const float* log_dt = (const float*)d_in[4];
    const float* se_w1  = (const float*)d_in[5];
    const float* se_b1  = (const float*)d_in[6];
    const float* se_w2  = (const float*)d_in[7];
    const float* se_b2  = (const float*)d_in[8];
    const float* n1g    = (const float*)d_in[9];
    const float* n1b    = (const float*)d_in[10];
    const float* up_w   = (const float*)d_in[11];
    const float* up_b   = (const float*)d_in[12];
    const float* dn_w   = (const float*)d_in[13];
    const float* dn_b   = (const float*)d_in[14];
    const float* mxg    = (const float*)d_in[15];
    const float* mxb    = (const float*)d_in[16];
    const float* n2g    = (const float*)d_in[17];
    const float* n2b    = (const float*)d_in[18];

    float* ws = (float*)d_ws;
    float* Kr   = ws + 0;          //   524,288
    float* dtb  = ws + 524288;     //        64
    float* ssum = ws + 524352;     //     4,096
    float* gbuf = ws + 528448;     //     4,096
    unsigned short* up_wb = (unsigned short*)(ws + 532544);   // 524,288 fl
    unsigned short* dn_wb = (unsigned short*)(ws + 1056832);  // 262,144 fl
    float* Bbar = ws + 1318976;    //   131,072
    float* Pow  = ws + 1450048;    //   163,840
    unsigned short* Bb_h = (unsigned short*)(ws + 1613888);   // 65,536 fl
    unsigned short* Bb_l = (unsigned short*)(ws + 1679424);
    unsigned short* Cp_h = (unsigned short*)(ws + 1744960);
    unsigned short* Cp_l = (unsigned short*)(ws + 1810496);
    unsigned short* Pst_h = (unsigned short*)(ws + 1876032);  // 262,144 fl each
    unsigned short* Pst_l = (unsigned short*)(ws + 2138176);
    unsigned short* Qst_h = (unsigned short*)(ws + 2400320);
    unsigned short* Qst_l = (unsigned short*)(ws + 2662464);
    float* Kpart = ws + 2924608;   // 2,097,152
    unsigned short* U_h = (unsigned short*)(ws + 5021760);    // 2,097,152 fl
    unsigned short* U_l = (unsigned short*)(ws + 7118912);
    unsigned short* V_h = (unsigned short*)(ws + 9216064);
    unsigned short* V_l = (unsigned short*)(ws + 11313216);
    float* xT   = ws + 5021760;    // alias U_h+U_l (dead after kgemm_k)
    float* yT   = ws + 9216064;    // alias V_h+V_l
    float* yb   = ws + 13410368;   // 4,194,304 (fresh)
    unsigned short* y1b = (unsigned short*)(ws + 9216064);    // alias yT after use
    unsigned short* act = (unsigned short*)(ws + 5021760);    // alias xT after conv
    float* zb   = ws + 13410368;   // alias yb after fuse1
    float* outp = (float*)d_out;

    // --- K pipeline ---
    hipLaunchKernelGGL(prep_comp, dim3(4), dim3(256), 0, stream, log_dt, Pow, dtb);
    hipLaunchKernelGGL(compute_bbar, dim3(8), dim3(256), 0, stream, Bp, dtb, Bbar);
    hipLaunchKernelGGL(f32_to_bf16_hl, dim3(64), dim3(256), 0, stream, Bbar, Bb_h, Bb_l, 16384);
    hipLaunchKernelGGL(f32_to_bf16_hl, dim3(64), dim3(256), 0, stream, Cp, Cp_h, Cp_l, 16384);
    hipLaunchKernelGGL(power_mats, dim3(64, 4), dim3(256), 0, stream, Pow, Pst_h, Pst_l, Qst_h, Qst_l);
    hipLaunchKernelGGL(kgemm_uv, dim3(4, 32, 4), dim3(256), 0, stream, Bb_h, Bb_l, Pst_h, Pst_l, V_h, V_l);
    hipLaunchKernelGGL(kgemm_uv, dim3(4, 32, 4), dim3(256), 0, stream, Cp_h, Cp_l, Qst_h, Qst_l, U_h, U_l);
    hipLaunchKernelGGL(kgemm_k, dim3(512), dim3(256), 0, stream, U_h, U_l, V_h, V_l, Kpart);
    hipLaunchKernelGGL(reduce_K, dim3(2048), dim3(256), 0, stream, Kpart, Dp, Kr);
    // --- weights ---
    hipLaunchKernelGGL(f32_to_bf16, dim3(512), dim3(256), 0, stream, up_w, up_wb, 131072);
    hipLaunchKernelGGL(f32_to_bf16, dim3(256), dim3(256), 0, stream, dn_w, dn_wb, 65536);
    // --- conv + block ---
    hipLaunchKernelGGL(transpose_bmat, dim3(32, 16, 8), dim3(256), 0, stream, x, xT, 1024, 512);
    hipLaunchKernelGGL(conv_mfma, dim3(512), dim3(256), 0, stream, xT, Kr, yT, ssum);
    hipLaunchKernelGGL(se_kernel, dim3(8), dim3(256), 0, stream, ssum, se_w1, se_b1, se_w2, se_b2, gbuf);
    hipLaunchKernelGGL(transpose_bmat, dim3(16, 32, 8), dim3(256), 0, stream, yT, yb, 512, 1024);
    hipLaunchKernelGGL(fuse1_kernel, dim3(8192), dim3(128), 0, stream, x, yb, gbuf, n1g, n1b, y1b);
    hipLaunchKernelGGL(gemm_glu, dim3(64, 16), dim3(256), 0, stream, y1b, up_wb, up_b, act);
    hipLaunchKernelGGL(gemm_plain, dim3(64, 4), dim3(256), 0, stream, act, dn_wb, dn_b, zb);
    hipLaunchKernelGGL(fuse2_kernel, dim3(8192), dim3(128), 0, stream, y1b, zb, mxg, mxb, n2g, n2b, outp);
}

// Round 6
// 240.180 us; speedup vs baseline: 3.5540x; 1.0970x over previous
//
#include <hip/hip_runtime.h>
#include <math.h>

// Sizes: B=8, L=1024, D=512, N=64, NC=4, HIDDEN=1024, up rows=2048, R=64

typedef short bf16x8 __attribute__((ext_vector_type(8)));
typedef float f32x4 __attribute__((ext_vector_type(4)));

__device__ __forceinline__ float sigmoidf_(float x) { return 1.0f / (1.0f + expf(-x)); }
__device__ __forceinline__ float geluf_(float x) { return 0.5f * x * (1.0f + erff(x * 0.70710678118654752f)); }
__device__ __forceinline__ unsigned short f2bf(float f) {
    unsigned u = __float_as_uint(f);
    unsigned r = (u + 0x7FFFu + ((u >> 16) & 1u)) >> 16;
    return (unsigned short)r;
}
__device__ __forceinline__ unsigned pk2(unsigned short a, unsigned short b) {
    return (unsigned)a | ((unsigned)b << 16);
}

// ---------------------------------------------------------------------------
// P1: A_bar via rank-1 O(N) forward substitution, then 9 squarings storing
// Pow[comp][s] = Abar^(2^s), s=0..9 (f32). 4 blocks.
// Squaring k-loop is UNIFORM 0..63 (upper-tri zeros contribute exact 0s via
// fma) + unroll 8 -> ~16 ds_read_b128 in flight, hides LDS latency (round-5
// fix: variable bounds serialized on LDS latency, 230 cyc/iter).
// ---------------------------------------------------------------------------
__global__ __launch_bounds__(256) void prep_comp(const float* __restrict__ log_dt,
                                                 float* __restrict__ Pow,
                                                 float* __restrict__ dtbuf) {
    int comp = blockIdx.x, tid = threadIdx.x;
    __shared__ __align__(16) float M1[4096];
    __shared__ __align__(16) float M1T[4096];
    __shared__ __align__(16) float M2[4096];
    __shared__ __align__(16) float M2T[4096];
    float ldt = log_dt[comp];
    float dt = log1pf(expf(ldt)) + 1e-6f;
    float hdt = 0.5f * dt;
    if (tid < 64) {
        int j = tid;
        float sqj = sqrtf(2.0f * (float)j + 1.0f);
        float S = 0.0f;
        for (int i = 0; i < 64; ++i) {
            float sqi = sqrtf(2.0f * (float)i + 1.0f);
            float r = (i == j) ? (1.0f - hdt * (float)(i + 1))
                               : ((i > j) ? (-hdt * sqi * sqj) : 0.0f);
            float X = (r - hdt * sqi * S) / (1.0f + hdt * (float)(i + 1));
            M1[i * 64 + j] = X;
            M1T[j * 64 + i] = X;
            S += sqi * X;
        }
    }
    __syncthreads();
    for (int ii = tid; ii < 4096; ii += 256) Pow[(size_t)comp * 40960 + ii] = M1[ii];
    float* cur = M1; float* curT = M1T; float* nxt = M2; float* nxtT = M2T;
    int ti = tid >> 4, tj = tid & 15;
    for (int s = 1; s <= 9; ++s) {
        float c[4][4] = {{0}};
#pragma unroll 8
        for (int k = 0; k < 64; ++k) {
            float4 a = *(const float4*)&curT[k * 64 + ti * 4];
            float4 b = *(const float4*)&cur[k * 64 + tj * 4];
            c[0][0] += a.x * b.x; c[0][1] += a.x * b.y; c[0][2] += a.x * b.z; c[0][3] += a.x * b.w;
            c[1][0] += a.y * b.x; c[1][1] += a.y * b.y; c[1][2] += a.y * b.z; c[1][3] += a.y * b.w;
            c[2][0] += a.z * b.x; c[2][1] += a.z * b.y; c[2][2] += a.z * b.z; c[2][3] += a.z * b.w;
            c[3][0] += a.w * b.x; c[3][1] += a.w * b.y; c[3][2] += a.w * b.z; c[3][3] += a.w * b.w;
        }
#pragma unroll
        for (int r = 0; r < 4; ++r) {
            float4 row; row.x = c[r][0]; row.y = c[r][1]; row.z = c[r][2]; row.w = c[r][3];
            *(float4*)&nxt[(ti * 4 + r) * 64 + tj * 4] = row;
            float4 colv; colv.x = c[0][r]; colv.y = c[1][r]; colv.z = c[2][r]; colv.w = c[3][r];
            *(float4*)&nxtT[(tj * 4 + r) * 64 + ti * 4] = colv;
        }
        __syncthreads();
        for (int ii = tid; ii < 4096; ii += 256) Pow[(size_t)comp * 40960 + s * 4096 + ii] = nxt[ii];
        float* t0 = cur; cur = nxt; nxt = t0;
        float* t1 = curT; curT = nxtT; nxtT = t1;
        __syncthreads();
    }
    if (tid == 0) dtbuf[comp] = dt;
}

// ---------------------------------------------------------------------------
// P2: B_bar rows, rank-1 O(N) per thread.
// ---------------------------------------------------------------------------
__global__ __launch_bounds__(256) void compute_bbar(const float* __restrict__ Bp,
                                                    const float* __restrict__ dtbuf,
                                                    float* __restrict__ Bbar) {
    int gid = blockIdx.x * 256 + threadIdx.x;
    int comp = gid >> 9;
    float dt = dtbuf[comp];
    float hdt = 0.5f * dt;
    const float* bp = Bp + (size_t)gid * 64;
    float* out = Bbar + (size_t)gid * 64;
    float S = 0.0f;
    for (int i = 0; i < 64; ++i) {
        float sqi = sqrtf(2.0f * (float)i + 1.0f);
        float y = (dt * bp[i] - hdt * sqi * S) / (1.0f + hdt * (float)(i + 1));
        out[i] = y;
        S += sqi * y;
    }
}

// f32 -> (hi, lo) bf16 split, 8 elems/thread.
__global__ __launch_bounds__(256) void f32_to_bf16_hl(const float* __restrict__ in,
                                                      unsigned short* __restrict__ oh,
                                                      unsigned short* __restrict__ ol,
                                                      int n8) {
    int i = blockIdx.x * 256 + threadIdx.x;
    if (i >= n8) return;
    float4 a = ((const float4*)in)[2 * i];
    float4 b = ((const float4*)in)[2 * i + 1];
    float vv[8] = {a.x, a.y, a.z, a.w, b.x, b.y, b.z, b.w};
    unsigned short hs[8], ls[8];
#pragma unroll
    for (int j = 0; j < 8; ++j) {
        unsigned short h = f2bf(vv[j]);
        hs[j] = h;
        ls[j] = f2bf(vv[j] - __uint_as_float((unsigned)h << 16));
    }
    uint4 ho, lo;
    ho.x = pk2(hs[0], hs[1]); ho.y = pk2(hs[2], hs[3]); ho.z = pk2(hs[4], hs[5]); ho.w = pk2(hs[6], hs[7]);
    lo.x = pk2(ls[0], ls[1]); lo.y = pk2(ls[2], ls[3]); lo.z = pk2(ls[4], ls[5]); lo.w = pk2(ls[6], ls[7]);
    *(uint4*)&oh[(size_t)i * 8] = ho;
    *(uint4*)&ol[(size_t)i * 8] = lo;
}

// ---------------------------------------------------------------------------
// power_mats: block (idx, comp). idx<32: P_r = Abar^idx -> Pst[(r,n)][k]=P[n][k].
// idx>=32: Q_q = Abar^(32q) -> Qst[(q,n)][m]=Q[m][n]. Binary exponentiation
// from Pow squarings. f32 in LDS; bf16 hi/lo out.
// ---------------------------------------------------------------------------
__global__ __launch_bounds__(256) void power_mats(const float* __restrict__ Pow,
                                                  unsigned short* __restrict__ Pst_h,
                                                  unsigned short* __restrict__ Pst_l,
                                                  unsigned short* __restrict__ Qst_h,
                                                  unsigned short* __restrict__ Qst_l) {
    int idx = blockIdx.x, comp = blockIdx.y, tid = threadIdx.x;
    __shared__ __align__(16) float R[4096], RT[4096], R2[4096], R2T[4096], SbT[4096];
    int isP = (idx < 32) ? 1 : 0;
    int f = isP ? idx : (idx - 32);
    int base_s = isP ? 0 : 5;
    const float* PowC = Pow + (size_t)comp * 40960;
    int i_ = tid & 63, kc = (tid >> 6) * 16;
    float* cur = R; float* curT = RT; float* nx = R2; float* nxT = R2T;
    if (f == 0) {
        for (int ii = tid; ii < 4096; ii += 256) {
            float v = ((ii >> 6) == (ii & 63)) ? 1.0f : 0.0f;
            R[ii] = v; RT[ii] = v;
        }
        __syncthreads();
    } else {
        int b0 = __ffs(f) - 1;
        const float* S0 = PowC + (size_t)(base_s + b0) * 4096;
#pragma unroll
        for (int j = 0; j < 16; j += 4) {
            float4 v = *(const float4*)&S0[i_ * 64 + kc + j];
            *(float4*)&R[i_ * 64 + kc + j] = v;
            RT[(kc + j + 0) * 64 + i_] = v.x;
            RT[(kc + j + 1) * 64 + i_] = v.y;
            RT[(kc + j + 2) * 64 + i_] = v.z;
            RT[(kc + j + 3) * 64 + i_] = v.w;
        }
        int rem = f & ~(1 << b0);
        int ti = tid >> 4, tj = tid & 15;
        __syncthreads();
        while (rem) {
            int b = __ffs(rem) - 1; rem &= rem - 1;
            const float* Sb = PowC + (size_t)(base_s + b) * 4096;
#pragma unroll
            for (int j = 0; j < 16; j += 4) {
                float4 v = *(const float4*)&Sb[i_ * 64 + kc + j];
                SbT[(kc + j + 0) * 64 + i_] = v.x;
                SbT[(kc + j + 1) * 64 + i_] = v.y;
                SbT[(kc + j + 2) * 64 + i_] = v.z;
                SbT[(kc + j + 3) * 64 + i_] = v.w;
            }
            __syncthreads();
            float c[4][4] = {{0}};
#pragma unroll 8
            for (int k = 0; k < 64; ++k) {
                float4 a = *(const float4*)&SbT[k * 64 + ti * 4];
                float4 b4 = *(const float4*)&cur[k * 64 + tj * 4];
                c[0][0] += a.x * b4.x; c[0][1] += a.x * b4.y; c[0][2] += a.x * b4.z; c[0][3] += a.x * b4.w;
                c[1][0] += a.y * b4.x; c[1][1] += a.y * b4.y; c[1][2] += a.y * b4.z; c[1][3] += a.y * b4.w;
                c[2][0] += a.z * b4.x; c[2][1] += a.z * b4.y; c[2][2] += a.z * b4.z; c[2][3] += a.z * b4.w;
                c[3][0] += a.w * b4.x; c[3][1] += a.w * b4.y; c[3][2] += a.w * b4.z; c[3][3] += a.w * b4.w;
            }
#pragma unroll
            for (int r = 0; r < 4; ++r) {
                float4 row; row.x = c[r][0]; row.y = c[r][1]; row.z = c[r][2]; row.w = c[r][3];
                *(float4*)&nx[(ti * 4 + r) * 64 + tj * 4] = row;
                float4 colv; colv.x = c[0][r]; colv.y = c[1][r]; colv.z = c[2][r]; colv.w = c[3][r];
                *(float4*)&nxT[(tj * 4 + r) * 64 + ti * 4] = colv;
            }
            __syncthreads();
            float* t0 = cur; cur = nx; nx = t0;
            float* t1 = curT; curT = nxT; nxT = t1;
        }
    }
    const float* src = isP ? cur : curT;
    int outrow = isP ? idx : (idx - 32);
    unsigned short* dh = (isP ? Pst_h : Qst_h) + (size_t)comp * 131072 + (size_t)outrow * 4096;
    unsigned short* dl = (isP ? Pst_l : Qst_l) + (size_t)comp * 131072 + (size_t)outrow * 4096;
    for (int ii = tid * 8; ii < 4096; ii += 2048) {
        float4 v0 = *(const float4*)&src[ii];
        float4 v1 = *(const float4*)&src[ii + 4];
        float vv[8] = {v0.x, v0.y, v0.z, v0.w, v1.x, v1.y, v1.z, v1.w};
        unsigned short hs[8], ls[8];
#pragma unroll
        for (int j = 0; j < 8; ++j) {
            unsigned short h = f2bf(vv[j]);
            hs[j] = h;
            ls[j] = f2bf(vv[j] - __uint_as_float((unsigned)h << 16));
        }
        uint4 ho, lo;
        ho.x = pk2(hs[0], hs[1]); ho.y = pk2(hs[2], hs[3]); ho.z = pk2(hs[4], hs[5]); ho.w = pk2(hs[6], hs[7]);
        lo.x = pk2(ls[0], ls[1]); lo.y = pk2(ls[2], ls[3]); lo.z = pk2(ls[4], ls[5]); lo.w = pk2(ls[6], ls[7]);
        *(uint4*)&dh[ii] = ho;
        *(uint4*)&dl[ii] = lo;
    }
}

// ---------------------------------------------------------------------------
// kgemm_uv: C[comp] = A[comp] (512x64) @ B[comp]^T (2048x64), hi/lo bf16
// 3-product MFMA. Out bf16 hi/lo [comp][512][2048]. Grid (4, 32, 4).
// ---------------------------------------------------------------------------
__global__ __launch_bounds__(256) void kgemm_uv(const unsigned short* __restrict__ Ah,
                                                const unsigned short* __restrict__ Al,
                                                const unsigned short* __restrict__ Bh,
                                                const unsigned short* __restrict__ Bl,
                                                unsigned short* __restrict__ Ch,
                                                unsigned short* __restrict__ Cl) {
    int m0 = blockIdx.x * 128, n0 = blockIdx.y * 64, comp = blockIdx.z;
    int tid = threadIdx.x, w = tid >> 6, l = tid & 63;
    __shared__ __align__(16) short Ash[8192], Asl[8192], Bsh[4096], Bsl[4096];
    const unsigned short* Abh = Ah + (size_t)comp * 32768;
    const unsigned short* Abl = Al + (size_t)comp * 32768;
    const unsigned short* Bbh = Bh + (size_t)comp * 131072;
    const unsigned short* Bbl = Bl + (size_t)comp * 131072;
#pragma unroll
    for (int i = 0; i < 4; ++i) {
        int cid = tid + 256 * i;
        int row = cid >> 3, slot = cid & 7;
        int goff = (m0 + row) * 64 + slot * 8;
        int loff = row * 64 + (slot ^ (row & 7)) * 8;
        *(uint4*)&Ash[loff] = *(const uint4*)(Abh + goff);
        *(uint4*)&Asl[loff] = *(const uint4*)(Abl + goff);
    }
#pragma unroll
    for (int i = 0; i < 2; ++i) {
        int cid = tid + 256 * i;
        int row = cid >> 3, slot = cid & 7;
        int goff = (n0 + row) * 64 + slot * 8;
        int loff = row * 64 + (slot ^ (row & 7)) * 8;
        *(uint4*)&Bsh[loff] = *(const uint4*)(Bbh + goff);
        *(uint4*)&Bsl[loff] = *(const uint4*)(Bbl + goff);
    }
    __syncthreads();
    int p = l >> 4, lr = l & 15;
    f32x4 acc[2][4];
#pragma unroll
    for (int rt = 0; rt < 2; ++rt)
#pragma unroll
        for (int ct = 0; ct < 4; ++ct) acc[rt][ct] = (f32x4)0.0f;
#pragma unroll
    for (int ks = 0; ks < 2; ++ks) {
        bf16x8 ah2[2], al2[2], bh2[4], bl2[4];
#pragma unroll
        for (int rt = 0; rt < 2; ++rt) {
            int row = w * 32 + rt * 16 + lr;
            int off = row * 64 + ((ks * 4 + p) ^ (row & 7)) * 8;
            ah2[rt] = *(bf16x8*)&Ash[off];
            al2[rt] = *(bf16x8*)&Asl[off];
        }
#pragma unroll
        for (int ct = 0; ct < 4; ++ct) {
            int cr = ct * 16 + lr;
            int off = cr * 64 + ((ks * 4 + p) ^ (cr & 7)) * 8;
            bh2[ct] = *(bf16x8*)&Bsh[off];
            bl2[ct] = *(bf16x8*)&Bsl[off];
        }
#pragma unroll
        for (int rt = 0; rt < 2; ++rt)
#pragma unroll
            for (int ct = 0; ct < 4; ++ct) {
                acc[rt][ct] = __builtin_amdgcn_mfma_f32_16x16x32_bf16(ah2[rt], bh2[ct], acc[rt][ct], 0, 0, 0);
                acc[rt][ct] = __builtin_amdgcn_mfma_f32_16x16x32_bf16(ah2[rt], bl2[ct], acc[rt][ct], 0, 0, 0);
                acc[rt][ct] = __builtin_amdgcn_mfma_f32_16x16x32_bf16(al2[rt], bh2[ct], acc[rt][ct], 0, 0, 0);
            }
    }
#pragma unroll
    for (int rt = 0; rt < 2; ++rt)
#pragma unroll
        for (int ct = 0; ct < 4; ++ct) {
#pragma unroll
            for (int reg = 0; reg < 4; ++reg) {
                int row = m0 + w * 32 + rt * 16 + p * 4 + reg;
                int col = n0 + ct * 16 + lr;
                float v = acc[rt][ct][reg];
                unsigned short h = f2bf(v);
                unsigned short lo2 = f2bf(v - __uint_as_float((unsigned)h << 16));
                size_t o = (size_t)comp * 1048576 + (size_t)row * 2048 + col;
                Ch[o] = h;
                Cl[o] = lo2;
            }
        }
}

// ---------------------------------------------------------------------------
// kgemm_k: per (comp,d): Kpart[g][32q+r] = sum_n U[g][q*64+n] * V[g][r*64+n].
// ---------------------------------------------------------------------------
__global__ __launch_bounds__(256) void kgemm_k(const unsigned short* __restrict__ Uh,
                                               const unsigned short* __restrict__ Ul,
                                               const unsigned short* __restrict__ Vh,
                                               const unsigned short* __restrict__ Vl,
                                               float* __restrict__ Kpart) {
    int tid = threadIdx.x, w = tid >> 6, l = tid & 63;
    int g = blockIdx.x * 4 + w;
    int p = l >> 4, lr = l & 15;
    const unsigned short* ubh = Uh + (size_t)g * 2048;
    const unsigned short* ubl = Ul + (size_t)g * 2048;
    const unsigned short* vbh = Vh + (size_t)g * 2048;
    const unsigned short* vbl = Vl + (size_t)g * 2048;
    f32x4 acc[2][2];
    acc[0][0] = (f32x4)0.0f; acc[0][1] = (f32x4)0.0f;
    acc[1][0] = (f32x4)0.0f; acc[1][1] = (f32x4)0.0f;
#pragma unroll
    for (int ks = 0; ks < 2; ++ks) {
        bf16x8 uh2[2], ul2[2], vh2[2], vl2[2];
#pragma unroll
        for (int mt = 0; mt < 2; ++mt) {
            int off = (mt * 16 + lr) * 64 + ks * 32 + p * 8;
            uh2[mt] = *(const bf16x8*)(ubh + off);
            ul2[mt] = *(const bf16x8*)(ubl + off);
            vh2[mt] = *(const bf16x8*)(vbh + off);
            vl2[mt] = *(const bf16x8*)(vbl + off);
        }
#pragma unroll
        for (int mt = 0; mt < 2; ++mt)
#pragma unroll
            for (int nt = 0; nt < 2; ++nt) {
                acc[mt][nt] = __builtin_amdgcn_mfma_f32_16x16x32_bf16(uh2[mt], vh2[nt], acc[mt][nt], 0, 0, 0);
                acc[mt][nt] = __builtin_amdgcn_mfma_f32_16x16x32_bf16(uh2[mt], vl2[nt], acc[mt][nt], 0, 0, 0);
                acc[mt][nt] = __builtin_amdgcn_mfma_f32_16x16x32_bf16(ul2[mt], vh2[nt], acc[mt][nt], 0, 0, 0);
            }
    }
#pragma unroll
    for (int mt = 0; mt < 2; ++mt)
#pragma unroll
        for (int nt = 0; nt < 2; ++nt)
#pragma unroll
            for (int reg = 0; reg < 4; ++reg) {
                int q = mt * 16 + p * 4 + reg;
                int r = nt * 16 + lr;
                Kpart[(size_t)g * 1024 + q * 32 + r] = acc[mt][nt][reg];
            }
}

// Sum over components + D (at l=0), REVERSE time index.
__global__ __launch_bounds__(256) void reduce_K(const float* __restrict__ Kpart,
                                                const float* __restrict__ Dp,
                                                float* __restrict__ Kr) {
    int idx = blockIdx.x * 256 + threadIdx.x;
    int d = idx >> 10, l = idx & 1023;
    float s = Kpart[idx] + Kpart[524288 + idx] + Kpart[1048576 + idx] + Kpart[1572864 + idx];
    if (l == 0) s += Dp[d] + Dp[512 + d] + Dp[1024 + d] + Dp[1536 + d];
    Kr[(size_t)d * 1024 + (1023 - l)] = s;
}

// Generic batched transpose: in [B][R][C] -> out [B][C][R]
__global__ __launch_bounds__(256) void transpose_bmat(const float* __restrict__ in,
                                                      float* __restrict__ out,
                                                      int R, int C) {
    __shared__ float tile[32][33];
    int r0 = blockIdx.x * 32, c0 = blockIdx.y * 32, b = blockIdx.z;
    int tx = threadIdx.x & 31, ty = threadIdx.x >> 5;
#pragma unroll
    for (int m = 0; m < 4; ++m)
        tile[ty + 8 * m][tx] = in[((size_t)b * R + r0 + ty + 8 * m) * C + c0 + tx];
    __syncthreads();
#pragma unroll
    for (int m = 0; m < 4; ++m)
        out[((size_t)b * C + c0 + ty + 8 * m) * R + r0 + tx] = tile[tx][ty + 8 * m];
}

// ---------------------------------------------------------------------------
// MFMA depthwise conv (unchanged).
// ---------------------------------------------------------------------------
__global__ __launch_bounds__(256) void conv_mfma(const float* __restrict__ xT,
                                                 const float* __restrict__ Kr,
                                                 float* __restrict__ yT,
                                                 float* __restrict__ ssum) {
    int c = blockIdx.x, tid = threadIdx.x;
    int w = tid >> 6, l = tid & 63;
    __shared__ __align__(16) float krp[1088];
    __shared__ __align__(16) short xh[8512], xl[8512];
    __shared__ __align__(16) short gh[10240], gl[10240];
    __shared__ float ssh[64];

    {
        float4 kv = *(const float4*)&Kr[(size_t)c * 1024 + tid * 4];
        *(float4*)&krp[32 + tid * 4] = kv;
        if (tid < 8) *(float4*)&krp[tid * 4] = make_float4(0, 0, 0, 0);
        else if (tid < 16) *(float4*)&krp[1056 + (tid - 8) * 4] = make_float4(0, 0, 0, 0);
    }
    if (tid < 32) {
        int b = tid >> 2, g = tid & 3;
        uint4 z = {0, 0, 0, 0};
        *(uint4*)&xh[(b * 133 + g) * 8] = z;
    } else if (tid < 64) {
        int t2 = tid - 32; int b = t2 >> 2, g = t2 & 3;
        uint4 z = {0, 0, 0, 0};
        *(uint4*)&xl[(b * 133 + g) * 8] = z;
    }
#pragma unroll
    for (int i = 0; i < 4; ++i) {
        int gid = tid + 256 * i;
        int b = gid >> 7, gt = gid & 127;
        const float* src = &xT[((size_t)(b * 512 + c)) * 1024 + gt * 8];
        float4 v0 = *(const float4*)src;
        float4 v1 = *(const float4*)(src + 4);
        float vv[8] = {v0.x, v0.y, v0.z, v0.w, v1.x, v1.y, v1.z, v1.w};
        unsigned short hsv[8], lsv[8];
#pragma unroll
        for (int j2 = 0; j2 < 8; ++j2) {
            unsigned short h = f2bf(vv[j2]);
            hsv[j2] = h;
            lsv[j2] = f2bf(vv[j2] - __uint_as_float((unsigned)h << 16));
        }
        uint4 hh, ll;
        hh.x = pk2(hsv[0], hsv[1]); hh.y = pk2(hsv[2], hsv[3]);
        hh.z = pk2(hsv[4], hsv[5]); hh.w = pk2(hsv[6], hsv[7]);
        ll.x = pk2(lsv[0], lsv[1]); ll.y = pk2(lsv[2], lsv[3]);
        ll.z = pk2(lsv[4], lsv[5]); ll.w = pk2(lsv[6], lsv[7]);
        int off = (b * 133 + 4 + gt) * 8;
        *(uint4*)&xh[off] = hh;
        *(uint4*)&xl[off] = ll;
    }
    __syncthreads();

    f32x4 acc[4][2];
#pragma unroll
    for (int i = 0; i < 4; ++i) { acc[i][0] = (f32x4)0.0f; acc[i][1] = (f32x4)0.0f; }

    int lr = l & 15, kg4 = l >> 4;
    for (int ch = 0; ch < 4; ++ch) {
        int dq0 = ch * 8;
        {
            int dqloc = tid >> 5, n = tid & 31, dq = dq0 + dqloc;
            int s0 = 32 * dq + n + 1;
            int a0 = s0 & ~3, sh = s0 & 3;
            float ff[36];
#pragma unroll
            for (int i = 0; i < 9; ++i) *(float4*)&ff[i * 4] = *(const float4*)&krp[a0 + i * 4];
            unsigned short hsv[32], lsv[32];
#pragma unroll
            for (int k = 0; k < 32; ++k) {
                int j2 = 31 - k;
                float v = (sh == 0) ? ff[j2] : (sh == 1) ? ff[j2 + 1] : (sh == 2) ? ff[j2 + 2] : ff[j2 + 3];
                unsigned short h = f2bf(v);
                hsv[k] = h;
                lsv[k] = f2bf(v - __uint_as_float((unsigned)h << 16));
            }
            int gbase = (dqloc * 32 + n) * 5 * 8;
#pragma unroll
            for (int kg = 0; kg < 4; ++kg) {
                uint4 hh, ll;
                hh.x = pk2(hsv[8 * kg + 0], hsv[8 * kg + 1]);
                hh.y = pk2(hsv[8 * kg + 2], hsv[8 * kg + 3]);
                hh.z = pk2(hsv[8 * kg + 4], hsv[8 * kg + 5]);
                hh.w = pk2(hsv[8 * kg + 6], hsv[8 * kg + 7]);
                ll.x = pk2(lsv[8 * kg + 0], lsv[8 * kg + 1]);
                ll.y = pk2(lsv[8 * kg + 2], lsv[8 * kg + 3]);
                ll.z = pk2(lsv[8 * kg + 4], lsv[8 * kg + 5]);
                ll.w = pk2(lsv[8 * kg + 6], lsv[8 * kg + 7]);
                *(uint4*)&gh[gbase + kg * 8] = hh;
                *(uint4*)&gl[gbase + kg * 8] = ll;
            }
        }
        __syncthreads();
        for (int dqloc = 0; dqloc < 8; ++dqloc) {
            int dq = dq0 + dqloc;
            bf16x8 bh[2], bl[2];
#pragma unroll
            for (int nf = 0; nf < 2; ++nf) {
                int go = ((dqloc * 32 + nf * 16 + lr) * 5 + kg4) * 8;
                bh[nf] = *(bf16x8*)&gh[go];
                bl[nf] = *(bf16x8*)&gl[go];
            }
#pragma unroll
            for (int ffi = 0; ffi < 4; ++ffi) {
                int F = w + 4 * ffi;
                if (2 * F + 1 < dq) continue;
                int b = lr & 7, qoff = lr >> 3;
                int q = 2 * F + qoff;
                int j = 4 * (q - dq) + kg4 + 4;
                int xo = (b * 133 + j) * 8;
                bf16x8 ah = *(bf16x8*)&xh[xo];
                bf16x8 al = *(bf16x8*)&xl[xo];
#pragma unroll
                for (int nf = 0; nf < 2; ++nf) {
                    acc[ffi][nf] = __builtin_amdgcn_mfma_f32_16x16x32_bf16(ah, bh[nf], acc[ffi][nf], 0, 0, 0);
                    acc[ffi][nf] = __builtin_amdgcn_mfma_f32_16x16x32_bf16(al, bh[nf], acc[ffi][nf], 0, 0, 0);
                    acc[ffi][nf] = __builtin_amdgcn_mfma_f32_16x16x32_bf16(ah, bl[nf], acc[ffi][nf], 0, 0, 0);
                }
            }
        }
        __syncthreads();
    }

    float bsum[4] = {0, 0, 0, 0};
#pragma unroll
    for (int ffi = 0; ffi < 4; ++ffi) {
        int F = w + 4 * ffi;
#pragma unroll
        for (int nf = 0; nf < 2; ++nf) {
#pragma unroll
            for (int reg = 0; reg < 4; ++reg) {
                int mloc = 4 * kg4 + reg;
                int b = mloc & 7;
                int q = 2 * F + (mloc >> 3);
                int t = 32 * q + nf * 16 + lr;
                yT[((size_t)(b * 512 + c)) * 1024 + t] = acc[ffi][nf][reg];
                bsum[reg] += acc[ffi][nf][reg];
            }
        }
    }
#pragma unroll
    for (int off = 1; off < 16; off <<= 1) {
#pragma unroll
        for (int reg = 0; reg < 4; ++reg) bsum[reg] += __shfl_xor(bsum[reg], off, 64);
    }
    if (lr == 0) {
#pragma unroll
        for (int reg = 0; reg < 4; ++reg) ssh[w * 16 + kg4 * 4 + reg] = bsum[reg];
    }
    __syncthreads();
    if (tid < 8) {
        float tot = 0.0f;
        for (int w2 = 0; w2 < 4; ++w2) tot += ssh[w2 * 16 + tid] + ssh[w2 * 16 + 8 + tid];
        ssum[tid * 512 + c] = tot;
    }
}

__global__ __launch_bounds__(256) void se_kernel(const float* __restrict__ ssum,
                                                 const float* __restrict__ w1,
                                                 const float* __restrict__ b1,
                                                 const float* __restrict__ w2,
                                                 const float* __restrict__ b2,
                                                 float* __restrict__ g) {
    int b = blockIdx.x, tid = threadIdx.x;
    __shared__ float s_sh[512];
    __shared__ float part[256];
    __shared__ float h_sh[64];
    for (int c = tid; c < 512; c += 256) s_sh[c] = ssum[b * 512 + c] * (1.0f / 1024.0f);
    __syncthreads();
    int r = tid & 63, seg = tid >> 6;
    float p = 0.0f;
    for (int c = seg * 128; c < seg * 128 + 128; ++c) p += s_sh[c] * w1[r * 512 + c];
    part[tid] = p;
    __syncthreads();
    if (tid < 64) {
        float h = part[tid] + part[tid + 64] + part[tid + 128] + part[tid + 192] + b1[tid];
        h_sh[tid] = fmaxf(h, 0.0f);
    }
    __syncthreads();
    for (int c = tid; c < 512; c += 256) {
        float acc = b2[c];
#pragma unroll 8
        for (int rr = 0; rr < 64; ++rr) acc += h_sh[rr] * w2[c * 64 + rr];
        g[b * 512 + c] = 1.0f / (1.0f + expf(-acc));
    }
}

// fuse1: y1b = bf16(LN(x + y*g, n1))
__global__ __launch_bounds__(128) void fuse1_kernel(const float* __restrict__ x,
                                                    const float* __restrict__ y,
                                                    const float* __restrict__ g,
                                                    const float* __restrict__ n1g,
                                                    const float* __restrict__ n1b,
                                                    unsigned short* __restrict__ y1b) {
    int row = blockIdx.x, b = row >> 10, tid = threadIdx.x, c = tid * 4;
    __shared__ float r1[2], r2[2];
    float4 xv = *(const float4*)&x[(size_t)row * 512 + c];
    float4 yv = *(const float4*)&y[(size_t)row * 512 + c];
    float4 gv = *(const float4*)&g[b * 512 + c];
    float4 v;
    v.x = xv.x + yv.x * gv.x; v.y = xv.y + yv.y * gv.y;
    v.z = xv.z + yv.z * gv.z; v.w = xv.w + yv.w * gv.w;
    float s1 = v.x + v.y + v.z + v.w;
    float s2 = v.x * v.x + v.y * v.y + v.z * v.z + v.w * v.w;
#pragma unroll
    for (int off = 32; off > 0; off >>= 1) {
        s1 += __shfl_down(s1, off, 64);
        s2 += __shfl_down(s2, off, 64);
    }
    if ((tid & 63) == 0) { r1[tid >> 6] = s1; r2[tid >> 6] = s2; }
    __syncthreads();
    float mean = (r1[0] + r1[1]) * (1.0f / 512.0f);
    float var = (r2[0] + r2[1]) * (1.0f / 512.0f) - mean * mean;
    float rstd = rsqrtf(var + 1e-5f);
    float4 g4 = *(const float4*)&n1g[c];
    float4 b4 = *(const float4*)&n1b[c];
    float4 o;
    o.x = (v.x - mean) * rstd * g4.x + b4.x; o.y = (v.y - mean) * rstd * g4.y + b4.y;
    o.z = (v.z - mean) * rstd * g4.z + b4.z; o.w = (v.w - mean) * rstd * g4.w + b4.w;
    uint2 pk;
    pk.x = pk2(f2bf(o.x), f2bf(o.y));
    pk.y = pk2(f2bf(o.z), f2bf(o.w));
    *(uint2*)&y1b[(size_t)row * 512 + c] = pk;
}

// f32 -> bf16 (RNE), 8 elems/thread.
__global__ __launch_bounds__(256) void f32_to_bf16(const float* __restrict__ in,
                                                   unsigned short* __restrict__ out,
                                                   int n8) {
    int i = blockIdx.x * 256 + threadIdx.x;
    if (i >= n8) return;
    float4 a = ((const float4*)in)[2 * i];
    float4 b = ((const float4*)in)[2 * i + 1];
    uint4 o;
    o.x = pk2(f2bf(a.x), f2bf(a.y));
    o.y = pk2(f2bf(a.z), f2bf(a.w));
    o.z = pk2(f2bf(b.x), f2bf(b.y));
    o.w = pk2(f2bf(b.z), f2bf(b.w));
    *(uint4*)&out[(size_t)i * 8] = o;
}

__device__ __forceinline__ int swz_slot(int slot, int row) {
    return slot ^ (row & 3) ^ ((row >> 2) & 3);
}

// ---------------------------------------------------------------------------
// GEMM1 + GLU (bf16 MFMA). BM=128, out cols 64/block.
// ---------------------------------------------------------------------------
__global__ __launch_bounds__(256) void gemm_glu(const unsigned short* __restrict__ A,
                                                const unsigned short* __restrict__ W,
                                                const float* __restrict__ bias,
                                                unsigned short* __restrict__ act) {
    const int K = 512;
    int m0 = blockIdx.x * 128, n0 = blockIdx.y * 64;
    int tid = threadIdx.x, w = tid >> 6, l = tid & 63;
    __shared__ short As[4096];
    __shared__ short Bs[4096];
    int idA0 = tid, idA1 = tid + 256;
    int rA0 = idA0 >> 2, sA0 = idA0 & 3, rA1 = idA1 >> 2, sA1 = idA1 & 3;
    int ldsA0 = rA0 * 32 + swz_slot(sA0, rA0) * 8;
    int ldsA1 = rA1 * 32 + swz_slot(sA1, rA1) * 8;
    const unsigned short* pA0 = A + (size_t)(m0 + rA0) * K + sA0 * 8;
    const unsigned short* pA1 = A + (size_t)(m0 + rA1) * K + sA1 * 8;
    int gB0 = (rA0 < 64) ? (n0 + rA0) : (1024 + n0 + rA0 - 64);
    int gB1 = (rA1 < 64) ? (n0 + rA1) : (1024 + n0 + rA1 - 64);
    const unsigned short* pB0 = W + (size_t)gB0 * K + sA0 * 8;
    const unsigned short* pB1 = W + (size_t)gB1 * K + sA1 * 8;
    int p = l >> 4, lr = l & 15;
    int aoff[2], bAoff[4], bGoff[4];
#pragma unroll
    for (int rt = 0; rt < 2; ++rt) {
        int r = w * 32 + rt * 16 + lr;
        aoff[rt] = r * 32 + swz_slot(p, r) * 8;
    }
#pragma unroll
    for (int ct = 0; ct < 4; ++ct) {
        int ca = ct * 16 + lr, cg = 64 + ct * 16 + lr;
        bAoff[ct] = ca * 32 + swz_slot(p, ca) * 8;
        bGoff[ct] = cg * 32 + swz_slot(p, cg) * 8;
    }
    f32x4 accA[2][4], accG[2][4];
#pragma unroll
    for (int rt = 0; rt < 2; ++rt)
#pragma unroll
        for (int ct = 0; ct < 4; ++ct) {
            accA[rt][ct] = (f32x4)0.0f;
            accG[rt][ct] = (f32x4)0.0f;
        }
    for (int kt = 0; kt < K; kt += 32) {
        uint4 va0 = *(const uint4*)pA0;
        uint4 va1 = *(const uint4*)pA1;
        uint4 vb0 = *(const uint4*)pB0;
        uint4 vb1 = *(const uint4*)pB1;
        __syncthreads();
        *(uint4*)&As[ldsA0] = va0;
        *(uint4*)&As[ldsA1] = va1;
        *(uint4*)&Bs[ldsA0] = vb0;
        *(uint4*)&Bs[ldsA1] = vb1;
        __syncthreads();
        bf16x8 af[2], bA[4], bG[4];
#pragma unroll
        for (int rt = 0; rt < 2; ++rt) af[rt] = *(bf16x8*)&As[aoff[rt]];
#pragma unroll
        for (int ct = 0; ct < 4; ++ct) {
            bA[ct] = *(bf16x8*)&Bs[bAoff[ct]];
            bG[ct] = *(bf16x8*)&Bs[bGoff[ct]];
        }
#pragma unroll
        for (int rt = 0; rt < 2; ++rt)
#pragma unroll
            for (int ct = 0; ct < 4; ++ct) {
                accA[rt][ct] = __builtin_amdgcn_mfma_f32_16x16x32_bf16(af[rt], bA[ct], accA[rt][ct], 0, 0, 0);
                accG[rt][ct] = __builtin_amdgcn_mfma_f32_16x16x32_bf16(af[rt], bG[ct], accG[rt][ct], 0, 0, 0);
            }
        pA0 += 32; pA1 += 32; pB0 += 32; pB1 += 32;
    }
#pragma unroll
    for (int rt = 0; rt < 2; ++rt)
#pragma unroll
        for (int ct = 0; ct < 4; ++ct) {
            int col = n0 + ct * 16 + lr;
            float ba = bias[col], bg = bias[1024 + col];
#pragma unroll
            for (int reg = 0; reg < 4; ++reg) {
                int row = m0 + w * 32 + rt * 16 + p * 4 + reg;
                float a = accA[rt][ct][reg] + ba;
                float g = accG[rt][ct][reg] + bg;
                act[(size_t)row * 1024 + col] = f2bf(geluf_(a) * sigmoidf_(g));
            }
        }
}

// ---------------------------------------------------------------------------
// GEMM2 (bf16 MFMA): BM=128, BN=128, 2x2 waves, 4x4 frags. C = A@W^T + bias.
// ---------------------------------------------------------------------------
__global__ __launch_bounds__(256) void gemm_plain(const unsigned short* __restrict__ A,
                                                  const unsigned short* __restrict__ W,
                                                  const float* __restrict__ bias,
                                                  float* __restrict__ Cout) {
    const int K = 1024, N = 512;
    int m0 = blockIdx.x * 128, n0 = blockIdx.y * 128;
    int tid = threadIdx.x, w = tid >> 6, l = tid & 63;
    int wr = w >> 1, wc = w & 1;
    __shared__ short As[4096];
    __shared__ short Bs[4096];
    int idA0 = tid, idA1 = tid + 256;
    int rA0 = idA0 >> 2, sA0 = idA0 & 3, rA1 = idA1 >> 2, sA1 = idA1 & 3;
    int ldsA0 = rA0 * 32 + swz_slot(sA0, rA0) * 8;
    int ldsA1 = rA1 * 32 + swz_slot(sA1, rA1) * 8;
    const unsigned short* pA0 = A + (size_t)(m0 + rA0) * K + sA0 * 8;
    const unsigned short* pA1 = A + (size_t)(m0 + rA1) * K + sA1 * 8;
    const unsigned short* pB0 = W + (size_t)(n0 + rA0) * K + sA0 * 8;
    const unsigned short* pB1 = W + (size_t)(n0 + rA1) * K + sA1 * 8;
    int p = l >> 4, lr = l & 15;
    int aoff[4], boff[4];
#pragma unroll
    for (int t = 0; t < 4; ++t) {
        int r = wr * 64 + t * 16 + lr;
        aoff[t] = r * 32 + swz_slot(p, r) * 8;
        int cq = wc * 64 + t * 16 + lr;
        boff[t] = cq * 32 + swz_slot(p, cq) * 8;
    }
    f32x4 acc[4][4];
#pragma unroll
    for (int i = 0; i < 4; ++i)
#pragma unroll
        for (int j = 0; j < 4; ++j) acc[i][j] = (f32x4)0.0f;
    for (int kt = 0; kt < K; kt += 32) {
        uint4 va0 = *(const uint4*)pA0;
        uint4 va1 = *(const uint4*)pA1;
        uint4 vb0 = *(const uint4*)pB0;
        uint4 vb1 = *(const uint4*)pB1;
        __syncthreads();
        *(uint4*)&As[ldsA0] = va0;
        *(uint4*)&As[ldsA1] = va1;
        *(uint4*)&Bs[ldsA0] = vb0;
        *(uint4*)&Bs[ldsA1] = vb1;
        __syncthreads();
        bf16x8 af[4], bfr[4];
#pragma unroll
        for (int t = 0; t < 4; ++t) {
            af[t] = *(bf16x8*)&As[aoff[t]];
            bfr[t] = *(bf16x8*)&Bs[boff[t]];
        }
#pragma unroll
        for (int i = 0; i < 4; ++i)
#pragma unroll
            for (int j = 0; j < 4; ++j)
                acc[i][j] = __builtin_amdgcn_mfma_f32_16x16x32_bf16(af[i], bfr[j], acc[i][j], 0, 0, 0);
        pA0 += 32; pA1 += 32; pB0 += 32; pB1 += 32;
    }
#pragma unroll
    for (int i = 0; i < 4; ++i)
#pragma unroll
        for (int j = 0; j < 4; ++j) {
            int col = n0 + wc * 64 + j * 16 + lr;
            float bb = bias[col];
#pragma unroll
            for (int reg = 0; reg < 4; ++reg) {
                int row = m0 + wr * 64 + i * 16 + p * 4 + reg;
                Cout[(size_t)row * N + col] = acc[i][j][reg] + bb;
            }
        }
}

// fuse2: z2 = LN(y1+z, mixn); out = LN(y1+z2, n2). y1 read as bf16.
__global__ __launch_bounds__(128) void fuse2_kernel(const unsigned short* __restrict__ y1b,
                                                    const float* __restrict__ z,
                                                    const float* __restrict__ mg,
                                                    const float* __restrict__ mb,
                                                    const float* __restrict__ g2,
                                                    const float* __restrict__ b2v,
                                                    float* __restrict__ out) {
    int row = blockIdx.x, tid = threadIdx.x, c = tid * 4;
    __shared__ float r1[2], r2[2];
    uint2 yu = *(const uint2*)&y1b[(size_t)row * 512 + c];
    float4 a;
    a.x = __uint_as_float(yu.x << 16);
    a.y = __uint_as_float(yu.x & 0xffff0000u);
    a.z = __uint_as_float(yu.y << 16);
    a.w = __uint_as_float(yu.y & 0xffff0000u);
    float4 zv = *(const float4*)&z[(size_t)row * 512 + c];
    float4 t1;
    t1.x = a.x + zv.x; t1.y = a.y + zv.y; t1.z = a.z + zv.z; t1.w = a.w + zv.w;
    float s1 = t1.x + t1.y + t1.z + t1.w;
    float s2 = t1.x * t1.x + t1.y * t1.y + t1.z * t1.z + t1.w * t1.w;
#pragma unroll
    for (int off = 32; off > 0; off >>= 1) {
        s1 += __shfl_down(s1, off, 64);
        s2 += __shfl_down(s2, off, 64);
    }
    if ((tid & 63) == 0) { r1[tid >> 6] = s1; r2[tid >> 6] = s2; }
    __syncthreads();
    float mean = (r1[0] + r1[1]) * (1.0f / 512.0f);
    float var = (r2[0] + r2[1]) * (1.0f / 512.0f) - mean * mean;
    float rstd = rsqrtf(var + 1e-5f);
    float4 mg4 = *(const float4*)&mg[c];
    float4 mb4 = *(const float4*)&mb[c];
    float4 t2;
    t2.x = a.x + ((t1.x - mean) * rstd * mg4.x + mb4.x);
    t2.y = a.y + ((t1.y - mean) * rstd * mg4.y + mb4.y);
    t2.z = a.z + ((t1.z - mean) * rstd * mg4.z + mb4.z);
    t2.w = a.w + ((t1.w - mean) * rstd * mg4.w + mb4.w);
    __syncthreads();
    s1 = t2.x + t2.y + t2.z + t2.w;
    s2 = t2.x * t2.x + t2.y * t2.y + t2.z * t2.z + t2.w * t2.w;
#pragma unroll
    for (int off = 32; off > 0; off >>= 1) {
        s1 += __shfl_down(s1, off, 64);
        s2 += __shfl_down(s2, off, 64);
    }
    if ((tid & 63) == 0) { r1[tid >> 6] = s1; r2[tid >> 6] = s2; }
    __syncthreads();
    float mean2 = (r1[0] + r1[1]) * (1.0f / 512.0f);
    float var2 = (r2[0] + r2[1]) * (1.0f / 512.0f) - mean2 * mean2;
    float rstd2 = rsqrtf(var2 + 1e-5f);
    float4 gg = *(const float4*)&g2[c];
    float4 bb = *(const float4*)&b2v[c];
    float4 o;
    o.x = (t2.x - mean2) * rstd2 * gg.x + bb.x;
    o.y = (t2.y - mean2) * rstd2 * gg.y + bb.y;
    o.z = (t2.z - mean2) * rstd2 * gg.z + bb.z;
    o.w = (t2.w - mean2) * rstd2 * gg.w + bb.w;
    *(float4*)&out[(size_t)row * 512 + c] = o;
}

// ---------------------------------------------------------------------------
// Workspace layout (float offsets). Same as round 5 (~70.4 MB high-water).
// ---------------------------------------------------------------------------
extern "C" void kernel_launch(void* const* d_in, const int* in_sizes, int n_in,
                              void* d_out, int out_size, void* d_ws, size_t ws_size,
                              hipStream_t stream) {
    (void)in_sizes; (void)n_in; (void)out_size; (void)ws_size;
    const float* x      = (const float*)d_in[0];
    const float* Bp     = (const float*)d_in[1];
    const float* Cp     = (const float*)d_in[2];
    const float* Dp     = (const float*)d_in[3];
    const float* log_dt = (const float*)d_in[4];
    const float* se_w1  = (const float*)d_in[5];
    const float* se_b1  = (const float*)d_in[6];
    const float* se_w2  = (const float*)d_in[7];
    const float* se_b2  = (const float*)d_in[8];
    const float* n1g    = (const float*)d_in[9];
    const float* n1b    = (const float*)d_in[10];
    const float* up_w   = (const float*)d_in[11];
    const float* up_b   = (const float*)d_in[12];
    const float* dn_w   = (const float*)d_in[13];
    const float* dn_b   = (const float*)d_in[14];
    const float* mxg    = (const float*)d_in[15];
    const float* mxb    = (const float*)d_in[16];
    const float* n2g    = (const float*)d_in[17];
    const float* n2b    = (const float*)d_in[18];

    float* ws = (float*)d_ws;
    float* Kr   = ws + 0;          //   524,288
    float* dtb  = ws + 524288;     //        64
    float* ssum = ws + 524352;     //     4,096
    float* gbuf = ws + 528448;     //     4,096
    unsigned short* up_wb = (unsigned short*)(ws + 532544);   // 524,288 fl
    unsigned short* dn_wb = (unsigned short*)(ws + 1056832);  // 262,144 fl
    float* Bbar = ws + 1318976;    //   131,072
    float* Pow  = ws + 1450048;    //   163,840
    unsigned short* Bb_h = (unsigned short*)(ws + 1613888);   // 65,536 fl
    unsigned short* Bb_l = (unsigned short*)(ws + 1679424);
    unsigned short* Cp_h = (unsigned short*)(ws + 1744960);
    unsigned short* Cp_l = (unsigned short*)(ws + 1810496);
    unsigned short* Pst_h = (unsigned short*)(ws + 1876032);  // 262,144 fl each
    unsigned short* Pst_l = (unsigned short*)(ws + 2138176);
    unsigned short* Qst_h = (unsigned short*)(ws + 2400320);
    unsigned short* Qst_l = (unsigned short*)(ws + 2662464);
    float* Kpart = ws + 2924608;   // 2,097,152
    unsigned short* U_h = (unsigned short*)(ws + 5021760);    // 2,097,152 fl
    unsigned short* U_l = (unsigned short*)(ws + 7118912);
    unsigned short* V_h = (unsigned short*)(ws + 9216064);
    unsigned short* V_l = (unsigned short*)(ws + 11313216);
    float* xT   = ws + 5021760;    // alias U_h+U_l (dead after kgemm_k)
    float* yT   = ws + 9216064;    // alias V_h+V_l
    float* yb   = ws + 13410368;   // 4,194,304 (fresh)
    unsigned short* y1b = (unsigned short*)(ws + 9216064);    // alias yT after use
    unsigned short* act = (unsigned short*)(ws + 5021760);    // alias xT after conv
    float* zb   = ws + 13410368;   // alias yb after fuse1
    float* outp = (float*)d_out;

    // --- K pipeline ---
    hipLaunchKernelGGL(prep_comp, dim3(4), dim3(256), 0, stream, log_dt, Pow, dtb);
    hipLaunchKernelGGL(compute_bbar, dim3(8), dim3(256), 0, stream, Bp, dtb, Bbar);
    hipLaunchKernelGGL(f32_to_bf16_hl, dim3(64), dim3(256), 0, stream, Bbar, Bb_h, Bb_l, 16384);
    hipLaunchKernelGGL(f32_to_bf16_hl, dim3(64), dim3(256), 0, stream, Cp, Cp_h, Cp_l, 16384);
    hipLaunchKernelGGL(power_mats, dim3(64, 4), dim3(256), 0, stream, Pow, Pst_h, Pst_l, Qst_h, Qst_l);
    hipLaunchKernelGGL(kgemm_uv, dim3(4, 32, 4), dim3(256), 0, stream, Bb_h, Bb_l, Pst_h, Pst_l, V_h, V_l);
    hipLaunchKernelGGL(kgemm_uv, dim3(4, 32, 4), dim3(256), 0, stream, Cp_h, Cp_l, Qst_h, Qst_l, U_h, U_l);
    hipLaunchKernelGGL(kgemm_k, dim3(512), dim3(256), 0, stream, U_h, U_l, V_h, V_l, Kpart);
    hipLaunchKernelGGL(reduce_K, dim3(2048), dim3(256), 0, stream, Kpart, Dp, Kr);
    // --- weights ---
    hipLaunchKernelGGL(f32_to_bf16, dim3(512), dim3(256), 0, stream, up_w, up_wb, 131072);
    hipLaunchKernelGGL(f32_to_bf16, dim3(256), dim3(256), 0, stream, dn_w, dn_wb, 65536);
    // --- conv + block ---
    hipLaunchKernelGGL(transpose_bmat, dim3(32, 16, 8), dim3(256), 0, stream, x, xT, 1024, 512);
    hipLaunchKernelGGL(conv_mfma, dim3(512), dim3(256), 0, stream, xT, Kr, yT, ssum);
    hipLaunchKernelGGL(se_kernel, dim3(8), dim3(256), 0, stream, ssum, se_w1, se_b1, se_w2, se_b2, gbuf);
    hipLaunchKernelGGL(transpose_bmat, dim3(16, 32, 8), dim3(256), 0, stream, yT, yb, 512, 1024);
    hipLaunchKernelGGL(fuse1_kernel, dim3(8192), dim3(128), 0, stream, x, yb, gbuf, n1g, n1b, y1b);
    hipLaunchKernelGGL(gemm_glu, dim3(64, 16), dim3(256), 0, stream, y1b, up_wb, up_b, act);
    hipLaunchKernelGGL(gemm_plain, dim3(64, 4), dim3(256), 0, stream, act, dn_wb, dn_b, zb);
    hipLaunchKernelGGL(fuse2_kernel, dim3(8192), dim3(128), 0, stream, y1b, zb, mxg, mxb, n2g, n2b, outp);
}

// Round 7
// 235.114 us; speedup vs baseline: 3.6306x; 1.0215x over previous
//
#include <hip/hip_runtime.h>
#include <math.h>

// Sizes: B=8, L=1024, D=512, N=64, NC=4, HIDDEN=1024, up rows=2048, R=64

typedef short bf16x8 __attribute__((ext_vector_type(8)));
typedef float f32x4 __attribute__((ext_vector_type(4)));

__device__ __forceinline__ float sigmoidf_(float x) { return 1.0f / (1.0f + expf(-x)); }
__device__ __forceinline__ float geluf_(float x) { return 0.5f * x * (1.0f + erff(x * 0.70710678118654752f)); }
__device__ __forceinline__ unsigned short f2bf(float f) {
    unsigned u = __float_as_uint(f);
    unsigned r = (u + 0x7FFFu + ((u >> 16) & 1u)) >> 16;
    return (unsigned short)r;
}
__device__ __forceinline__ unsigned pk2(unsigned short a, unsigned short b) {
    return (unsigned)a | ((unsigned)b << 16);
}
// async global->LDS, 16B per lane; LDS dest is wave-uniform base + lane*16.
__device__ __forceinline__ void gload16(const void* g, void* l) {
    __builtin_amdgcn_global_load_lds((const __attribute__((address_space(1))) unsigned int*)g,
                                     (__attribute__((address_space(3))) unsigned int*)l, 16, 0, 0);
}

// ---------------------------------------------------------------------------
// P1: A_bar via rank-1 O(N) forward substitution + 9 squarings (uniform
// k-loop, unroll 8). Pow[comp][s] = Abar^(2^s), s=0..9.
// ---------------------------------------------------------------------------
__global__ __launch_bounds__(256) void prep_comp(const float* __restrict__ log_dt,
                                                 float* __restrict__ Pow,
                                                 float* __restrict__ dtbuf) {
    int comp = blockIdx.x, tid = threadIdx.x;
    __shared__ __align__(16) float M1[4096];
    __shared__ __align__(16) float M1T[4096];
    __shared__ __align__(16) float M2[4096];
    __shared__ __align__(16) float M2T[4096];
    float ldt = log_dt[comp];
    float dt = log1pf(expf(ldt)) + 1e-6f;
    float hdt = 0.5f * dt;
    if (tid < 64) {
        int j = tid;
        float sqj = sqrtf(2.0f * (float)j + 1.0f);
        float S = 0.0f;
        for (int i = 0; i < 64; ++i) {
            float sqi = sqrtf(2.0f * (float)i + 1.0f);
            float r = (i == j) ? (1.0f - hdt * (float)(i + 1))
                               : ((i > j) ? (-hdt * sqi * sqj) : 0.0f);
            float X = (r - hdt * sqi * S) / (1.0f + hdt * (float)(i + 1));
            M1[i * 64 + j] = X;
            M1T[j * 64 + i] = X;
            S += sqi * X;
        }
    }
    __syncthreads();
    for (int ii = tid; ii < 4096; ii += 256) Pow[(size_t)comp * 40960 + ii] = M1[ii];
    float* cur = M1; float* curT = M1T; float* nxt = M2; float* nxtT = M2T;
    int ti = tid >> 4, tj = tid & 15;
    for (int s = 1; s <= 9; ++s) {
        float c[4][4] = {{0}};
#pragma unroll 8
        for (int k = 0; k < 64; ++k) {
            float4 a = *(const float4*)&curT[k * 64 + ti * 4];
            float4 b = *(const float4*)&cur[k * 64 + tj * 4];
            c[0][0] += a.x * b.x; c[0][1] += a.x * b.y; c[0][2] += a.x * b.z; c[0][3] += a.x * b.w;
            c[1][0] += a.y * b.x; c[1][1] += a.y * b.y; c[1][2] += a.y * b.z; c[1][3] += a.y * b.w;
            c[2][0] += a.z * b.x; c[2][1] += a.z * b.y; c[2][2] += a.z * b.z; c[2][3] += a.z * b.w;
            c[3][0] += a.w * b.x; c[3][1] += a.w * b.y; c[3][2] += a.w * b.z; c[3][3] += a.w * b.w;
        }
#pragma unroll
        for (int r = 0; r < 4; ++r) {
            float4 row; row.x = c[r][0]; row.y = c[r][1]; row.z = c[r][2]; row.w = c[r][3];
            *(float4*)&nxt[(ti * 4 + r) * 64 + tj * 4] = row;
            float4 colv; colv.x = c[0][r]; colv.y = c[1][r]; colv.z = c[2][r]; colv.w = c[3][r];
            *(float4*)&nxtT[(tj * 4 + r) * 64 + ti * 4] = colv;
        }
        __syncthreads();
        for (int ii = tid; ii < 4096; ii += 256) Pow[(size_t)comp * 40960 + s * 4096 + ii] = nxt[ii];
        float* t0 = cur; cur = nxt; nxt = t0;
        float* t1 = curT; curT = nxtT; nxtT = t1;
        __syncthreads();
    }
    if (tid == 0) dtbuf[comp] = dt;
}

// ---------------------------------------------------------------------------
// P2: B_bar rows, rank-1 O(N) per thread; emits bf16 hi/lo directly.
// ---------------------------------------------------------------------------
__global__ __launch_bounds__(256) void compute_bbar(const float* __restrict__ Bp,
                                                    const float* __restrict__ dtbuf,
                                                    unsigned short* __restrict__ Bb_h,
                                                    unsigned short* __restrict__ Bb_l) {
    int gid = blockIdx.x * 256 + threadIdx.x;
    int comp = gid >> 9;
    float dt = dtbuf[comp];
    float hdt = 0.5f * dt;
    const float* bp = Bp + (size_t)gid * 64;
    unsigned short* oh = Bb_h + (size_t)gid * 64;
    unsigned short* ol = Bb_l + (size_t)gid * 64;
    float S = 0.0f;
    for (int i = 0; i < 64; ++i) {
        float sqi = sqrtf(2.0f * (float)i + 1.0f);
        float y = (dt * bp[i] - hdt * sqi * S) / (1.0f + hdt * (float)(i + 1));
        unsigned short h = f2bf(y);
        oh[i] = h;
        ol[i] = f2bf(y - __uint_as_float((unsigned)h << 16));
        S += sqi * y;
    }
}

// ---------------------------------------------------------------------------
// convert_all: up_w -> bf16, dn_w -> bf16, Cp -> bf16 hi/lo. One launch.
// n8 units: up 131072, dn 65536, Cp 16384. Grid 832.
// ---------------------------------------------------------------------------
__global__ __launch_bounds__(256) void convert_all(const float* __restrict__ up_w,
                                                   const float* __restrict__ dn_w,
                                                   const float* __restrict__ Cp,
                                                   unsigned short* __restrict__ up_wb,
                                                   unsigned short* __restrict__ dn_wb,
                                                   unsigned short* __restrict__ Cp_h,
                                                   unsigned short* __restrict__ Cp_l) {
    int i = blockIdx.x * 256 + threadIdx.x;
    if (i < 196608) {
        const float* src = (i < 131072) ? up_w : dn_w;
        unsigned short* dst = (i < 131072) ? up_wb : dn_wb;
        int j = (i < 131072) ? i : (i - 131072);
        float4 a = ((const float4*)src)[2 * j];
        float4 b = ((const float4*)src)[2 * j + 1];
        uint4 o;
        o.x = pk2(f2bf(a.x), f2bf(a.y));
        o.y = pk2(f2bf(a.z), f2bf(a.w));
        o.z = pk2(f2bf(b.x), f2bf(b.y));
        o.w = pk2(f2bf(b.z), f2bf(b.w));
        *(uint4*)&dst[(size_t)j * 8] = o;
    } else if (i < 212992) {
        int j = i - 196608;
        float4 a = ((const float4*)Cp)[2 * j];
        float4 b = ((const float4*)Cp)[2 * j + 1];
        float vv[8] = {a.x, a.y, a.z, a.w, b.x, b.y, b.z, b.w};
        unsigned short hs[8], ls[8];
#pragma unroll
        for (int k = 0; k < 8; ++k) {
            unsigned short h = f2bf(vv[k]);
            hs[k] = h;
            ls[k] = f2bf(vv[k] - __uint_as_float((unsigned)h << 16));
        }
        uint4 ho, lo;
        ho.x = pk2(hs[0], hs[1]); ho.y = pk2(hs[2], hs[3]); ho.z = pk2(hs[4], hs[5]); ho.w = pk2(hs[6], hs[7]);
        lo.x = pk2(ls[0], ls[1]); lo.y = pk2(ls[2], ls[3]); lo.z = pk2(ls[4], ls[5]); lo.w = pk2(ls[6], ls[7]);
        *(uint4*)&Cp_h[(size_t)j * 8] = ho;
        *(uint4*)&Cp_l[(size_t)j * 8] = lo;
    }
}

// ---------------------------------------------------------------------------
// power_mats: unchanged from round 6.
// ---------------------------------------------------------------------------
__global__ __launch_bounds__(256) void power_mats(const float* __restrict__ Pow,
                                                  unsigned short* __restrict__ Pst_h,
                                                  unsigned short* __restrict__ Pst_l,
                                                  unsigned short* __restrict__ Qst_h,
                                                  unsigned short* __restrict__ Qst_l) {
    int idx = blockIdx.x, comp = blockIdx.y, tid = threadIdx.x;
    __shared__ __align__(16) float R[4096], RT[4096], R2[4096], R2T[4096], SbT[4096];
    int isP = (idx < 32) ? 1 : 0;
    int f = isP ? idx : (idx - 32);
    int base_s = isP ? 0 : 5;
    const float* PowC = Pow + (size_t)comp * 40960;
    int i_ = tid & 63, kc = (tid >> 6) * 16;
    float* cur = R; float* curT = RT; float* nx = R2; float* nxT = R2T;
    if (f == 0) {
        for (int ii = tid; ii < 4096; ii += 256) {
            float v = ((ii >> 6) == (ii & 63)) ? 1.0f : 0.0f;
            R[ii] = v; RT[ii] = v;
        }
        __syncthreads();
    } else {
        int b0 = __ffs(f) - 1;
        const float* S0 = PowC + (size_t)(base_s + b0) * 4096;
#pragma unroll
        for (int j = 0; j < 16; j += 4) {
            float4 v = *(const float4*)&S0[i_ * 64 + kc + j];
            *(float4*)&R[i_ * 64 + kc + j] = v;
            RT[(kc + j + 0) * 64 + i_] = v.x;
            RT[(kc + j + 1) * 64 + i_] = v.y;
            RT[(kc + j + 2) * 64 + i_] = v.z;
            RT[(kc + j + 3) * 64 + i_] = v.w;
        }
        int rem = f & ~(1 << b0);
        int ti = tid >> 4, tj = tid & 15;
        __syncthreads();
        while (rem) {
            int b = __ffs(rem) - 1; rem &= rem - 1;
            const float* Sb = PowC + (size_t)(base_s + b) * 4096;
#pragma unroll
            for (int j = 0; j < 16; j += 4) {
                float4 v = *(const float4*)&Sb[i_ * 64 + kc + j];
                SbT[(kc + j + 0) * 64 + i_] = v.x;
                SbT[(kc + j + 1) * 64 + i_] = v.y;
                SbT[(kc + j + 2) * 64 + i_] = v.z;
                SbT[(kc + j + 3) * 64 + i_] = v.w;
            }
            __syncthreads();
            float c[4][4] = {{0}};
#pragma unroll 8
            for (int k = 0; k < 64; ++k) {
                float4 a = *(const float4*)&SbT[k * 64 + ti * 4];
                float4 b4 = *(const float4*)&cur[k * 64 + tj * 4];
                c[0][0] += a.x * b4.x; c[0][1] += a.x * b4.y; c[0][2] += a.x * b4.z; c[0][3] += a.x * b4.w;
                c[1][0] += a.y * b4.x; c[1][1] += a.y * b4.y; c[1][2] += a.y * b4.z; c[1][3] += a.y * b4.w;
                c[2][0] += a.z * b4.x; c[2][1] += a.z * b4.y; c[2][2] += a.z * b4.z; c[2][3] += a.z * b4.w;
                c[3][0] += a.w * b4.x; c[3][1] += a.w * b4.y; c[3][2] += a.w * b4.z; c[3][3] += a.w * b4.w;
            }
#pragma unroll
            for (int r = 0; r < 4; ++r) {
                float4 row; row.x = c[r][0]; row.y = c[r][1]; row.z = c[r][2]; row.w = c[r][3];
                *(float4*)&nx[(ti * 4 + r) * 64 + tj * 4] = row;
                float4 colv; colv.x = c[0][r]; colv.y = c[1][r]; colv.z = c[2][r]; colv.w = c[3][r];
                *(float4*)&nxT[(tj * 4 + r) * 64 + ti * 4] = colv;
            }
            __syncthreads();
            float* t0 = cur; cur = nx; nx = t0;
            float* t1 = curT; curT = nxT; nxT = t1;
        }
    }
    const float* src = isP ? cur : curT;
    int outrow = isP ? idx : (idx - 32);
    unsigned short* dh = (isP ? Pst_h : Qst_h) + (size_t)comp * 131072 + (size_t)outrow * 4096;
    unsigned short* dl = (isP ? Pst_l : Qst_l) + (size_t)comp * 131072 + (size_t)outrow * 4096;
    for (int ii = tid * 8; ii < 4096; ii += 2048) {
        float4 v0 = *(const float4*)&src[ii];
        float4 v1 = *(const float4*)&src[ii + 4];
        float vv[8] = {v0.x, v0.y, v0.z, v0.w, v1.x, v1.y, v1.z, v1.w};
        unsigned short hs[8], ls[8];
#pragma unroll
        for (int j = 0; j < 8; ++j) {
            unsigned short h = f2bf(vv[j]);
            hs[j] = h;
            ls[j] = f2bf(vv[j] - __uint_as_float((unsigned)h << 16));
        }
        uint4 ho, lo;
        ho.x = pk2(hs[0], hs[1]); ho.y = pk2(hs[2], hs[3]); ho.z = pk2(hs[4], hs[5]); ho.w = pk2(hs[6], hs[7]);
        lo.x = pk2(ls[0], ls[1]); lo.y = pk2(ls[2], ls[3]); lo.z = pk2(ls[4], ls[5]); lo.w = pk2(ls[6], ls[7]);
        *(uint4*)&dh[ii] = ho;
        *(uint4*)&dl[ii] = lo;
    }
}

// ---------------------------------------------------------------------------
// kgemm_uv2: merged U and V. z<4: V[comp=z] = Bb @ Pst^T; z>=4: U[z-4] = Cp @ Qst^T.
// Grid (4, 32, 8).
// ---------------------------------------------------------------------------
__global__ __launch_bounds__(256) void kgemm_uv2(const unsigned short* __restrict__ Bb_h,
                                                 const unsigned short* __restrict__ Bb_l,
                                                 const unsigned short* __restrict__ Pst_h,
                                                 const unsigned short* __restrict__ Pst_l,
                                                 const unsigned short* __restrict__ Cp_h,
                                                 const unsigned short* __restrict__ Cp_l,
                                                 const unsigned short* __restrict__ Qst_h,
                                                 const unsigned short* __restrict__ Qst_l,
                                                 unsigned short* __restrict__ V_h,
                                                 unsigned short* __restrict__ V_l,
                                                 unsigned short* __restrict__ U_h,
                                                 unsigned short* __restrict__ U_l) {
    int zz = blockIdx.z;
    int isV = (zz < 4) ? 1 : 0;
    int comp = isV ? zz : (zz - 4);
    const unsigned short* Ah = isV ? Bb_h : Cp_h;
    const unsigned short* Al = isV ? Bb_l : Cp_l;
    const unsigned short* Bh = isV ? Pst_h : Qst_h;
    const unsigned short* Bl = isV ? Pst_l : Qst_l;
    unsigned short* Ch = isV ? V_h : U_h;
    unsigned short* Cl = isV ? V_l : U_l;
    int m0 = blockIdx.x * 128, n0 = blockIdx.y * 64;
    int tid = threadIdx.x, w = tid >> 6, l = tid & 63;
    __shared__ __align__(16) short Ash[8192], Asl[8192], Bsh[4096], Bsl[4096];
    const unsigned short* Abh = Ah + (size_t)comp * 32768;
    const unsigned short* Abl = Al + (size_t)comp * 32768;
    const unsigned short* Bbh = Bh + (size_t)comp * 131072;
    const unsigned short* Bbl = Bl + (size_t)comp * 131072;
#pragma unroll
    for (int i = 0; i < 4; ++i) {
        int cid = tid + 256 * i;
        int row = cid >> 3, slot = cid & 7;
        int goff = (m0 + row) * 64 + slot * 8;
        int loff = row * 64 + (slot ^ (row & 7)) * 8;
        *(uint4*)&Ash[loff] = *(const uint4*)(Abh + goff);
        *(uint4*)&Asl[loff] = *(const uint4*)(Abl + goff);
    }
#pragma unroll
    for (int i = 0; i < 2; ++i) {
        int cid = tid + 256 * i;
        int row = cid >> 3, slot = cid & 7;
        int goff = (n0 + row) * 64 + slot * 8;
        int loff = row * 64 + (slot ^ (row & 7)) * 8;
        *(uint4*)&Bsh[loff] = *(const uint4*)(Bbh + goff);
        *(uint4*)&Bsl[loff] = *(const uint4*)(Bbl + goff);
    }
    __syncthreads();
    int p = l >> 4, lr = l & 15;
    f32x4 acc[2][4];
#pragma unroll
    for (int rt = 0; rt < 2; ++rt)
#pragma unroll
        for (int ct = 0; ct < 4; ++ct) acc[rt][ct] = (f32x4)0.0f;
#pragma unroll
    for (int ks = 0; ks < 2; ++ks) {
        bf16x8 ah2[2], al2[2], bh2[4], bl2[4];
#pragma unroll
        for (int rt = 0; rt < 2; ++rt) {
            int row = w * 32 + rt * 16 + lr;
            int off = row * 64 + ((ks * 4 + p) ^ (row & 7)) * 8;
            ah2[rt] = *(bf16x8*)&Ash[off];
            al2[rt] = *(bf16x8*)&Asl[off];
        }
#pragma unroll
        for (int ct = 0; ct < 4; ++ct) {
            int cr = ct * 16 + lr;
            int off = cr * 64 + ((ks * 4 + p) ^ (cr & 7)) * 8;
            bh2[ct] = *(bf16x8*)&Bsh[off];
            bl2[ct] = *(bf16x8*)&Bsl[off];
        }
#pragma unroll
        for (int rt = 0; rt < 2; ++rt)
#pragma unroll
            for (int ct = 0; ct < 4; ++ct) {
                acc[rt][ct] = __builtin_amdgcn_mfma_f32_16x16x32_bf16(ah2[rt], bh2[ct], acc[rt][ct], 0, 0, 0);
                acc[rt][ct] = __builtin_amdgcn_mfma_f32_16x16x32_bf16(ah2[rt], bl2[ct], acc[rt][ct], 0, 0, 0);
                acc[rt][ct] = __builtin_amdgcn_mfma_f32_16x16x32_bf16(al2[rt], bh2[ct], acc[rt][ct], 0, 0, 0);
            }
    }
#pragma unroll
    for (int rt = 0; rt < 2; ++rt)
#pragma unroll
        for (int ct = 0; ct < 4; ++ct) {
#pragma unroll
            for (int reg = 0; reg < 4; ++reg) {
                int row = m0 + w * 32 + rt * 16 + p * 4 + reg;
                int col = n0 + ct * 16 + lr;
                float v = acc[rt][ct][reg];
                unsigned short h = f2bf(v);
                unsigned short lo2 = f2bf(v - __uint_as_float((unsigned)h << 16));
                size_t o = (size_t)comp * 1048576 + (size_t)row * 2048 + col;
                Ch[o] = h;
                Cl[o] = lo2;
            }
        }
}

// ---------------------------------------------------------------------------
// kgemm_kr: fused kgemm_k + reduce_K. One block per d; wave w = comp w.
// Writes Kr[d][1023-l] = sum_comp Kpart + D (at l=0).
// ---------------------------------------------------------------------------
__global__ __launch_bounds__(256) void kgemm_kr(const unsigned short* __restrict__ Uh,
                                                const unsigned short* __restrict__ Ul,
                                                const unsigned short* __restrict__ Vh,
                                                const unsigned short* __restrict__ Vl,
                                                const float* __restrict__ Dp,
                                                float* __restrict__ Kr) {
    int tid = threadIdx.x, w = tid >> 6, l = tid & 63;
    int d = blockIdx.x;
    int g = w * 512 + d;  // comp w, channel d
    int p = l >> 4, lr = l & 15;
    __shared__ float ksh[4096];
    const unsigned short* ubh = Uh + (size_t)g * 2048;
    const unsigned short* ubl = Ul + (size_t)g * 2048;
    const unsigned short* vbh = Vh + (size_t)g * 2048;
    const unsigned short* vbl = Vl + (size_t)g * 2048;
    f32x4 acc[2][2];
    acc[0][0] = (f32x4)0.0f; acc[0][1] = (f32x4)0.0f;
    acc[1][0] = (f32x4)0.0f; acc[1][1] = (f32x4)0.0f;
#pragma unroll
    for (int ks = 0; ks < 2; ++ks) {
        bf16x8 uh2[2], ul2[2], vh2[2], vl2[2];
#pragma unroll
        for (int mt = 0; mt < 2; ++mt) {
            int off = (mt * 16 + lr) * 64 + ks * 32 + p * 8;
            uh2[mt] = *(const bf16x8*)(ubh + off);
            ul2[mt] = *(const bf16x8*)(ubl + off);
            vh2[mt] = *(const bf16x8*)(vbh + off);
            vl2[mt] = *(const bf16x8*)(vbl + off);
        }
#pragma unroll
        for (int mt = 0; mt < 2; ++mt)
#pragma unroll
            for (int nt = 0; nt < 2; ++nt) {
                acc[mt][nt] = __builtin_amdgcn_mfma_f32_16x16x32_bf16(uh2[mt], vh2[nt], acc[mt][nt], 0, 0, 0);
                acc[mt][nt] = __builtin_amdgcn_mfma_f32_16x16x32_bf16(uh2[mt], vl2[nt], acc[mt][nt], 0, 0, 0);
                acc[mt][nt] = __builtin_amdgcn_mfma_f32_16x16x32_bf16(ul2[mt], vh2[nt], acc[mt][nt], 0, 0, 0);
            }
    }
#pragma unroll
    for (int mt = 0; mt < 2; ++mt)
#pragma unroll
        for (int nt = 0; nt < 2; ++nt)
#pragma unroll
            for (int reg = 0; reg < 4; ++reg) {
                int q = mt * 16 + p * 4 + reg;
                int r = nt * 16 + lr;
                ksh[w * 1024 + q * 32 + r] = acc[mt][nt][reg];
            }
    __syncthreads();
#pragma unroll
    for (int j = 0; j < 4; ++j) {
        int ll = tid * 4 + j;
        float s = ksh[ll] + ksh[1024 + ll] + ksh[2048 + ll] + ksh[3072 + ll];
        if (ll == 0) s += Dp[d] + Dp[512 + d] + Dp[1024 + d] + Dp[1536 + d];
        Kr[(size_t)d * 1024 + (1023 - ll)] = s;
    }
}

// Generic batched transpose: in [B][R][C] -> out [B][C][R]
__global__ __launch_bounds__(256) void transpose_bmat(const float* __restrict__ in,
                                                      float* __restrict__ out,
                                                      int R, int C) {
    __shared__ float tile[32][33];
    int r0 = blockIdx.x * 32, c0 = blockIdx.y * 32, b = blockIdx.z;
    int tx = threadIdx.x & 31, ty = threadIdx.x >> 5;
#pragma unroll
    for (int m = 0; m < 4; ++m)
        tile[ty + 8 * m][tx] = in[((size_t)b * R + r0 + ty + 8 * m) * C + c0 + tx];
    __syncthreads();
#pragma unroll
    for (int m = 0; m < 4; ++m)
        out[((size_t)b * C + c0 + ty + 8 * m) * R + r0 + tx] = tile[tx][ty + 8 * m];
}

// ---------------------------------------------------------------------------
// MFMA depthwise conv (unchanged).
// ---------------------------------------------------------------------------
__global__ __launch_bounds__(256) void conv_mfma(const float* __restrict__ xT,
                                                 const float* __restrict__ Kr,
                                                 float* __restrict__ yT,
                                                 float* __restrict__ ssum) {
    int c = blockIdx.x, tid = threadIdx.x;
    int w = tid >> 6, l = tid & 63;
    __shared__ __align__(16) float krp[1088];
    __shared__ __align__(16) short xh[8512], xl[8512];
    __shared__ __align__(16) short gh[10240], gl[10240];
    __shared__ float ssh[64];

    {
        float4 kv = *(const float4*)&Kr[(size_t)c * 1024 + tid * 4];
        *(float4*)&krp[32 + tid * 4] = kv;
        if (tid < 8) *(float4*)&krp[tid * 4] = make_float4(0, 0, 0, 0);
        else if (tid < 16) *(float4*)&krp[1056 + (tid - 8) * 4] = make_float4(0, 0, 0, 0);
    }
    if (tid < 32) {
        int b = tid >> 2, g = tid & 3;
        uint4 z = {0, 0, 0, 0};
        *(uint4*)&xh[(b * 133 + g) * 8] = z;
    } else if (tid < 64) {
        int t2 = tid - 32; int b = t2 >> 2, g = t2 & 3;
        uint4 z = {0, 0, 0, 0};
        *(uint4*)&xl[(b * 133 + g) * 8] = z;
    }
#pragma unroll
    for (int i = 0; i < 4; ++i) {
        int gid = tid + 256 * i;
        int b = gid >> 7, gt = gid & 127;
        const float* src = &xT[((size_t)(b * 512 + c)) * 1024 + gt * 8];
        float4 v0 = *(const float4*)src;
        float4 v1 = *(const float4*)(src + 4);
        float vv[8] = {v0.x, v0.y, v0.z, v0.w, v1.x, v1.y, v1.z, v1.w};
        unsigned short hsv[8], lsv[8];
#pragma unroll
        for (int j2 = 0; j2 < 8; ++j2) {
            unsigned short h = f2bf(vv[j2]);
            hsv[j2] = h;
            lsv[j2] = f2bf(vv[j2] - __uint_as_float((unsigned)h << 16));
        }
        uint4 hh, ll;
        hh.x = pk2(hsv[0], hsv[1]); hh.y = pk2(hsv[2], hsv[3]);
        hh.z = pk2(hsv[4], hsv[5]); hh.w = pk2(hsv[6], hsv[7]);
        ll.x = pk2(lsv[0], lsv[1]); ll.y = pk2(lsv[2], lsv[3]);
        ll.z = pk2(lsv[4], lsv[5]); ll.w = pk2(lsv[6], lsv[7]);
        int off = (b * 133 + 4 + gt) * 8;
        *(uint4*)&xh[off] = hh;
        *(uint4*)&xl[off] = ll;
    }
    __syncthreads();

    f32x4 acc[4][2];
#pragma unroll
    for (int i = 0; i < 4; ++i) { acc[i][0] = (f32x4)0.0f; acc[i][1] = (f32x4)0.0f; }

    int lr = l & 15, kg4 = l >> 4;
    for (int ch = 0; ch < 4; ++ch) {
        int dq0 = ch * 8;
        {
            int dqloc = tid >> 5, n = tid & 31, dq = dq0 + dqloc;
            int s0 = 32 * dq + n + 1;
            int a0 = s0 & ~3, sh = s0 & 3;
            float ff[36];
#pragma unroll
            for (int i = 0; i < 9; ++i) *(float4*)&ff[i * 4] = *(const float4*)&krp[a0 + i * 4];
            unsigned short hsv[32], lsv[32];
#pragma unroll
            for (int k = 0; k < 32; ++k) {
                int j2 = 31 - k;
                float v = (sh == 0) ? ff[j2] : (sh == 1) ? ff[j2 + 1] : (sh == 2) ? ff[j2 + 2] : ff[j2 + 3];
                unsigned short h = f2bf(v);
                hsv[k] = h;
                lsv[k] = f2bf(v - __uint_as_float((unsigned)h << 16));
            }
            int gbase = (dqloc * 32 + n) * 5 * 8;
#pragma unroll
            for (int kg = 0; kg < 4; ++kg) {
                uint4 hh, ll;
                hh.x = pk2(hsv[8 * kg + 0], hsv[8 * kg + 1]);
                hh.y = pk2(hsv[8 * kg + 2], hsv[8 * kg + 3]);
                hh.z = pk2(hsv[8 * kg + 4], hsv[8 * kg + 5]);
                hh.w = pk2(hsv[8 * kg + 6], hsv[8 * kg + 7]);
                ll.x = pk2(lsv[8 * kg + 0], lsv[8 * kg + 1]);
                ll.y = pk2(lsv[8 * kg + 2], lsv[8 * kg + 3]);
                ll.z = pk2(lsv[8 * kg + 4], lsv[8 * kg + 5]);
                ll.w = pk2(lsv[8 * kg + 6], lsv[8 * kg + 7]);
                *(uint4*)&gh[gbase + kg * 8] = hh;
                *(uint4*)&gl[gbase + kg * 8] = ll;
            }
        }
        __syncthreads();
        for (int dqloc = 0; dqloc < 8; ++dqloc) {
            int dq = dq0 + dqloc;
            bf16x8 bh[2], bl[2];
#pragma unroll
            for (int nf = 0; nf < 2; ++nf) {
                int go = ((dqloc * 32 + nf * 16 + lr) * 5 + kg4) * 8;
                bh[nf] = *(bf16x8*)&gh[go];
                bl[nf] = *(bf16x8*)&gl[go];
            }
#pragma unroll
            for (int ffi = 0; ffi < 4; ++ffi) {
                int F = w + 4 * ffi;
                if (2 * F + 1 < dq) continue;
                int b = lr & 7, qoff = lr >> 3;
                int q = 2 * F + qoff;
                int j = 4 * (q - dq) + kg4 + 4;
                int xo = (b * 133 + j) * 8;
                bf16x8 ah = *(bf16x8*)&xh[xo];
                bf16x8 al = *(bf16x8*)&xl[xo];
#pragma unroll
                for (int nf = 0; nf < 2; ++nf) {
                    acc[ffi][nf] = __builtin_amdgcn_mfma_f32_16x16x32_bf16(ah, bh[nf], acc[ffi][nf], 0, 0, 0);
                    acc[ffi][nf] = __builtin_amdgcn_mfma_f32_16x16x32_bf16(al, bh[nf], acc[ffi][nf], 0, 0, 0);
                    acc[ffi][nf] = __builtin_amdgcn_mfma_f32_16x16x32_bf16(ah, bl[nf], acc[ffi][nf], 0, 0, 0);
                }
            }
        }
        __syncthreads();
    }

    float bsum[4] = {0, 0, 0, 0};
#pragma unroll
    for (int ffi = 0; ffi < 4; ++ffi) {
        int F = w + 4 * ffi;
#pragma unroll
        for (int nf = 0; nf < 2; ++nf) {
#pragma unroll
            for (int reg = 0; reg < 4; ++reg) {
                int mloc = 4 * kg4 + reg;
                int b = mloc & 7;
                int q = 2 * F + (mloc >> 3);
                int t = 32 * q + nf * 16 + lr;
                yT[((size_t)(b * 512 + c)) * 1024 + t] = acc[ffi][nf][reg];
                bsum[reg] += acc[ffi][nf][reg];
            }
        }
    }
#pragma unroll
    for (int off = 1; off < 16; off <<= 1) {
#pragma unroll
        for (int reg = 0; reg < 4; ++reg) bsum[reg] += __shfl_xor(bsum[reg], off, 64);
    }
    if (lr == 0) {
#pragma unroll
        for (int reg = 0; reg < 4; ++reg) ssh[w * 16 + kg4 * 4 + reg] = bsum[reg];
    }
    __syncthreads();
    if (tid < 8) {
        float tot = 0.0f;
        for (int w2 = 0; w2 < 4; ++w2) tot += ssh[w2 * 16 + tid] + ssh[w2 * 16 + 8 + tid];
        ssum[tid * 512 + c] = tot;
    }
}

__global__ __launch_bounds__(256) void se_kernel(const float* __restrict__ ssum,
                                                 const float* __restrict__ w1,
                                                 const float* __restrict__ b1,
                                                 const float* __restrict__ w2,
                                                 const float* __restrict__ b2,
                                                 float* __restrict__ g) {
    int b = blockIdx.x, tid = threadIdx.x;
    __shared__ float s_sh[512];
    __shared__ float part[256];
    __shared__ float h_sh[64];
    for (int c = tid; c < 512; c += 256) s_sh[c] = ssum[b * 512 + c] * (1.0f / 1024.0f);
    __syncthreads();
    int r = tid & 63, seg = tid >> 6;
    float p = 0.0f;
    for (int c = seg * 128; c < seg * 128 + 128; ++c) p += s_sh[c] * w1[r * 512 + c];
    part[tid] = p;
    __syncthreads();
    if (tid < 64) {
        float h = part[tid] + part[tid + 64] + part[tid + 128] + part[tid + 192] + b1[tid];
        h_sh[tid] = fmaxf(h, 0.0f);
    }
    __syncthreads();
    for (int c = tid; c < 512; c += 256) {
        float acc = b2[c];
#pragma unroll 8
        for (int rr = 0; rr < 64; ++rr) acc += h_sh[rr] * w2[c * 64 + rr];
        g[b * 512 + c] = 1.0f / (1.0f + expf(-acc));
    }
}

// fuse1: y1b = bf16(LN(x + y*g, n1))
__global__ __launch_bounds__(128) void fuse1_kernel(const float* __restrict__ x,
                                                    const float* __restrict__ y,
                                                    const float* __restrict__ g,
                                                    const float* __restrict__ n1g,
                                                    const float* __restrict__ n1b,
                                                    unsigned short* __restrict__ y1b) {
    int row = blockIdx.x, b = row >> 10, tid = threadIdx.x, c = tid * 4;
    __shared__ float r1[2], r2[2];
    float4 xv = *(const float4*)&x[(size_t)row * 512 + c];
    float4 yv = *(const float4*)&y[(size_t)row * 512 + c];
    float4 gv = *(const float4*)&g[b * 512 + c];
    float4 v;
    v.x = xv.x + yv.x * gv.x; v.y = xv.y + yv.y * gv.y;
    v.z = xv.z + yv.z * gv.z; v.w = xv.w + yv.w * gv.w;
    float s1 = v.x + v.y + v.z + v.w;
    float s2 = v.x * v.x + v.y * v.y + v.z * v.z + v.w * v.w;
#pragma unroll
    for (int off = 32; off > 0; off >>= 1) {
        s1 += __shfl_down(s1, off, 64);
        s2 += __shfl_down(s2, off, 64);
    }
    if ((tid & 63) == 0) { r1[tid >> 6] = s1; r2[tid >> 6] = s2; }
    __syncthreads();
    float mean = (r1[0] + r1[1]) * (1.0f / 512.0f);
    float var = (r2[0] + r2[1]) * (1.0f / 512.0f) - mean * mean;
    float rstd = rsqrtf(var + 1e-5f);
    float4 g4 = *(const float4*)&n1g[c];
    float4 b4 = *(const float4*)&n1b[c];
    float4 o;
    o.x = (v.x - mean) * rstd * g4.x + b4.x; o.y = (v.y - mean) * rstd * g4.y + b4.y;
    o.z = (v.z - mean) * rstd * g4.z + b4.z; o.w = (v.w - mean) * rstd * g4.w + b4.w;
    uint2 pk;
    pk.x = pk2(f2bf(o.x), f2bf(o.y));
    pk.y = pk2(f2bf(o.z), f2bf(o.w));
    *(uint2*)&y1b[(size_t)row * 512 + c] = pk;
}

__device__ __forceinline__ int swz_slot(int slot, int row) {
    return slot ^ (row & 3) ^ ((row >> 2) & 3);
}

// ---------------------------------------------------------------------------
// GEMM1 + GLU (bf16 MFMA). Staging via global_load_lds width=16:
// linear LDS dest, inverse-swizzled per-lane global source (same XOR layout
// as before, since swz is an involution). 2-barrier m97 schedule.
// ---------------------------------------------------------------------------
__global__ __launch_bounds__(256) void gemm_glu(const unsigned short* __restrict__ A,
                                                const unsigned short* __restrict__ W,
                                                const float* __restrict__ bias,
                                                unsigned short* __restrict__ act) {
    const int K = 512;
    int m0 = blockIdx.x * 128, n0 = blockIdx.y * 64;
    int tid = threadIdx.x, w = tid >> 6, l = tid & 63;
    __shared__ __align__(16) short As[4096];
    __shared__ __align__(16) short Bs[4096];
    // wave w stages segments 2w, 2w+1 (16 rows x 64B each) of A and B
    int seg0 = 2 * w, seg1 = 2 * w + 1;
    int rA0 = seg0 * 16 + (l >> 2), rA1 = seg1 * 16 + (l >> 2);
    int ss0 = (l & 3) ^ (rA0 & 3) ^ ((rA0 >> 2) & 3);
    int ss1 = (l & 3) ^ (rA1 & 3) ^ ((rA1 >> 2) & 3);
    const unsigned short* gA0 = A + (size_t)(m0 + rA0) * K + ss0 * 8;
    const unsigned short* gA1 = A + (size_t)(m0 + rA1) * K + ss1 * 8;
    int gBr0 = (rA0 < 64) ? (n0 + rA0) : (1024 + n0 + rA0 - 64);
    int gBr1 = (rA1 < 64) ? (n0 + rA1) : (1024 + n0 + rA1 - 64);
    const unsigned short* gB0 = W + (size_t)gBr0 * K + ss0 * 8;
    const unsigned short* gB1 = W + (size_t)gBr1 * K + ss1 * 8;
    short* ldsA0 = &As[seg0 * 512];
    short* ldsA1 = &As[seg1 * 512];
    short* ldsB0 = &Bs[seg0 * 512];
    short* ldsB1 = &Bs[seg1 * 512];
    int p = l >> 4, lr = l & 15;
    int aoff[2], bAoff[4], bGoff[4];
#pragma unroll
    for (int rt = 0; rt < 2; ++rt) {
        int r = w * 32 + rt * 16 + lr;
        aoff[rt] = r * 32 + swz_slot(p, r) * 8;
    }
#pragma unroll
    for (int ct = 0; ct < 4; ++ct) {
        int ca = ct * 16 + lr, cg = 64 + ct * 16 + lr;
        bAoff[ct] = ca * 32 + swz_slot(p, ca) * 8;
        bGoff[ct] = cg * 32 + swz_slot(p, cg) * 8;
    }
    f32x4 accA[2][4], accG[2][4];
#pragma unroll
    for (int rt = 0; rt < 2; ++rt)
#pragma unroll
        for (int ct = 0; ct < 4; ++ct) {
            accA[rt][ct] = (f32x4)0.0f;
            accG[rt][ct] = (f32x4)0.0f;
        }
    for (int kt = 0; kt < K; kt += 32) {
        __syncthreads();
        gload16(gA0 + kt, ldsA0);
        gload16(gA1 + kt, ldsA1);
        gload16(gB0 + kt, ldsB0);
        gload16(gB1 + kt, ldsB1);
        __syncthreads();
        bf16x8 af[2], bA[4], bG[4];
#pragma unroll
        for (int rt = 0; rt < 2; ++rt) af[rt] = *(bf16x8*)&As[aoff[rt]];
#pragma unroll
        for (int ct = 0; ct < 4; ++ct) {
            bA[ct] = *(bf16x8*)&Bs[bAoff[ct]];
            bG[ct] = *(bf16x8*)&Bs[bGoff[ct]];
        }
#pragma unroll
        for (int rt = 0; rt < 2; ++rt)
#pragma unroll
            for (int ct = 0; ct < 4; ++ct) {
                accA[rt][ct] = __builtin_amdgcn_mfma_f32_16x16x32_bf16(af[rt], bA[ct], accA[rt][ct], 0, 0, 0);
                accG[rt][ct] = __builtin_amdgcn_mfma_f32_16x16x32_bf16(af[rt], bG[ct], accG[rt][ct], 0, 0, 0);
            }
    }
#pragma unroll
    for (int rt = 0; rt < 2; ++rt)
#pragma unroll
        for (int ct = 0; ct < 4; ++ct) {
            int col = n0 + ct * 16 + lr;
            float ba = bias[col], bg = bias[1024 + col];
#pragma unroll
            for (int reg = 0; reg < 4; ++reg) {
                int row = m0 + w * 32 + rt * 16 + p * 4 + reg;
                float a = accA[rt][ct][reg] + ba;
                float g = accG[rt][ct][reg] + bg;
                act[(size_t)row * 1024 + col] = f2bf(geluf_(a) * sigmoidf_(g));
            }
        }
}

// ---------------------------------------------------------------------------
// GEMM2 (bf16 MFMA): BM=128, BN=128; global_load_lds staging as above.
// ---------------------------------------------------------------------------
__global__ __launch_bounds__(256) void gemm_plain(const unsigned short* __restrict__ A,
                                                  const unsigned short* __restrict__ W,
                                                  const float* __restrict__ bias,
                                                  float* __restrict__ Cout) {
    const int K = 1024, N = 512;
    int m0 = blockIdx.x * 128, n0 = blockIdx.y * 128;
    int tid = threadIdx.x, w = tid >> 6, l = tid & 63;
    int wr = w >> 1, wc = w & 1;
    __shared__ __align__(16) short As[4096];
    __shared__ __align__(16) short Bs[4096];
    int seg0 = 2 * w, seg1 = 2 * w + 1;
    int rA0 = seg0 * 16 + (l >> 2), rA1 = seg1 * 16 + (l >> 2);
    int ss0 = (l & 3) ^ (rA0 & 3) ^ ((rA0 >> 2) & 3);
    int ss1 = (l & 3) ^ (rA1 & 3) ^ ((rA1 >> 2) & 3);
    const unsigned short* gA0 = A + (size_t)(m0 + rA0) * K + ss0 * 8;
    const unsigned short* gA1 = A + (size_t)(m0 + rA1) * K + ss1 * 8;
    const unsigned short* gB0 = W + (size_t)(n0 + rA0) * K + ss0 * 8;
    const unsigned short* gB1 = W + (size_t)(n0 + rA1) * K + ss1 * 8;
    short* ldsA0 = &As[seg0 * 512];
    short* ldsA1 = &As[seg1 * 512];
    short* ldsB0 = &Bs[seg0 * 512];
    short* ldsB1 = &Bs[seg1 * 512];
    int p = l >> 4, lr = l & 15;
    int aoff[4], boff[4];
#pragma unroll
    for (int t = 0; t < 4; ++t) {
        int r = wr * 64 + t * 16 + lr;
        aoff[t] = r * 32 + swz_slot(p, r) * 8;
        int cq = wc * 64 + t * 16 + lr;
        boff[t] = cq * 32 + swz_slot(p, cq) * 8;
    }
    f32x4 acc[4][4];
#pragma unroll
    for (int i = 0; i < 4; ++i)
#pragma unroll
        for (int j = 0; j < 4; ++j) acc[i][j] = (f32x4)0.0f;
    for (int kt = 0; kt < K; kt += 32) {
        __syncthreads();
        gload16(gA0 + kt, ldsA0);
        gload16(gA1 + kt, ldsA1);
        gload16(gB0 + kt, ldsB0);
        gload16(gB1 + kt, ldsB1);
        __syncthreads();
        bf16x8 af[4], bfr[4];
#pragma unroll
        for (int t = 0; t < 4; ++t) {
            af[t] = *(bf16x8*)&As[aoff[t]];
            bfr[t] = *(bf16x8*)&Bs[boff[t]];
        }
#pragma unroll
        for (int i = 0; i < 4; ++i)
#pragma unroll
            for (int j = 0; j < 4; ++j)
                acc[i][j] = __builtin_amdgcn_mfma_f32_16x16x32_bf16(af[i], bfr[j], acc[i][j], 0, 0, 0);
    }
#pragma unroll
    for (int i = 0; i < 4; ++i)
#pragma unroll
        for (int j = 0; j < 4; ++j) {
            int col = n0 + wc * 64 + j * 16 + lr;
            float bb = bias[col];
#pragma unroll
            for (int reg = 0; reg < 4; ++reg) {
                int row = m0 + wr * 64 + i * 16 + p * 4 + reg;
                Cout[(size_t)row * N + col] = acc[i][j][reg] + bb;
            }
        }
}

// fuse2: z2 = LN(y1+z, mixn); out = LN(y1+z2, n2). y1 read as bf16.
__global__ __launch_bounds__(128) void fuse2_kernel(const unsigned short* __restrict__ y1b,
                                                    const float* __restrict__ z,
                                                    const float* __restrict__ mg,
                                                    const float* __restrict__ mb,
                                                    const float* __restrict__ g2,
                                                    const float* __restrict__ b2v,
                                                    float* __restrict__ out) {
    int row = blockIdx.x, tid = threadIdx.x, c = tid * 4;
    __shared__ float r1[2], r2[2];
    uint2 yu = *(const uint2*)&y1b[(size_t)row * 512 + c];
    float4 a;
    a.x = __uint_as_float(yu.x << 16);
    a.y = __uint_as_float(yu.x & 0xffff0000u);
    a.z = __uint_as_float(yu.y << 16);
    a.w = __uint_as_float(yu.y & 0xffff0000u);
    float4 zv = *(const float4*)&z[(size_t)row * 512 + c];
    float4 t1;
    t1.x = a.x + zv.x; t1.y = a.y + zv.y; t1.z = a.z + zv.z; t1.w = a.w + zv.w;
    float s1 = t1.x + t1.y + t1.z + t1.w;
    float s2 = t1.x * t1.x + t1.y * t1.y + t1.z * t1.z + t1.w * t1.w;
#pragma unroll
    for (int off = 32; off > 0; off >>= 1) {
        s1 += __shfl_down(s1, off, 64);
        s2 += __shfl_down(s2, off, 64);
    }
    if ((tid & 63) == 0) { r1[tid >> 6] = s1; r2[tid >> 6] = s2; }
    __syncthreads();
    float mean = (r1[0] + r1[1]) * (1.0f / 512.0f);
    float var = (r2[0] + r2[1]) * (1.0f / 512.0f) - mean * mean;
    float rstd = rsqrtf(var + 1e-5f);
    float4 mg4 = *(const float4*)&mg[c];
    float4 mb4 = *(const float4*)&mb[c];
    float4 t2;
    t2.x = a.x + ((t1.x - mean) * rstd * mg4.x + mb4.x);
    t2.y = a.y + ((t1.y - mean) * rstd * mg4.y + mb4.y);
    t2.z = a.z + ((t1.z - mean) * rstd * mg4.z + mb4.z);
    t2.w = a.w + ((t1.w - mean) * rstd * mg4.w + mb4.w);
    __syncthreads();
    s1 = t2.x + t2.y + t2.z + t2.w;
    s2 = t2.x * t2.x + t2.y * t2.y + t2.z * t2.z + t2.w * t2.w;
#pragma unroll
    for (int off = 32; off > 0; off >>= 1) {
        s1 += __shfl_down(s1, off, 64);
        s2 += __shfl_down(s2, off, 64);
    }
    if ((tid & 63) == 0) { r1[tid >> 6] = s1; r2[tid >> 6] = s2; }
    __syncthreads();
    float mean2 = (r1[0] + r1[1]) * (1.0f / 512.0f);
    float var2 = (r2[0] + r2[1]) * (1.0f / 512.0f) - mean2 * mean2;
    float rstd2 = rsqrtf(var2 + 1e-5f);
    float4 gg = *(const float4*)&g2[c];
    float4 bb = *(const float4*)&b2v[c];
    float4 o;
    o.x = (t2.x - mean2) * rstd2 * gg.x + bb.x;
    o.y = (t2.y - mean2) * rstd2 * gg.y + bb.y;
    o.z = (t2.z - mean2) * rstd2 * gg.z + bb.z;
    o.w = (t2.w - mean2) * rstd2 * gg.w + bb.w;
    *(float4*)&out[(size_t)row * 512 + c] = o;
}

// ---------------------------------------------------------------------------
// Workspace layout (float offsets), same map as round 5/6 (~70 MB high-water).
// Bbar f32 and Kpart slots now unused (fused away) but offsets kept.
// ---------------------------------------------------------------------------
extern "C" void kernel_launch(void* const* d_in, const int* in_sizes, int n_in,
                              void* d_out, int out_size, void* d_ws, size_t ws_size,
                              hipStream_t stream) {
    (void)in_sizes; (void)n_in; (void)out_size; (void)ws_size;
    const float* x      = (const float*)d_in[0];
    const float* Bp     = (const float*)d_in[1];
    const float* Cp     = (const float*)d_in[2];
    const float* Dp     = (const float*)d_in[3];
    const float* log_dt = (const float*)d_in[4];
    const float* se_w1  = (const float*)d_in[5];
    const float* se_b1  = (const float*)d_in[6];
    const float* se_w2  = (const float*)d_in[7];
    const float* se_b2  = (const float*)d_in[8];
    const float* n1g    = (const float*)d_in[9];
    const float* n1b    = (const float*)d_in[10];
    const float* up_w   = (const float*)d_in[11];
    const float* up_b   = (const float*)d_in[12];
    const float* dn_w   = (const float*)d_in[13];
    const float* dn_b   = (const float*)d_in[14];
    const float* mxg    = (const float*)d_in[15];
    const float* mxb    = (const float*)d_in[16];
    const float* n2g    = (const float*)d_in[17];
    const float* n2b    = (const float*)d_in[18];

    float* ws = (float*)d_ws;
    float* Kr   = ws + 0;          //   524,288
    float* dtb  = ws + 524288;     //        64
    float* ssum = ws + 524352;     //     4,096
    float* gbuf = ws + 528448;     //     4,096
    unsigned short* up_wb = (unsigned short*)(ws + 532544);   // 524,288 fl
    unsigned short* dn_wb = (unsigned short*)(ws + 1056832);  // 262,144 fl
    float* Pow  = ws + 1450048;    //   163,840
    unsigned short* Bb_h = (unsigned short*)(ws + 1613888);   // 65,536 fl each
    unsigned short* Bb_l = (unsigned short*)(ws + 1679424);
    unsigned short* Cp_h = (unsigned short*)(ws + 1744960);
    unsigned short* Cp_l = (unsigned short*)(ws + 1810496);
    unsigned short* Pst_h = (unsigned short*)(ws + 1876032);  // 262,144 fl each
    unsigned short* Pst_l = (unsigned short*)(ws + 2138176);
    unsigned short* Qst_h = (unsigned short*)(ws + 2400320);
    unsigned short* Qst_l = (unsigned short*)(ws + 2662464);
    unsigned short* U_h = (unsigned short*)(ws + 5021760);    // 2,097,152 fl
    unsigned short* U_l = (unsigned short*)(ws + 7118912);
    unsigned short* V_h = (unsigned short*)(ws + 9216064);
    unsigned short* V_l = (unsigned short*)(ws + 11313216);
    float* xT   = ws + 5021760;    // alias U_h+U_l (dead after kgemm_kr)
    float* yT   = ws + 9216064;    // alias V_h+V_l
    float* yb   = ws + 13410368;   // 4,194,304 (fresh)
    unsigned short* y1b = (unsigned short*)(ws + 9216064);    // alias yT after use
    unsigned short* act = (unsigned short*)(ws + 5021760);    // alias xT after conv
    float* zb   = ws + 13410368;   // alias yb after fuse1
    float* outp = (float*)d_out;

    // --- K pipeline ---
    hipLaunchKernelGGL(prep_comp, dim3(4), dim3(256), 0, stream, log_dt, Pow, dtb);
    hipLaunchKernelGGL(compute_bbar, dim3(8), dim3(256), 0, stream, Bp, dtb, Bb_h, Bb_l);
    hipLaunchKernelGGL(convert_all, dim3(832), dim3(256), 0, stream, up_w, dn_w, Cp, up_wb, dn_wb, Cp_h, Cp_l);
    hipLaunchKernelGGL(power_mats, dim3(64, 4), dim3(256), 0, stream, Pow, Pst_h, Pst_l, Qst_h, Qst_l);
    hipLaunchKernelGGL(kgemm_uv2, dim3(4, 32, 8), dim3(256), 0, stream,
                       Bb_h, Bb_l, Pst_h, Pst_l, Cp_h, Cp_l, Qst_h, Qst_l, V_h, V_l, U_h, U_l);
    hipLaunchKernelGGL(kgemm_kr, dim3(512), dim3(256), 0, stream, U_h, U_l, V_h, V_l, Dp, Kr);
    // --- conv + block ---
    hipLaunchKernelGGL(transpose_bmat, dim3(32, 16, 8), dim3(256), 0, stream, x, xT, 1024, 512);
    hipLaunchKernelGGL(conv_mfma, dim3(512), dim3(256), 0, stream, xT, Kr, yT, ssum);
    hipLaunchKernelGGL(se_kernel, dim3(8), dim3(256), 0, stream, ssum, se_w1, se_b1, se_w2, se_b2, gbuf);
    hipLaunchKernelGGL(transpose_bmat, dim3(16, 32, 8), dim3(256), 0, stream, yT, yb, 512, 1024);
    hipLaunchKernelGGL(fuse1_kernel, dim3(8192), dim3(128), 0, stream, x, yb, gbuf, n1g, n1b, y1b);
    hipLaunchKernelGGL(gemm_glu, dim3(64, 16), dim3(256), 0, stream, y1b, up_wb, up_b, act);
    hipLaunchKernelGGL(gemm_plain, dim3(64, 4), dim3(256), 0, stream, act, dn_wb, dn_b, zb);
    hipLaunchKernelGGL(fuse2_kernel, dim3(8192), dim3(128), 0, stream, y1b, zb, mxg, mxb, n2g, n2b, outp);
}

// Round 8
// 234.384 us; speedup vs baseline: 3.6419x; 1.0031x over previous
//
#include <hip/hip_runtime.h>
#include <math.h>

// Sizes: B=8, L=1024, D=512, N=64, NC=4, HIDDEN=1024, up rows=2048, R=64

typedef short bf16x8 __attribute__((ext_vector_type(8)));
typedef float f32x4 __attribute__((ext_vector_type(4)));

__device__ __forceinline__ float sigmoidf_(float x) { return 1.0f / (1.0f + expf(-x)); }
__device__ __forceinline__ float geluf_(float x) { return 0.5f * x * (1.0f + erff(x * 0.70710678118654752f)); }
__device__ __forceinline__ unsigned short f2bf(float f) {
    unsigned u = __float_as_uint(f);
    unsigned r = (u + 0x7FFFu + ((u >> 16) & 1u)) >> 16;
    return (unsigned short)r;
}
__device__ __forceinline__ unsigned pk2(unsigned short a, unsigned short b) {
    return (unsigned)a | ((unsigned)b << 16);
}
// async global->LDS, 16B per lane; LDS dest is wave-uniform base + lane*16.
__device__ __forceinline__ void gload16(const void* g, void* l) {
    __builtin_amdgcn_global_load_lds((const __attribute__((address_space(1))) unsigned int*)g,
                                     (__attribute__((address_space(3))) unsigned int*)l, 16, 0, 0);
}

// ---------------------------------------------------------------------------
// P1: A_bar via rank-1 O(N) forward substitution + 9 squarings (uniform
// k-loop, unroll 8). Pow[comp][s] = Abar^(2^s), s=0..9.
// ---------------------------------------------------------------------------
__global__ __launch_bounds__(256) void prep_comp(const float* __restrict__ log_dt,
                                                 float* __restrict__ Pow,
                                                 float* __restrict__ dtbuf) {
    int comp = blockIdx.x, tid = threadIdx.x;
    __shared__ __align__(16) float M1[4096];
    __shared__ __align__(16) float M1T[4096];
    __shared__ __align__(16) float M2[4096];
    __shared__ __align__(16) float M2T[4096];
    float ldt = log_dt[comp];
    float dt = log1pf(expf(ldt)) + 1e-6f;
    float hdt = 0.5f * dt;
    if (tid < 64) {
        int j = tid;
        float sqj = sqrtf(2.0f * (float)j + 1.0f);
        float S = 0.0f;
        for (int i = 0; i < 64; ++i) {
            float sqi = sqrtf(2.0f * (float)i + 1.0f);
            float r = (i == j) ? (1.0f - hdt * (float)(i + 1))
                               : ((i > j) ? (-hdt * sqi * sqj) : 0.0f);
            float X = (r - hdt * sqi * S) / (1.0f + hdt * (float)(i + 1));
            M1[i * 64 + j] = X;
            M1T[j * 64 + i] = X;
            S += sqi * X;
        }
    }
    __syncthreads();
    for (int ii = tid; ii < 4096; ii += 256) Pow[(size_t)comp * 40960 + ii] = M1[ii];
    float* cur = M1; float* curT = M1T; float* nxt = M2; float* nxtT = M2T;
    int ti = tid >> 4, tj = tid & 15;
    for (int s = 1; s <= 9; ++s) {
        float c[4][4] = {{0}};
#pragma unroll 8
        for (int k = 0; k < 64; ++k) {
            float4 a = *(const float4*)&curT[k * 64 + ti * 4];
            float4 b = *(const float4*)&cur[k * 64 + tj * 4];
            c[0][0] += a.x * b.x; c[0][1] += a.x * b.y; c[0][2] += a.x * b.z; c[0][3] += a.x * b.w;
            c[1][0] += a.y * b.x; c[1][1] += a.y * b.y; c[1][2] += a.y * b.z; c[1][3] += a.y * b.w;
            c[2][0] += a.z * b.x; c[2][1] += a.z * b.y; c[2][2] += a.z * b.z; c[2][3] += a.z * b.w;
            c[3][0] += a.w * b.x; c[3][1] += a.w * b.y; c[3][2] += a.w * b.z; c[3][3] += a.w * b.w;
        }
#pragma unroll
        for (int r = 0; r < 4; ++r) {
            float4 row; row.x = c[r][0]; row.y = c[r][1]; row.z = c[r][2]; row.w = c[r][3];
            *(float4*)&nxt[(ti * 4 + r) * 64 + tj * 4] = row;
            float4 colv; colv.x = c[0][r]; colv.y = c[1][r]; colv.z = c[2][r]; colv.w = c[3][r];
            *(float4*)&nxtT[(tj * 4 + r) * 64 + ti * 4] = colv;
        }
        __syncthreads();
        for (int ii = tid; ii < 4096; ii += 256) Pow[(size_t)comp * 40960 + s * 4096 + ii] = nxt[ii];
        float* t0 = cur; cur = nxt; nxt = t0;
        float* t1 = curT; curT = nxtT; nxtT = t1;
        __syncthreads();
    }
    if (tid == 0) dtbuf[comp] = dt;
}

// ---------------------------------------------------------------------------
// P2: B_bar rows, rank-1 O(N) per thread; emits bf16 hi/lo directly.
// ---------------------------------------------------------------------------
__global__ __launch_bounds__(256) void compute_bbar(const float* __restrict__ Bp,
                                                    const float* __restrict__ dtbuf,
                                                    unsigned short* __restrict__ Bb_h,
                                                    unsigned short* __restrict__ Bb_l) {
    int gid = blockIdx.x * 256 + threadIdx.x;
    int comp = gid >> 9;
    float dt = dtbuf[comp];
    float hdt = 0.5f * dt;
    const float* bp = Bp + (size_t)gid * 64;
    unsigned short* oh = Bb_h + (size_t)gid * 64;
    unsigned short* ol = Bb_l + (size_t)gid * 64;
    float S = 0.0f;
    for (int i = 0; i < 64; ++i) {
        float sqi = sqrtf(2.0f * (float)i + 1.0f);
        float y = (dt * bp[i] - hdt * sqi * S) / (1.0f + hdt * (float)(i + 1));
        unsigned short h = f2bf(y);
        oh[i] = h;
        ol[i] = f2bf(y - __uint_as_float((unsigned)h << 16));
        S += sqi * y;
    }
}

// ---------------------------------------------------------------------------
// convert_all: up_w -> bf16, dn_w -> bf16, Cp -> bf16 hi/lo. One launch.
// ---------------------------------------------------------------------------
__global__ __launch_bounds__(256) void convert_all(const float* __restrict__ up_w,
                                                   const float* __restrict__ dn_w,
                                                   const float* __restrict__ Cp,
                                                   unsigned short* __restrict__ up_wb,
                                                   unsigned short* __restrict__ dn_wb,
                                                   unsigned short* __restrict__ Cp_h,
                                                   unsigned short* __restrict__ Cp_l) {
    int i = blockIdx.x * 256 + threadIdx.x;
    if (i < 196608) {
        const float* src = (i < 131072) ? up_w : dn_w;
        unsigned short* dst = (i < 131072) ? up_wb : dn_wb;
        int j = (i < 131072) ? i : (i - 131072);
        float4 a = ((const float4*)src)[2 * j];
        float4 b = ((const float4*)src)[2 * j + 1];
        uint4 o;
        o.x = pk2(f2bf(a.x), f2bf(a.y));
        o.y = pk2(f2bf(a.z), f2bf(a.w));
        o.z = pk2(f2bf(b.x), f2bf(b.y));
        o.w = pk2(f2bf(b.z), f2bf(b.w));
        *(uint4*)&dst[(size_t)j * 8] = o;
    } else if (i < 212992) {
        int j = i - 196608;
        float4 a = ((const float4*)Cp)[2 * j];
        float4 b = ((const float4*)Cp)[2 * j + 1];
        float vv[8] = {a.x, a.y, a.z, a.w, b.x, b.y, b.z, b.w};
        unsigned short hs[8], ls[8];
#pragma unroll
        for (int k = 0; k < 8; ++k) {
            unsigned short h = f2bf(vv[k]);
            hs[k] = h;
            ls[k] = f2bf(vv[k] - __uint_as_float((unsigned)h << 16));
        }
        uint4 ho, lo;
        ho.x = pk2(hs[0], hs[1]); ho.y = pk2(hs[2], hs[3]); ho.z = pk2(hs[4], hs[5]); ho.w = pk2(hs[6], hs[7]);
        lo.x = pk2(ls[0], ls[1]); lo.y = pk2(ls[2], ls[3]); lo.z = pk2(ls[4], ls[5]); lo.w = pk2(ls[6], ls[7]);
        *(uint4*)&Cp_h[(size_t)j * 8] = ho;
        *(uint4*)&Cp_l[(size_t)j * 8] = lo;
    }
}

// ---------------------------------------------------------------------------
// power_mats: unchanged.
// ---------------------------------------------------------------------------
__global__ __launch_bounds__(256) void power_mats(const float* __restrict__ Pow,
                                                  unsigned short* __restrict__ Pst_h,
                                                  unsigned short* __restrict__ Pst_l,
                                                  unsigned short* __restrict__ Qst_h,
                                                  unsigned short* __restrict__ Qst_l) {
    int idx = blockIdx.x, comp = blockIdx.y, tid = threadIdx.x;
    __shared__ __align__(16) float R[4096], RT[4096], R2[4096], R2T[4096], SbT[4096];
    int isP = (idx < 32) ? 1 : 0;
    int f = isP ? idx : (idx - 32);
    int base_s = isP ? 0 : 5;
    const float* PowC = Pow + (size_t)comp * 40960;
    int i_ = tid & 63, kc = (tid >> 6) * 16;
    float* cur = R; float* curT = RT; float* nx = R2; float* nxT = R2T;
    if (f == 0) {
        for (int ii = tid; ii < 4096; ii += 256) {
            float v = ((ii >> 6) == (ii & 63)) ? 1.0f : 0.0f;
            R[ii] = v; RT[ii] = v;
        }
        __syncthreads();
    } else {
        int b0 = __ffs(f) - 1;
        const float* S0 = PowC + (size_t)(base_s + b0) * 4096;
#pragma unroll
        for (int j = 0; j < 16; j += 4) {
            float4 v = *(const float4*)&S0[i_ * 64 + kc + j];
            *(float4*)&R[i_ * 64 + kc + j] = v;
            RT[(kc + j + 0) * 64 + i_] = v.x;
            RT[(kc + j + 1) * 64 + i_] = v.y;
            RT[(kc + j + 2) * 64 + i_] = v.z;
            RT[(kc + j + 3) * 64 + i_] = v.w;
        }
        int rem = f & ~(1 << b0);
        int ti = tid >> 4, tj = tid & 15;
        __syncthreads();
        while (rem) {
            int b = __ffs(rem) - 1; rem &= rem - 1;
            const float* Sb = PowC + (size_t)(base_s + b) * 4096;
#pragma unroll
            for (int j = 0; j < 16; j += 4) {
                float4 v = *(const float4*)&Sb[i_ * 64 + kc + j];
                SbT[(kc + j + 0) * 64 + i_] = v.x;
                SbT[(kc + j + 1) * 64 + i_] = v.y;
                SbT[(kc + j + 2) * 64 + i_] = v.z;
                SbT[(kc + j + 3) * 64 + i_] = v.w;
            }
            __syncthreads();
            float c[4][4] = {{0}};
#pragma unroll 8
            for (int k = 0; k < 64; ++k) {
                float4 a = *(const float4*)&SbT[k * 64 + ti * 4];
                float4 b4 = *(const float4*)&cur[k * 64 + tj * 4];
                c[0][0] += a.x * b4.x; c[0][1] += a.x * b4.y; c[0][2] += a.x * b4.z; c[0][3] += a.x * b4.w;
                c[1][0] += a.y * b4.x; c[1][1] += a.y * b4.y; c[1][2] += a.y * b4.z; c[1][3] += a.y * b4.w;
                c[2][0] += a.z * b4.x; c[2][1] += a.z * b4.y; c[2][2] += a.z * b4.z; c[2][3] += a.z * b4.w;
                c[3][0] += a.w * b4.x; c[3][1] += a.w * b4.y; c[3][2] += a.w * b4.z; c[3][3] += a.w * b4.w;
            }
#pragma unroll
            for (int r = 0; r < 4; ++r) {
                float4 row; row.x = c[r][0]; row.y = c[r][1]; row.z = c[r][2]; row.w = c[r][3];
                *(float4*)&nx[(ti * 4 + r) * 64 + tj * 4] = row;
                float4 colv; colv.x = c[0][r]; colv.y = c[1][r]; colv.z = c[2][r]; colv.w = c[3][r];
                *(float4*)&nxT[(tj * 4 + r) * 64 + ti * 4] = colv;
            }
            __syncthreads();
            float* t0 = cur; cur = nx; nx = t0;
            float* t1 = curT; curT = nxT; nxT = t1;
        }
    }
    const float* src = isP ? cur : curT;
    int outrow = isP ? idx : (idx - 32);
    unsigned short* dh = (isP ? Pst_h : Qst_h) + (size_t)comp * 131072 + (size_t)outrow * 4096;
    unsigned short* dl = (isP ? Pst_l : Qst_l) + (size_t)comp * 131072 + (size_t)outrow * 4096;
    for (int ii = tid * 8; ii < 4096; ii += 2048) {
        float4 v0 = *(const float4*)&src[ii];
        float4 v1 = *(const float4*)&src[ii + 4];
        float vv[8] = {v0.x, v0.y, v0.z, v0.w, v1.x, v1.y, v1.z, v1.w};
        unsigned short hs[8], ls[8];
#pragma unroll
        for (int j = 0; j < 8; ++j) {
            unsigned short h = f2bf(vv[j]);
            hs[j] = h;
            ls[j] = f2bf(vv[j] - __uint_as_float((unsigned)h << 16));
        }
        uint4 ho, lo;
        ho.x = pk2(hs[0], hs[1]); ho.y = pk2(hs[2], hs[3]); ho.z = pk2(hs[4], hs[5]); ho.w = pk2(hs[6], hs[7]);
        lo.x = pk2(ls[0], ls[1]); lo.y = pk2(ls[2], ls[3]); lo.z = pk2(ls[4], ls[5]); lo.w = pk2(ls[6], ls[7]);
        *(uint4*)&dh[ii] = ho;
        *(uint4*)&dl[ii] = lo;
    }
}

// ---------------------------------------------------------------------------
// kgemm_uv2: merged U and V (unchanged).
// ---------------------------------------------------------------------------
__global__ __launch_bounds__(256) void kgemm_uv2(const unsigned short* __restrict__ Bb_h,
                                                 const unsigned short* __restrict__ Bb_l,
                                                 const unsigned short* __restrict__ Pst_h,
                                                 const unsigned short* __restrict__ Pst_l,
                                                 const unsigned short* __restrict__ Cp_h,
                                                 const unsigned short* __restrict__ Cp_l,
                                                 const unsigned short* __restrict__ Qst_h,
                                                 const unsigned short* __restrict__ Qst_l,
                                                 unsigned short* __restrict__ V_h,
                                                 unsigned short* __restrict__ V_l,
                                                 unsigned short* __restrict__ U_h,
                                                 unsigned short* __restrict__ U_l) {
    int zz = blockIdx.z;
    int isV = (zz < 4) ? 1 : 0;
    int comp = isV ? zz : (zz - 4);
    const unsigned short* Ah = isV ? Bb_h : Cp_h;
    const unsigned short* Al = isV ? Bb_l : Cp_l;
    const unsigned short* Bh = isV ? Pst_h : Qst_h;
    const unsigned short* Bl = isV ? Pst_l : Qst_l;
    unsigned short* Ch = isV ? V_h : U_h;
    unsigned short* Cl = isV ? V_l : U_l;
    int m0 = blockIdx.x * 128, n0 = blockIdx.y * 64;
    int tid = threadIdx.x, w = tid >> 6, l = tid & 63;
    __shared__ __align__(16) short Ash[8192], Asl[8192], Bsh[4096], Bsl[4096];
    const unsigned short* Abh = Ah + (size_t)comp * 32768;
    const unsigned short* Abl = Al + (size_t)comp * 32768;
    const unsigned short* Bbh = Bh + (size_t)comp * 131072;
    const unsigned short* Bbl = Bl + (size_t)comp * 131072;
#pragma unroll
    for (int i = 0; i < 4; ++i) {
        int cid = tid + 256 * i;
        int row = cid >> 3, slot = cid & 7;
        int goff = (m0 + row) * 64 + slot * 8;
        int loff = row * 64 + (slot ^ (row & 7)) * 8;
        *(uint4*)&Ash[loff] = *(const uint4*)(Abh + goff);
        *(uint4*)&Asl[loff] = *(const uint4*)(Abl + goff);
    }
#pragma unroll
    for (int i = 0; i < 2; ++i) {
        int cid = tid + 256 * i;
        int row = cid >> 3, slot = cid & 7;
        int goff = (n0 + row) * 64 + slot * 8;
        int loff = row * 64 + (slot ^ (row & 7)) * 8;
        *(uint4*)&Bsh[loff] = *(const uint4*)(Bbh + goff);
        *(uint4*)&Bsl[loff] = *(const uint4*)(Bbl + goff);
    }
    __syncthreads();
    int p = l >> 4, lr = l & 15;
    f32x4 acc[2][4];
#pragma unroll
    for (int rt = 0; rt < 2; ++rt)
#pragma unroll
        for (int ct = 0; ct < 4; ++ct) acc[rt][ct] = (f32x4)0.0f;
#pragma unroll
    for (int ks = 0; ks < 2; ++ks) {
        bf16x8 ah2[2], al2[2], bh2[4], bl2[4];
#pragma unroll
        for (int rt = 0; rt < 2; ++rt) {
            int row = w * 32 + rt * 16 + lr;
            int off = row * 64 + ((ks * 4 + p) ^ (row & 7)) * 8;
            ah2[rt] = *(bf16x8*)&Ash[off];
            al2[rt] = *(bf16x8*)&Asl[off];
        }
#pragma unroll
        for (int ct = 0; ct < 4; ++ct) {
            int cr = ct * 16 + lr;
            int off = cr * 64 + ((ks * 4 + p) ^ (cr & 7)) * 8;
            bh2[ct] = *(bf16x8*)&Bsh[off];
            bl2[ct] = *(bf16x8*)&Bsl[off];
        }
#pragma unroll
        for (int rt = 0; rt < 2; ++rt)
#pragma unroll
            for (int ct = 0; ct < 4; ++ct) {
                acc[rt][ct] = __builtin_amdgcn_mfma_f32_16x16x32_bf16(ah2[rt], bh2[ct], acc[rt][ct], 0, 0, 0);
                acc[rt][ct] = __builtin_amdgcn_mfma_f32_16x16x32_bf16(ah2[rt], bl2[ct], acc[rt][ct], 0, 0, 0);
                acc[rt][ct] = __builtin_amdgcn_mfma_f32_16x16x32_bf16(al2[rt], bh2[ct], acc[rt][ct], 0, 0, 0);
            }
    }
#pragma unroll
    for (int rt = 0; rt < 2; ++rt)
#pragma unroll
        for (int ct = 0; ct < 4; ++ct) {
#pragma unroll
            for (int reg = 0; reg < 4; ++reg) {
                int row = m0 + w * 32 + rt * 16 + p * 4 + reg;
                int col = n0 + ct * 16 + lr;
                float v = acc[rt][ct][reg];
                unsigned short h = f2bf(v);
                unsigned short lo2 = f2bf(v - __uint_as_float((unsigned)h << 16));
                size_t o = (size_t)comp * 1048576 + (size_t)row * 2048 + col;
                Ch[o] = h;
                Cl[o] = lo2;
            }
        }
}

// ---------------------------------------------------------------------------
// kgemm_kr: fused kgemm_k + reduce_K (unchanged).
// ---------------------------------------------------------------------------
__global__ __launch_bounds__(256) void kgemm_kr(const unsigned short* __restrict__ Uh,
                                                const unsigned short* __restrict__ Ul,
                                                const unsigned short* __restrict__ Vh,
                                                const unsigned short* __restrict__ Vl,
                                                const float* __restrict__ Dp,
                                                float* __restrict__ Kr) {
    int tid = threadIdx.x, w = tid >> 6, l = tid & 63;
    int d = blockIdx.x;
    int g = w * 512 + d;
    int p = l >> 4, lr = l & 15;
    __shared__ float ksh[4096];
    const unsigned short* ubh = Uh + (size_t)g * 2048;
    const unsigned short* ubl = Ul + (size_t)g * 2048;
    const unsigned short* vbh = Vh + (size_t)g * 2048;
    const unsigned short* vbl = Vl + (size_t)g * 2048;
    f32x4 acc[2][2];
    acc[0][0] = (f32x4)0.0f; acc[0][1] = (f32x4)0.0f;
    acc[1][0] = (f32x4)0.0f; acc[1][1] = (f32x4)0.0f;
#pragma unroll
    for (int ks = 0; ks < 2; ++ks) {
        bf16x8 uh2[2], ul2[2], vh2[2], vl2[2];
#pragma unroll
        for (int mt = 0; mt < 2; ++mt) {
            int off = (mt * 16 + lr) * 64 + ks * 32 + p * 8;
            uh2[mt] = *(const bf16x8*)(ubh + off);
            ul2[mt] = *(const bf16x8*)(ubl + off);
            vh2[mt] = *(const bf16x8*)(vbh + off);
            vl2[mt] = *(const bf16x8*)(vbl + off);
        }
#pragma unroll
        for (int mt = 0; mt < 2; ++mt)
#pragma unroll
            for (int nt = 0; nt < 2; ++nt) {
                acc[mt][nt] = __builtin_amdgcn_mfma_f32_16x16x32_bf16(uh2[mt], vh2[nt], acc[mt][nt], 0, 0, 0);
                acc[mt][nt] = __builtin_amdgcn_mfma_f32_16x16x32_bf16(uh2[mt], vl2[nt], acc[mt][nt], 0, 0, 0);
                acc[mt][nt] = __builtin_amdgcn_mfma_f32_16x16x32_bf16(ul2[mt], vh2[nt], acc[mt][nt], 0, 0, 0);
            }
    }
#pragma unroll
    for (int mt = 0; mt < 2; ++mt)
#pragma unroll
        for (int nt = 0; nt < 2; ++nt)
#pragma unroll
            for (int reg = 0; reg < 4; ++reg) {
                int q = mt * 16 + p * 4 + reg;
                int r = nt * 16 + lr;
                ksh[w * 1024 + q * 32 + r] = acc[mt][nt][reg];
            }
    __syncthreads();
#pragma unroll
    for (int j = 0; j < 4; ++j) {
        int ll = tid * 4 + j;
        float s = ksh[ll] + ksh[1024 + ll] + ksh[2048 + ll] + ksh[3072 + ll];
        if (ll == 0) s += Dp[d] + Dp[512 + d] + Dp[1024 + d] + Dp[1536 + d];
        Kr[(size_t)d * 1024 + (1023 - ll)] = s;
    }
}

// Generic batched transpose: in [B][R][C] -> out [B][C][R]
__global__ __launch_bounds__(256) void transpose_bmat(const float* __restrict__ in,
                                                      float* __restrict__ out,
                                                      int R, int C) {
    __shared__ float tile[32][33];
    int r0 = blockIdx.x * 32, c0 = blockIdx.y * 32, b = blockIdx.z;
    int tx = threadIdx.x & 31, ty = threadIdx.x >> 5;
#pragma unroll
    for (int m = 0; m < 4; ++m)
        tile[ty + 8 * m][tx] = in[((size_t)b * R + r0 + ty + 8 * m) * C + c0 + tx];
    __syncthreads();
#pragma unroll
    for (int m = 0; m < 4; ++m)
        out[((size_t)b * C + c0 + ty + 8 * m) * R + r0 + tx] = tile[tx][ty + 8 * m];
}

// ---------------------------------------------------------------------------
// MFMA depthwise conv (unchanged).
// ---------------------------------------------------------------------------
__global__ __launch_bounds__(256) void conv_mfma(const float* __restrict__ xT,
                                                 const float* __restrict__ Kr,
                                                 float* __restrict__ yT,
                                                 float* __restrict__ ssum) {
    int c = blockIdx.x, tid = threadIdx.x;
    int w = tid >> 6, l = tid & 63;
    __shared__ __align__(16) float krp[1088];
    __shared__ __align__(16) short xh[8512], xl[8512];
    __shared__ __align__(16) short gh[10240], gl[10240];
    __shared__ float ssh[64];

    {
        float4 kv = *(const float4*)&Kr[(size_t)c * 1024 + tid * 4];
        *(float4*)&krp[32 + tid * 4] = kv;
        if (tid < 8) *(float4*)&krp[tid * 4] = make_float4(0, 0, 0, 0);
        else if (tid < 16) *(float4*)&krp[1056 + (tid - 8) * 4] = make_float4(0, 0, 0, 0);
    }
    if (tid < 32) {
        int b = tid >> 2, g = tid & 3;
        uint4 z = {0, 0, 0, 0};
        *(uint4*)&xh[(b * 133 + g) * 8] = z;
    } else if (tid < 64) {
        int t2 = tid - 32; int b = t2 >> 2, g = t2 & 3;
        uint4 z = {0, 0, 0, 0};
        *(uint4*)&xl[(b * 133 + g) * 8] = z;
    }
#pragma unroll
    for (int i = 0; i < 4; ++i) {
        int gid = tid + 256 * i;
        int b = gid >> 7, gt = gid & 127;
        const float* src = &xT[((size_t)(b * 512 + c)) * 1024 + gt * 8];
        float4 v0 = *(const float4*)src;
        float4 v1 = *(const float4*)(src + 4);
        float vv[8] = {v0.x, v0.y, v0.z, v0.w, v1.x, v1.y, v1.z, v1.w};
        unsigned short hsv[8], lsv[8];
#pragma unroll
        for (int j2 = 0; j2 < 8; ++j2) {
            unsigned short h = f2bf(vv[j2]);
            hsv[j2] = h;
            lsv[j2] = f2bf(vv[j2] - __uint_as_float((unsigned)h << 16));
        }
        uint4 hh, ll;
        hh.x = pk2(hsv[0], hsv[1]); hh.y = pk2(hsv[2], hsv[3]);
        hh.z = pk2(hsv[4], hsv[5]); hh.w = pk2(hsv[6], hsv[7]);
        ll.x = pk2(lsv[0], lsv[1]); ll.y = pk2(lsv[2], lsv[3]);
        ll.z = pk2(lsv[4], lsv[5]); ll.w = pk2(lsv[6], lsv[7]);
        int off = (b * 133 + 4 + gt) * 8;
        *(uint4*)&xh[off] = hh;
        *(uint4*)&xl[off] = ll;
    }
    __syncthreads();

    f32x4 acc[4][2];
#pragma unroll
    for (int i = 0; i < 4; ++i) { acc[i][0] = (f32x4)0.0f; acc[i][1] = (f32x4)0.0f; }

    int lr = l & 15, kg4 = l >> 4;
    for (int ch = 0; ch < 4; ++ch) {
        int dq0 = ch * 8;
        {
            int dqloc = tid >> 5, n = tid & 31, dq = dq0 + dqloc;
            int s0 = 32 * dq + n + 1;
            int a0 = s0 & ~3, sh = s0 & 3;
            float ff[36];
#pragma unroll
            for (int i = 0; i < 9; ++i) *(float4*)&ff[i * 4] = *(const float4*)&krp[a0 + i * 4];
            unsigned short hsv[32], lsv[32];
#pragma unroll
            for (int k = 0; k < 32; ++k) {
                int j2 = 31 - k;
                float v = (sh == 0) ? ff[j2] : (sh == 1) ? ff[j2 + 1] : (sh == 2) ? ff[j2 + 2] : ff[j2 + 3];
                unsigned short h = f2bf(v);
                hsv[k] = h;
                lsv[k] = f2bf(v - __uint_as_float((unsigned)h << 16));
            }
            int gbase = (dqloc * 32 + n) * 5 * 8;
#pragma unroll
            for (int kg = 0; kg < 4; ++kg) {
                uint4 hh, ll;
                hh.x = pk2(hsv[8 * kg + 0], hsv[8 * kg + 1]);
                hh.y = pk2(hsv[8 * kg + 2], hsv[8 * kg + 3]);
                hh.z = pk2(hsv[8 * kg + 4], hsv[8 * kg + 5]);
                hh.w = pk2(hsv[8 * kg + 6], hsv[8 * kg + 7]);
                ll.x = pk2(lsv[8 * kg + 0], lsv[8 * kg + 1]);
                ll.y = pk2(lsv[8 * kg + 2], lsv[8 * kg + 3]);
                ll.z = pk2(lsv[8 * kg + 4], lsv[8 * kg + 5]);
                ll.w = pk2(lsv[8 * kg + 6], lsv[8 * kg + 7]);
                *(uint4*)&gh[gbase + kg * 8] = hh;
                *(uint4*)&gl[gbase + kg * 8] = ll;
            }
        }
        __syncthreads();
        for (int dqloc = 0; dqloc < 8; ++dqloc) {
            int dq = dq0 + dqloc;
            bf16x8 bh[2], bl[2];
#pragma unroll
            for (int nf = 0; nf < 2; ++nf) {
                int go = ((dqloc * 32 + nf * 16 + lr) * 5 + kg4) * 8;
                bh[nf] = *(bf16x8*)&gh[go];
                bl[nf] = *(bf16x8*)&gl[go];
            }
#pragma unroll
            for (int ffi = 0; ffi < 4; ++ffi) {
                int F = w + 4 * ffi;
                if (2 * F + 1 < dq) continue;
                int b = lr & 7, qoff = lr >> 3;
                int q = 2 * F + qoff;
                int j = 4 * (q - dq) + kg4 + 4;
                int xo = (b * 133 + j) * 8;
                bf16x8 ah = *(bf16x8*)&xh[xo];
                bf16x8 al = *(bf16x8*)&xl[xo];
#pragma unroll
                for (int nf = 0; nf < 2; ++nf) {
                    acc[ffi][nf] = __builtin_amdgcn_mfma_f32_16x16x32_bf16(ah, bh[nf], acc[ffi][nf], 0, 0, 0);
                    acc[ffi][nf] = __builtin_amdgcn_mfma_f32_16x16x32_bf16(al, bh[nf], acc[ffi][nf], 0, 0, 0);
                    acc[ffi][nf] = __builtin_amdgcn_mfma_f32_16x16x32_bf16(ah, bl[nf], acc[ffi][nf], 0, 0, 0);
                }
            }
        }
        __syncthreads();
    }

    float bsum[4] = {0, 0, 0, 0};
#pragma unroll
    for (int ffi = 0; ffi < 4; ++ffi) {
        int F = w + 4 * ffi;
#pragma unroll
        for (int nf = 0; nf < 2; ++nf) {
#pragma unroll
            for (int reg = 0; reg < 4; ++reg) {
                int mloc = 4 * kg4 + reg;
                int b = mloc & 7;
                int q = 2 * F + (mloc >> 3);
                int t = 32 * q + nf * 16 + lr;
                yT[((size_t)(b * 512 + c)) * 1024 + t] = acc[ffi][nf][reg];
                bsum[reg] += acc[ffi][nf][reg];
            }
        }
    }
#pragma unroll
    for (int off = 1; off < 16; off <<= 1) {
#pragma unroll
        for (int reg = 0; reg < 4; ++reg) bsum[reg] += __shfl_xor(bsum[reg], off, 64);
    }
    if (lr == 0) {
#pragma unroll
        for (int reg = 0; reg < 4; ++reg) ssh[w * 16 + kg4 * 4 + reg] = bsum[reg];
    }
    __syncthreads();
    if (tid < 8) {
        float tot = 0.0f;
        for (int w2 = 0; w2 < 4; ++w2) tot += ssh[w2 * 16 + tid] + ssh[w2 * 16 + 8 + tid];
        ssum[tid * 512 + c] = tot;
    }
}

__global__ __launch_bounds__(256) void se_kernel(const float* __restrict__ ssum,
                                                 const float* __restrict__ w1,
                                                 const float* __restrict__ b1,
                                                 const float* __restrict__ w2,
                                                 const float* __restrict__ b2,
                                                 float* __restrict__ g) {
    int b = blockIdx.x, tid = threadIdx.x;
    __shared__ float s_sh[512];
    __shared__ float part[256];
    __shared__ float h_sh[64];
    for (int c = tid; c < 512; c += 256) s_sh[c] = ssum[b * 512 + c] * (1.0f / 1024.0f);
    __syncthreads();
    int r = tid & 63, seg = tid >> 6;
    float p = 0.0f;
    for (int c = seg * 128; c < seg * 128 + 128; ++c) p += s_sh[c] * w1[r * 512 + c];
    part[tid] = p;
    __syncthreads();
    if (tid < 64) {
        float h = part[tid] + part[tid + 64] + part[tid + 128] + part[tid + 192] + b1[tid];
        h_sh[tid] = fmaxf(h, 0.0f);
    }
    __syncthreads();
    for (int c = tid; c < 512; c += 256) {
        float acc = b2[c];
#pragma unroll 8
        for (int rr = 0; rr < 64; ++rr) acc += h_sh[rr] * w2[c * 64 + rr];
        g[b * 512 + c] = 1.0f / (1.0f + expf(-acc));
    }
}

// fuse1: y1b = bf16(LN(x + y*g, n1))
__global__ __launch_bounds__(128) void fuse1_kernel(const float* __restrict__ x,
                                                    const float* __restrict__ y,
                                                    const float* __restrict__ g,
                                                    const float* __restrict__ n1g,
                                                    const float* __restrict__ n1b,
                                                    unsigned short* __restrict__ y1b) {
    int row = blockIdx.x, b = row >> 10, tid = threadIdx.x, c = tid * 4;
    __shared__ float r1[2], r2[2];
    float4 xv = *(const float4*)&x[(size_t)row * 512 + c];
    float4 yv = *(const float4*)&y[(size_t)row * 512 + c];
    float4 gv = *(const float4*)&g[b * 512 + c];
    float4 v;
    v.x = xv.x + yv.x * gv.x; v.y = xv.y + yv.y * gv.y;
    v.z = xv.z + yv.z * gv.z; v.w = xv.w + yv.w * gv.w;
    float s1 = v.x + v.y + v.z + v.w;
    float s2 = v.x * v.x + v.y * v.y + v.z * v.z + v.w * v.w;
#pragma unroll
    for (int off = 32; off > 0; off >>= 1) {
        s1 += __shfl_down(s1, off, 64);
        s2 += __shfl_down(s2, off, 64);
    }
    if ((tid & 63) == 0) { r1[tid >> 6] = s1; r2[tid >> 6] = s2; }
    __syncthreads();
    float mean = (r1[0] + r1[1]) * (1.0f / 512.0f);
    float var = (r2[0] + r2[1]) * (1.0f / 512.0f) - mean * mean;
    float rstd = rsqrtf(var + 1e-5f);
    float4 g4 = *(const float4*)&n1g[c];
    float4 b4 = *(const float4*)&n1b[c];
    float4 o;
    o.x = (v.x - mean) * rstd * g4.x + b4.x; o.y = (v.y - mean) * rstd * g4.y + b4.y;
    o.z = (v.z - mean) * rstd * g4.z + b4.z; o.w = (v.w - mean) * rstd * g4.w + b4.w;
    uint2 pk;
    pk.x = pk2(f2bf(o.x), f2bf(o.y));
    pk.y = pk2(f2bf(o.z), f2bf(o.w));
    *(uint2*)&y1b[(size_t)row * 512 + c] = pk;
}

__device__ __forceinline__ int swz_slot(int slot, int row) {
    return slot ^ (row & 3) ^ ((row >> 2) & 3);
}

// ---------------------------------------------------------------------------
// GEMM1 + GLU (bf16 MFMA). 2-phase double-buffered LDS: stage(next) issued
// right after the single per-iter barrier; that barrier's vmcnt(0) drain is
// the completion wait for the loads issued LAST iteration (in flight across
// the whole ds_read+MFMA phase). One barrier per K-step.
// ---------------------------------------------------------------------------
__global__ __launch_bounds__(256) void gemm_glu(const unsigned short* __restrict__ A,
                                                const unsigned short* __restrict__ W,
                                                const float* __restrict__ bias,
                                                unsigned short* __restrict__ act) {
    const int K = 512;
    int m0 = blockIdx.x * 128, n0 = blockIdx.y * 64;
    int tid = threadIdx.x, w = tid >> 6, l = tid & 63;
    __shared__ __align__(16) short As[2][4096];
    __shared__ __align__(16) short Bs[2][4096];
    int seg0 = 2 * w, seg1 = 2 * w + 1;
    int rA0 = seg0 * 16 + (l >> 2), rA1 = seg1 * 16 + (l >> 2);
    int ss0 = (l & 3) ^ (rA0 & 3) ^ ((rA0 >> 2) & 3);
    int ss1 = (l & 3) ^ (rA1 & 3) ^ ((rA1 >> 2) & 3);
    const unsigned short* gA0 = A + (size_t)(m0 + rA0) * K + ss0 * 8;
    const unsigned short* gA1 = A + (size_t)(m0 + rA1) * K + ss1 * 8;
    int gBr0 = (rA0 < 64) ? (n0 + rA0) : (1024 + n0 + rA0 - 64);
    int gBr1 = (rA1 < 64) ? (n0 + rA1) : (1024 + n0 + rA1 - 64);
    const unsigned short* gB0 = W + (size_t)gBr0 * K + ss0 * 8;
    const unsigned short* gB1 = W + (size_t)gBr1 * K + ss1 * 8;
    int p = l >> 4, lr = l & 15;
    int aoff[2], bAoff[4], bGoff[4];
#pragma unroll
    for (int rt = 0; rt < 2; ++rt) {
        int r = w * 32 + rt * 16 + lr;
        aoff[rt] = r * 32 + swz_slot(p, r) * 8;
    }
#pragma unroll
    for (int ct = 0; ct < 4; ++ct) {
        int ca = ct * 16 + lr, cg = 64 + ct * 16 + lr;
        bAoff[ct] = ca * 32 + swz_slot(p, ca) * 8;
        bGoff[ct] = cg * 32 + swz_slot(p, cg) * 8;
    }
    f32x4 accA[2][4], accG[2][4];
#pragma unroll
    for (int rt = 0; rt < 2; ++rt)
#pragma unroll
        for (int ct = 0; ct < 4; ++ct) {
            accA[rt][ct] = (f32x4)0.0f;
            accG[rt][ct] = (f32x4)0.0f;
        }
    // prologue: stage kt=0 into buffer 0
    gload16(gA0, &As[0][seg0 * 512]);
    gload16(gA1, &As[0][seg1 * 512]);
    gload16(gB0, &Bs[0][seg0 * 512]);
    gload16(gB1, &Bs[0][seg1 * 512]);
    int cur = 0;
    for (int kt = 0; kt < K; kt += 32) {
        __syncthreads();  // vmcnt(0): buffer `cur` staged; all reads of cur^1 done
        if (kt + 32 < K) {
            int nb = cur ^ 1;
            gload16(gA0 + kt + 32, &As[nb][seg0 * 512]);
            gload16(gA1 + kt + 32, &As[nb][seg1 * 512]);
            gload16(gB0 + kt + 32, &Bs[nb][seg0 * 512]);
            gload16(gB1 + kt + 32, &Bs[nb][seg1 * 512]);
        }
        bf16x8 af[2], bA[4], bG[4];
#pragma unroll
        for (int rt = 0; rt < 2; ++rt) af[rt] = *(bf16x8*)&As[cur][aoff[rt]];
#pragma unroll
        for (int ct = 0; ct < 4; ++ct) {
            bA[ct] = *(bf16x8*)&Bs[cur][bAoff[ct]];
            bG[ct] = *(bf16x8*)&Bs[cur][bGoff[ct]];
        }
#pragma unroll
        for (int rt = 0; rt < 2; ++rt)
#pragma unroll
            for (int ct = 0; ct < 4; ++ct) {
                accA[rt][ct] = __builtin_amdgcn_mfma_f32_16x16x32_bf16(af[rt], bA[ct], accA[rt][ct], 0, 0, 0);
                accG[rt][ct] = __builtin_amdgcn_mfma_f32_16x16x32_bf16(af[rt], bG[ct], accG[rt][ct], 0, 0, 0);
            }
        cur ^= 1;
    }
#pragma unroll
    for (int rt = 0; rt < 2; ++rt)
#pragma unroll
        for (int ct = 0; ct < 4; ++ct) {
            int col = n0 + ct * 16 + lr;
            float ba = bias[col], bg = bias[1024 + col];
#pragma unroll
            for (int reg = 0; reg < 4; ++reg) {
                int row = m0 + w * 32 + rt * 16 + p * 4 + reg;
                float a = accA[rt][ct][reg] + ba;
                float g = accG[rt][ct][reg] + bg;
                act[(size_t)row * 1024 + col] = f2bf(geluf_(a) * sigmoidf_(g));
            }
        }
}

// ---------------------------------------------------------------------------
// GEMM2 (bf16 MFMA): BM=128, BN=128; same 2-phase dbuf staging.
// ---------------------------------------------------------------------------
__global__ __launch_bounds__(256) void gemm_plain(const unsigned short* __restrict__ A,
                                                  const unsigned short* __restrict__ W,
                                                  const float* __restrict__ bias,
                                                  float* __restrict__ Cout) {
    const int K = 1024, N = 512;
    int m0 = blockIdx.x * 128, n0 = blockIdx.y * 128;
    int tid = threadIdx.x, w = tid >> 6, l = tid & 63;
    int wr = w >> 1, wc = w & 1;
    __shared__ __align__(16) short As[2][4096];
    __shared__ __align__(16) short Bs[2][4096];
    int seg0 = 2 * w, seg1 = 2 * w + 1;
    int rA0 = seg0 * 16 + (l >> 2), rA1 = seg1 * 16 + (l >> 2);
    int ss0 = (l & 3) ^ (rA0 & 3) ^ ((rA0 >> 2) & 3);
    int ss1 = (l & 3) ^ (rA1 & 3) ^ ((rA1 >> 2) & 3);
    const unsigned short* gA0 = A + (size_t)(m0 + rA0) * K + ss0 * 8;
    const unsigned short* gA1 = A + (size_t)(m0 + rA1) * K + ss1 * 8;
    const unsigned short* gB0 = W + (size_t)(n0 + rA0) * K + ss0 * 8;
    const unsigned short* gB1 = W + (size_t)(n0 + rA1) * K + ss1 * 8;
    int p = l >> 4, lr = l & 15;
    int aoff[4], boff[4];
#pragma unroll
    for (int t = 0; t < 4; ++t) {
        int r = wr * 64 + t * 16 + lr;
        aoff[t] = r * 32 + swz_slot(p, r) * 8;
        int cq = wc * 64 + t * 16 + lr;
        boff[t] = cq * 32 + swz_slot(p, cq) * 8;
    }
    f32x4 acc[4][4];
#pragma unroll
    for (int i = 0; i < 4; ++i)
#pragma unroll
        for (int j = 0; j < 4; ++j) acc[i][j] = (f32x4)0.0f;
    gload16(gA0, &As[0][seg0 * 512]);
    gload16(gA1, &As[0][seg1 * 512]);
    gload16(gB0, &Bs[0][seg0 * 512]);
    gload16(gB1, &Bs[0][seg1 * 512]);
    int cur = 0;
    for (int kt = 0; kt < K; kt += 32) {
        __syncthreads();
        if (kt + 32 < K) {
            int nb = cur ^ 1;
            gload16(gA0 + kt + 32, &As[nb][seg0 * 512]);
            gload16(gA1 + kt + 32, &As[nb][seg1 * 512]);
            gload16(gB0 + kt + 32, &Bs[nb][seg0 * 512]);
            gload16(gB1 + kt + 32, &Bs[nb][seg1 * 512]);
        }
        bf16x8 af[4], bfr[4];
#pragma unroll
        for (int t = 0; t < 4; ++t) {
            af[t] = *(bf16x8*)&As[cur][aoff[t]];
            bfr[t] = *(bf16x8*)&Bs[cur][boff[t]];
        }
#pragma unroll
        for (int i = 0; i < 4; ++i)
#pragma unroll
            for (int j = 0; j < 4; ++j)
                acc[i][j] = __builtin_amdgcn_mfma_f32_16x16x32_bf16(af[i], bfr[j], acc[i][j], 0, 0, 0);
        cur ^= 1;
    }
#pragma unroll
    for (int i = 0; i < 4; ++i)
#pragma unroll
        for (int j = 0; j < 4; ++j) {
            int col = n0 + wc * 64 + j * 16 + lr;
            float bb = bias[col];
#pragma unroll
            for (int reg = 0; reg < 4; ++reg) {
                int row = m0 + wr * 64 + i * 16 + p * 4 + reg;
                Cout[(size_t)row * N + col] = acc[i][j][reg] + bb;
            }
        }
}

// fuse2: z2 = LN(y1+z, mixn); out = LN(y1+z2, n2). y1 read as bf16.
__global__ __launch_bounds__(128) void fuse2_kernel(const unsigned short* __restrict__ y1b,
                                                    const float* __restrict__ z,
                                                    const float* __restrict__ mg,
                                                    const float* __restrict__ mb,
                                                    const float* __restrict__ g2,
                                                    const float* __restrict__ b2v,
                                                    float* __restrict__ out) {
    int row = blockIdx.x, tid = threadIdx.x, c = tid * 4;
    __shared__ float r1[2], r2[2];
    uint2 yu = *(const uint2*)&y1b[(size_t)row * 512 + c];
    float4 a;
    a.x = __uint_as_float(yu.x << 16);
    a.y = __uint_as_float(yu.x & 0xffff0000u);
    a.z = __uint_as_float(yu.y << 16);
    a.w = __uint_as_float(yu.y & 0xffff0000u);
    float4 zv = *(const float4*)&z[(size_t)row * 512 + c];
    float4 t1;
    t1.x = a.x + zv.x; t1.y = a.y + zv.y; t1.z = a.z + zv.z; t1.w = a.w + zv.w;
    float s1 = t1.x + t1.y + t1.z + t1.w;
    float s2 = t1.x * t1.x + t1.y * t1.y + t1.z * t1.z + t1.w * t1.w;
#pragma unroll
    for (int off = 32; off > 0; off >>= 1) {
        s1 += __shfl_down(s1, off, 64);
        s2 += __shfl_down(s2, off, 64);
    }
    if ((tid & 63) == 0) { r1[tid >> 6] = s1; r2[tid >> 6] = s2; }
    __syncthreads();
    float mean = (r1[0] + r1[1]) * (1.0f / 512.0f);
    float var = (r2[0] + r2[1]) * (1.0f / 512.0f) - mean * mean;
    float rstd = rsqrtf(var + 1e-5f);
    float4 mg4 = *(const float4*)&mg[c];
    float4 mb4 = *(const float4*)&mb[c];
    float4 t2;
    t2.x = a.x + ((t1.x - mean) * rstd * mg4.x + mb4.x);
    t2.y = a.y + ((t1.y - mean) * rstd * mg4.y + mb4.y);
    t2.z = a.z + ((t1.z - mean) * rstd * mg4.z + mb4.z);
    t2.w = a.w + ((t1.w - mean) * rstd * mg4.w + mb4.w);
    __syncthreads();
    s1 = t2.x + t2.y + t2.z + t2.w;
    s2 = t2.x * t2.x + t2.y * t2.y + t2.z * t2.z + t2.w * t2.w;
#pragma unroll
    for (int off = 32; off > 0; off >>= 1) {
        s1 += __shfl_down(s1, off, 64);
        s2 += __shfl_down(s2, off, 64);
    }
    if ((tid & 63) == 0) { r1[tid >> 6] = s1; r2[tid >> 6] = s2; }
    __syncthreads();
    float mean2 = (r1[0] + r1[1]) * (1.0f / 512.0f);
    float var2 = (r2[0] + r2[1]) * (1.0f / 512.0f) - mean2 * mean2;
    float rstd2 = rsqrtf(var2 + 1e-5f);
    float4 gg = *(const float4*)&g2[c];
    float4 bb = *(const float4*)&b2v[c];
    float4 o;
    o.x = (t2.x - mean2) * rstd2 * gg.x + bb.x;
    o.y = (t2.y - mean2) * rstd2 * gg.y + bb.y;
    o.z = (t2.z - mean2) * rstd2 * gg.z + bb.z;
    o.w = (t2.w - mean2) * rstd2 * gg.w + bb.w;
    *(float4*)&out[(size_t)row * 512 + c] = o;
}

// ---------------------------------------------------------------------------
// Workspace layout (float offsets), same map as rounds 5-7 (~70 MB).
// ---------------------------------------------------------------------------
extern "C" void kernel_launch(void* const* d_in, const int* in_sizes, int n_in,
                              void* d_out, int out_size, void* d_ws, size_t ws_size,
                              hipStream_t stream) {
    (void)in_sizes; (void)n_in; (void)out_size; (void)ws_size;
    const float* x      = (const float*)d_in[0];
    const float* Bp     = (const float*)d_in[1];
    const float* Cp     = (const float*)d_in[2];
    const float* Dp     = (const float*)d_in[3];
    const float* log_dt = (const float*)d_in[4];
    const float* se_w1  = (const float*)d_in[5];
    const float* se_b1  = (const float*)d_in[6];
    const float* se_w2  = (const float*)d_in[7];
    const float* se_b2  = (const float*)d_in[8];
    const float* n1g    = (const float*)d_in[9];
    const float* n1b    = (const float*)d_in[10];
    const float* up_w   = (const float*)d_in[11];
    const float* up_b   = (const float*)d_in[12];
    const float* dn_w   = (const float*)d_in[13];
    const float* dn_b   = (const float*)d_in[14];
    const float* mxg    = (const float*)d_in[15];
    const float* mxb    = (const float*)d_in[16];
    const float* n2g    = (const float*)d_in[17];
    const float* n2b    = (const float*)d_in[18];

    float* ws = (float*)d_ws;
    float* Kr   = ws + 0;          //   524,288
    float* dtb  = ws + 524288;     //        64
    float* ssum = ws + 524352;     //     4,096
    float* gbuf = ws + 528448;     //     4,096
    unsigned short* up_wb = (unsigned short*)(ws + 532544);   // 524,288 fl
    unsigned short* dn_wb = (unsigned short*)(ws + 1056832);  // 262,144 fl
    float* Pow  = ws + 1450048;    //   163,840
    unsigned short* Bb_h = (unsigned short*)(ws + 1613888);   // 65,536 fl each
    unsigned short* Bb_l = (unsigned short*)(ws + 1679424);
    unsigned short* Cp_h = (unsigned short*)(ws + 1744960);
    unsigned short* Cp_l = (unsigned short*)(ws + 1810496);
    unsigned short* Pst_h = (unsigned short*)(ws + 1876032);  // 262,144 fl each
    unsigned short* Pst_l = (unsigned short*)(ws + 2138176);
    unsigned short* Qst_h = (unsigned short*)(ws + 2400320);
    unsigned short* Qst_l = (unsigned short*)(ws + 2662464);
    unsigned short* U_h = (unsigned short*)(ws + 5021760);    // 2,097,152 fl
    unsigned short* U_l = (unsigned short*)(ws + 7118912);
    unsigned short* V_h = (unsigned short*)(ws + 9216064);
    unsigned short* V_l = (unsigned short*)(ws + 11313216);
    float* xT   = ws + 5021760;    // alias U_h+U_l (dead after kgemm_kr)
    float* yT   = ws + 9216064;    // alias V_h+V_l
    float* yb   = ws + 13410368;   // 4,194,304 (fresh)
    unsigned short* y1b = (unsigned short*)(ws + 9216064);    // alias yT after use
    unsigned short* act = (unsigned short*)(ws + 5021760);    // alias xT after conv
    float* zb   = ws + 13410368;   // alias yb after fuse1
    float* outp = (float*)d_out;

    // --- K pipeline ---
    hipLaunchKernelGGL(prep_comp, dim3(4), dim3(256), 0, stream, log_dt, Pow, dtb);
    hipLaunchKernelGGL(compute_bbar, dim3(8), dim3(256), 0, stream, Bp, dtb, Bb_h, Bb_l);
    hipLaunchKernelGGL(convert_all, dim3(832), dim3(256), 0, stream, up_w, dn_w, Cp, up_wb, dn_wb, Cp_h, Cp_l);
    hipLaunchKernelGGL(power_mats, dim3(64, 4), dim3(256), 0, stream, Pow, Pst_h, Pst_l, Qst_h, Qst_l);
    hipLaunchKernelGGL(kgemm_uv2, dim3(4, 32, 8), dim3(256), 0, stream,
                       Bb_h, Bb_l, Pst_h, Pst_l, Cp_h, Cp_l, Qst_h, Qst_l, V_h, V_l, U_h, U_l);
    hipLaunchKernelGGL(kgemm_kr, dim3(512), dim3(256), 0, stream, U_h, U_l, V_h, V_l, Dp, Kr);
    // --- conv + block ---
    hipLaunchKernelGGL(transpose_bmat, dim3(32, 16, 8), dim3(256), 0, stream, x, xT, 1024, 512);
    hipLaunchKernelGGL(conv_mfma, dim3(512), dim3(256), 0, stream, xT, Kr, yT, ssum);
    hipLaunchKernelGGL(se_kernel, dim3(8), dim3(256), 0, stream, ssum, se_w1, se_b1, se_w2, se_b2, gbuf);
    hipLaunchKernelGGL(transpose_bmat, dim3(16, 32, 8), dim3(256), 0, stream, yT, yb, 512, 1024);
    hipLaunchKernelGGL(fuse1_kernel, dim3(8192), dim3(128), 0, stream, x, yb, gbuf, n1g, n1b, y1b);
    hipLaunchKernelGGL(gemm_glu, dim3(64, 16), dim3(256), 0, stream, y1b, up_wb, up_b, act);
    hipLaunchKernelGGL(gemm_plain, dim3(64, 4), dim3(256), 0, stream, act, dn_wb, dn_b, zb);
    hipLaunchKernelGGL(fuse2_kernel, dim3(8192), dim3(128), 0, stream, y1b, zb, mxg, mxb, n2g, n2b, outp);
}